// Round 7
// baseline (1044.755 us; speedup 1.0000x reference)
//
#include <hip/hip_runtime.h>

// Problem constants (from reference)
constexpr int kNGene = 40000;
constexpr int kNGoid = 10000;
constexpr int kN     = 50000;
constexpr int kE     = 800000;
constexpr int kInDim = 1280;
constexpr int kH1    = 256;
constexpr int kH2    = 128;
constexpr int kOut   = 64;
constexpr int kGDim  = 4096;
constexpr int kD1    = 1024;

typedef short bf16x8 __attribute__((ext_vector_type(8)));
typedef float f32x4  __attribute__((ext_vector_type(4)));

static __device__ __forceinline__ short f2bf(float f) {
  union { float f; unsigned u; } v; v.f = f;
  unsigned r = v.u + 0x7FFF + ((v.u >> 16) & 1);   // RNE; inputs are finite
  return (short)(r >> 16);
}
static __device__ __forceinline__ float bf2f(short s) {
  union { unsigned u; float f; } v;
  v.u = ((unsigned)(unsigned short)s) << 16;
  return v.f;
}
// async global->LDS, 16B per lane; lds dest = base + lane*16 (wave-linear)
static __device__ __forceinline__ void gld16(const void* g, void* l) {
  __builtin_amdgcn_global_load_lds(
      (const __attribute__((address_space(1))) void*)g,
      (__attribute__((address_space(3))) void*)l, 16, 0, 0);
}

// ---------------- fp32 -> bf16 row-block convert ----------------
__global__ __launch_bounds__(256)
void k_cvt_rows(const float* __restrict__ src, int lda, short* __restrict__ dst,
                int rows, int cols) {
  int chunks_per_row = cols >> 3;
  long long total = (long long)rows * chunks_per_row;
  long long stride = (long long)gridDim.x * blockDim.x;
  for (long long i = blockIdx.x * (long long)blockDim.x + threadIdx.x; i < total; i += stride) {
    int r = (int)(i / chunks_per_row);
    int c = (int)(i - (long long)r * chunks_per_row) << 3;
    const float* sp = src + (size_t)r * lda + c;
    float4 v0 = *reinterpret_cast<const float4*>(sp);
    float4 v1 = *reinterpret_cast<const float4*>(sp + 4);
    bf16x8 t;
    t[0]=f2bf(v0.x); t[1]=f2bf(v0.y); t[2]=f2bf(v0.z); t[3]=f2bf(v0.w);
    t[4]=f2bf(v1.x); t[5]=f2bf(v1.y); t[6]=f2bf(v1.z); t[7]=f2bf(v1.w);
    *reinterpret_cast<bf16x8*>(dst + (size_t)r * cols + c) = t;
  }
}

// ---------------- degree / norm / CSR ----------------
__global__ void k_deg_init(float* deg, int* gcount) {
  int i = blockIdx.x * blockDim.x + threadIdx.x;
  if (i < kN) deg[i] = 1.0f;  // self-loop
  if (i == 0) *gcount = 0;
}
__global__ void k_zero_i(int* p, int n) {
  int i = blockIdx.x * blockDim.x + threadIdx.x;
  if (i < n) p[i] = 0;
}
// fused: degree count (all dst) + gene-dst histogram
__global__ void k_deg_hist(const int* __restrict__ ei, float* __restrict__ deg,
                           int* __restrict__ cnt) {
  int e = blockIdx.x * blockDim.x + threadIdx.x;
  if (e >= kE) return;
  int dst = ei[kE + e];
  atomicAdd(&deg[dst], 1.0f);
  if (dst < kNGene) atomicAdd(&cnt[dst], 1);
}
__global__ void k_rsqrt(float* deg) {
  int i = blockIdx.x * blockDim.x + threadIdx.x;
  if (i < kN) deg[i] = rsqrtf(deg[i]);
}
// parallel segment assignment: wave-level prefix of cnt + one atomic per wave.
// Segment ORDER across waves is arbitrary (disjoint), which is fine.
__global__ void k_rowassign(const int* __restrict__ cnt, int* __restrict__ rowstart,
                            int* __restrict__ cursor, int* __restrict__ gcount) {
  int i = blockIdx.x * blockDim.x + threadIdx.x;
  int lane = threadIdx.x & 63;
  int c = (i < kNGene) ? cnt[i] : 0;
  int incl = c;
#pragma unroll
  for (int off = 1; off < 64; off <<= 1) {
    int t = __shfl_up(incl, off, 64);
    if (lane >= off) incl += t;
  }
  int total = __shfl(incl, 63, 64);
  int base = 0;
  if (lane == 63) base = atomicAdd(gcount, total);
  base = __shfl(base, 63, 64);
  if (i < kNGene) {
    int s = base + incl - c;
    rowstart[i] = s;
    cursor[i] = s;
  }
}
__global__ void k_fill(const int* __restrict__ ei, const float* __restrict__ dinv,
                       int* __restrict__ cursor, int* __restrict__ srcs,
                       float* __restrict__ norms) {
  int e = blockIdx.x * blockDim.x + threadIdx.x;
  if (e >= kE) return;
  int dst = ei[kE + e];
  if (dst >= kNGene) return;  // those rows are overwritten later
  int src = ei[e];
  int pos = atomicAdd(&cursor[dst], 1);
  srcs[pos] = src;
  norms[pos] = dinv[src] * dinv[dst];
}

// ---------------- fused gather aggregation (bf16 messages) ------------------
// one wave per dst row; lane owns F/64 consecutive features. OBF: bf16 output.
template <int F, int OBF>
__global__ __launch_bounds__(256)
void k_gather_bf(const short* __restrict__ xw, const float* __restrict__ dinv,
                 const int* __restrict__ rowstart, const int* __restrict__ cnt,
                 const int* __restrict__ srcs, const float* __restrict__ norms,
                 const float* __restrict__ bias, void* __restrict__ hv) {
  constexpr int VEC = F / 64;
  int row = (blockIdx.x * blockDim.x + threadIdx.x) >> 6;
  int lane = threadIdx.x & 63;
  if (row >= kNGene) return;
  float d = dinv[row];
  float acc[VEC];
  {
    const short* xr = xw + (size_t)row * F + lane * VEC;
    if constexpr (VEC == 4) {
      short4 s = *reinterpret_cast<const short4*>(xr);
      acc[0] = bf2f(s.x) * d * d; acc[1] = bf2f(s.y) * d * d;
      acc[2] = bf2f(s.z) * d * d; acc[3] = bf2f(s.w) * d * d;
    } else {
      short2 s = *reinterpret_cast<const short2*>(xr);
      acc[0] = bf2f(s.x) * d * d; acc[1] = bf2f(s.y) * d * d;
    }
  }
  int e0 = rowstart[row], e1 = e0 + cnt[row];
  for (int e = e0; e < e1; ++e) {
    int src = srcs[e];
    float nrm = norms[e];
    const short* xs = xw + (size_t)src * F + lane * VEC;
    if constexpr (VEC == 4) {
      short4 s = *reinterpret_cast<const short4*>(xs);
      acc[0] += bf2f(s.x) * nrm; acc[1] += bf2f(s.y) * nrm;
      acc[2] += bf2f(s.z) * nrm; acc[3] += bf2f(s.w) * nrm;
    } else {
      short2 s = *reinterpret_cast<const short2*>(xs);
      acc[0] += bf2f(s.x) * nrm; acc[1] += bf2f(s.y) * nrm;
    }
  }
#pragma unroll
  for (int v = 0; v < VEC; ++v) acc[v] = fmaxf(acc[v] + bias[lane * VEC + v], 0.f);
  if constexpr (OBF) {
    short* hp = (short*)hv + (size_t)row * F + lane * VEC;
    if constexpr (VEC == 4) {
      short4 o; o.x = f2bf(acc[0]); o.y = f2bf(acc[1]); o.z = f2bf(acc[2]); o.w = f2bf(acc[3]);
      *reinterpret_cast<short4*>(hp) = o;
    } else {
      short2 o; o.x = f2bf(acc[0]); o.y = f2bf(acc[1]);
      *reinterpret_cast<short2*>(hp) = o;
    }
  } else {
    float* hp = (float*)hv + (size_t)row * F + lane * VEC;
    if constexpr (VEC == 4) {
      float4 o; o.x = acc[0]; o.y = acc[1]; o.z = acc[2]; o.w = acc[3];
      *reinterpret_cast<float4*>(hp) = o;
    } else {
      float2 o; o.x = acc[0]; o.y = acc[1];
      *reinterpret_cast<float2*>(hp) = o;
    }
  }
}

// ---------------- weight transpose fp32[K][N] -> bf16[N][K] ----------------
__global__ __launch_bounds__(256)
void k_wtrans(const float* __restrict__ W, short* __restrict__ Wt, int K, int N) {
  __shared__ float t[32][33];
  int tx = threadIdx.x & 31, ty = threadIdx.x >> 5;  // 32 x 8
  int n0 = blockIdx.x * 32, k0 = blockIdx.y * 32;
#pragma unroll
  for (int p = 0; p < 4; ++p)
    t[ty + 8 * p][tx] = W[(size_t)(k0 + ty + 8 * p) * N + n0 + tx];
  __syncthreads();
#pragma unroll
  for (int p = 0; p < 4; ++p)
    Wt[(size_t)(n0 + ty + 8 * p) * K + k0 + tx] = f2bf(t[tx][ty + 8 * p]);
}

// ---------------- bf16 MFMA GEMM, A bf16, global_load_lds staging -----------
// C[M,N] = A[M,K] @ B ; A bf16 row-major stride lda, Bt bf16 [N][K].
// N multiple of 128, K multiple of 32, lda multiple of 8.
// Tile 128x128, BK=32, 4 waves (2x2). LDS layout [kchunk][row][8].
// OBF=1 -> bf16 C; else fp32 C (+ optional dual bf16 copy C2).
template <int RELU, int OBF>
__global__ __launch_bounds__(256)
void k_gemm_bf16a(const short* __restrict__ A, int lda,
                  const short* __restrict__ Bt,
                  const float* __restrict__ bias,
                  void* __restrict__ Cv, int ldc,
                  short* __restrict__ C2,
                  int M, int K)
{
  __shared__ __align__(16) short As[4096];   // [kc][row][8] : kc*1024 + row*8
  __shared__ __align__(16) short Bs[4096];
  const int tid  = threadIdx.x;
  const int lane = tid & 63;
  const int wid  = tid >> 6;
  const int wr = wid >> 1, wc = wid & 1;
  const int row0 = blockIdx.y * 128;
  const int col0 = blockIdx.x * 128;
  const int l15 = lane & 15, l4 = lane >> 4;

  f32x4 acc[4][4] = {};

  for (int k0 = 0; k0 < K; k0 += 32) {
    // wave `wid` stages k-chunk `wid` for both 64-row/col halves
#pragma unroll
    for (int q = 0; q < 2; ++q) {
      int grow = row0 + q * 64 + lane;
      if (grow >= M) grow = M - 1;   // duplicate last row; epilogue masks
      gld16(A + (size_t)grow * lda + k0 + wid * 8, &As[wid * 1024 + q * 512]);
    }
#pragma unroll
    for (int q = 0; q < 2; ++q) {
      int gcol = col0 + q * 64 + lane;
      gld16(Bt + (size_t)gcol * K + k0 + wid * 8, &Bs[wid * 1024 + q * 512]);
    }
    __syncthreads();   // drains vmcnt (compiler emits full waitcnt before barrier)

    bf16x8 af[4], bfr[4];
#pragma unroll
    for (int m = 0; m < 4; ++m)
      af[m] = *reinterpret_cast<bf16x8*>(&As[l4 * 1024 + (wr * 64 + m * 16 + l15) * 8]);
#pragma unroll
    for (int n = 0; n < 4; ++n)
      bfr[n] = *reinterpret_cast<bf16x8*>(&Bs[l4 * 1024 + (wc * 64 + n * 16 + l15) * 8]);
#pragma unroll
    for (int m = 0; m < 4; ++m)
#pragma unroll
      for (int n = 0; n < 4; ++n)
        acc[m][n] = __builtin_amdgcn_mfma_f32_16x16x32_bf16(af[m], bfr[n], acc[m][n], 0, 0, 0);
    __syncthreads();
  }

#pragma unroll
  for (int n = 0; n < 4; ++n) {
    int col = col0 + wc * 64 + n * 16 + l15;
    float bv = bias ? bias[col] : 0.f;
#pragma unroll
    for (int m = 0; m < 4; ++m) {
      int rb = row0 + wr * 64 + m * 16 + l4 * 4;
#pragma unroll
      for (int e = 0; e < 4; ++e) {
        int r = rb + e;
        if (r < M) {
          float v = acc[m][n][e] + bv;
          if (RELU) v = fmaxf(v, 0.f);
          size_t idx = (size_t)r * ldc + col;
          if constexpr (OBF) ((short*)Cv)[idx] = f2bf(v);
          else {
            ((float*)Cv)[idx] = v;
            if (C2) C2[idx] = f2bf(v);
          }
        }
      }
    }
  }
}

// ---------------- bf16 MFMA GEMM, fp32 A on the fly, tile 128 x N=256 -------
// Single pass over A (full N per block). Bs staged via global_load_lds.
template <int RELU, int OBF>
__global__ __launch_bounds__(256)
void k_gemm_bf16f_n256(const float* __restrict__ A, int lda,
                       const short* __restrict__ Bt,   // [256][K]
                       const float* __restrict__ bias,
                       void* __restrict__ Cv, int ldc,
                       int M, int K)
{
  __shared__ __align__(16) short As[128 * 40];   // [row][k] pad-40
  __shared__ __align__(16) short Bs[8192];       // [kc][col][8] : kc*2048 + col*8
  const int tid  = threadIdx.x;
  const int lane = tid & 63;
  const int wid  = tid >> 6;
  const int wr = wid >> 1;           // 64-row half
  const int wc = wid & 1;            // 128-col half
  const int row0 = blockIdx.x * 128;
  const int l15 = lane & 15, l4 = lane >> 4;

  f32x4 acc[4][8] = {};
  const int sr = tid >> 2;
  const int sc = tid & 3;

  for (int k0 = 0; k0 < K; k0 += 32) {
    // B: wave `wid` stages k-chunk `wid` for all four 64-col groups
#pragma unroll
    for (int q = 0; q < 4; ++q) {
      int gcol = q * 64 + lane;
      gld16(Bt + (size_t)gcol * K + k0 + wid * 8, &Bs[wid * 2048 + q * 512]);
    }
    // A: fp32 -> bf16 VALU staging (pad-40 layout)
#pragma unroll
    for (int p = 0; p < 2; ++p) {
      int r = p * 64 + sr;
      int grow = row0 + r;
      float4 v0 = make_float4(0.f,0.f,0.f,0.f), v1 = v0;
      if (grow < M) {
        const float* ap = A + (size_t)grow * lda + k0 + sc * 8;
        v0 = *reinterpret_cast<const float4*>(ap);
        v1 = *reinterpret_cast<const float4*>(ap + 4);
      }
      bf16x8 t;
      t[0]=f2bf(v0.x); t[1]=f2bf(v0.y); t[2]=f2bf(v0.z); t[3]=f2bf(v0.w);
      t[4]=f2bf(v1.x); t[5]=f2bf(v1.y); t[6]=f2bf(v1.z); t[7]=f2bf(v1.w);
      *reinterpret_cast<bf16x8*>(&As[r * 40 + sc * 8]) = t;
    }
    __syncthreads();

    bf16x8 af[4], bfr[8];
#pragma unroll
    for (int m = 0; m < 4; ++m)
      af[m] = *reinterpret_cast<bf16x8*>(&As[(wr * 64 + m * 16 + l15) * 40 + l4 * 8]);
#pragma unroll
    for (int n = 0; n < 8; ++n)
      bfr[n] = *reinterpret_cast<bf16x8*>(&Bs[l4 * 2048 + (wc * 128 + n * 16 + l15) * 8]);
#pragma unroll
    for (int m = 0; m < 4; ++m)
#pragma unroll
      for (int n = 0; n < 8; ++n)
        acc[m][n] = __builtin_amdgcn_mfma_f32_16x16x32_bf16(af[m], bfr[n], acc[m][n], 0, 0, 0);
    __syncthreads();
  }

#pragma unroll
  for (int n = 0; n < 8; ++n) {
    int col = wc * 128 + n * 16 + l15;
    float bv = bias ? bias[col] : 0.f;
#pragma unroll
    for (int m = 0; m < 4; ++m) {
      int rb = row0 + wr * 64 + m * 16 + l4 * 4;
#pragma unroll
      for (int e = 0; e < 4; ++e) {
        int r = rb + e;
        if (r < M) {
          float v = acc[m][n][e] + bv;
          if (RELU) v = fmaxf(v, 0.f);
          size_t idx = (size_t)r * ldc + col;
          if constexpr (OBF) ((short*)Cv)[idx] = f2bf(v);
          else               ((float*)Cv)[idx] = v;
        }
      }
    }
  }
}

// ---------------- fp32 tiled GEMM (small output-path layers) ----------------
__global__ __launch_bounds__(256)
void k_gemm_f32(const float* __restrict__ A, int lda,
                const float* __restrict__ B, int ldb,
                const float* __restrict__ bias,
                float* __restrict__ C, int ldc,
                int M, int Ncol, int K, int do_relu)
{
  __shared__ float As[16][65];
  __shared__ float Bs[16][68];
  const int tid = threadIdx.x;
  const int tx = tid & 15, ty = tid >> 4;
  const int row0 = blockIdx.y * 64;
  const int col0 = blockIdx.x * 64;
  float acc[4][4] = {};
  for (int k0 = 0; k0 < K; k0 += 16) {
    {
      int r = tid >> 2;
      int c = (tid & 3) << 2;
      int grow = row0 + r;
      float4 v = make_float4(0.f, 0.f, 0.f, 0.f);
      if (grow < M)
        v = *reinterpret_cast<const float4*>(A + (size_t)grow * lda + k0 + c);
      As[c + 0][r] = v.x; As[c + 1][r] = v.y; As[c + 2][r] = v.z; As[c + 3][r] = v.w;
    }
    {
      int r = tid >> 4;
      int c = (tid & 15) << 2;
      int gcol = col0 + c;
      float4 v = make_float4(0.f, 0.f, 0.f, 0.f);
      if (gcol < Ncol)
        v = *reinterpret_cast<const float4*>(B + (size_t)(k0 + r) * ldb + gcol);
      *reinterpret_cast<float4*>(&Bs[r][c]) = v;
    }
    __syncthreads();
#pragma unroll
    for (int k = 0; k < 16; ++k) {
      float a[4], b[4];
#pragma unroll
      for (int i = 0; i < 4; ++i) a[i] = As[k][ty + 16 * i];
#pragma unroll
      for (int j = 0; j < 4; ++j) b[j] = Bs[k][tx + 16 * j];
#pragma unroll
      for (int i = 0; i < 4; ++i)
#pragma unroll
        for (int j = 0; j < 4; ++j)
          acc[i][j] = fmaf(a[i], b[j], acc[i][j]);
    }
    __syncthreads();
  }
#pragma unroll
  for (int i = 0; i < 4; ++i) {
    int r = row0 + ty + 16 * i;
    if (r >= M) continue;
#pragma unroll
    for (int j = 0; j < 4; ++j) {
      int ccol = col0 + tx + 16 * j;
      if (ccol >= Ncol) continue;
      float v = acc[i][j];
      if (bias) v += bias[ccol];
      if (do_relu) v = fmaxf(v, 0.f);
      C[(size_t)r * ldc + ccol] = v;
    }
  }
}

extern "C" void kernel_launch(void* const* d_in, const int* in_sizes, int n_in,
                              void* d_out, int out_size, void* d_ws, size_t ws_size,
                              hipStream_t stream) {
  const float* x   = (const float*)d_in[0];
  const int*   ei  = (const int*)d_in[1];
  const float* Wd1 = (const float*)d_in[3];
  const float* bd1 = (const float*)d_in[4];
  const float* Wd2 = (const float*)d_in[5];
  const float* bd2 = (const float*)d_in[6];
  const float* W1  = (const float*)d_in[7];
  const float* b1  = (const float*)d_in[8];
  const float* W2  = (const float*)d_in[9];
  const float* b2  = (const float*)d_in[10];
  const float* Wp1 = (const float*)d_in[11];
  const float* bp1 = (const float*)d_in[12];
  const float* Wp2 = (const float*)d_in[13];
  const float* bp2 = (const float*)d_in[14];
  const float* Wf  = (const float*)d_in[15];
  const float* bf_ = (const float*)d_in[16];
  float* out = (float*)d_out;
  float* ws  = (float*)d_ws;

  // workspace (float offsets), non-overlapping, all 16B-aligned; ~247 MB total
  short* goidx_bf = (short*)(ws + 0);          // 10000 x 4096 bf16
  short* goidt_bf = (short*)(ws + 20480000);   // 10000 x 1280 bf16
  short* h1tmp_bf = (short*)(ws + 26880000);   // 10000 x 1024 bf16
  short* Wd1t = (short*)(ws + 32000000);       // 1024 x 4096
  short* Wd2t = (short*)(ws + 34097152);       // 1280 x 1024
  short* W1t  = (short*)(ws + 34752512);       //  256 x 1280
  short* Wp1t = (short*)(ws + 34916352);       //  256 x 1280
  short* W2t  = (short*)(ws + 35080192);       //  128 x 256 (ends 35,096,576)
  short* xw1_bf = (short*)(ws + 35100000);     // 50000 x 256 bf16 (6.4M fl)
  short* h1bf   = (short*)(ws + 41500000);     // 50000 x 256 bf16 (6.4M fl)
  float* p1     = ws + 47900000;               // 10000 x 256 fp32 (2.56M fl)
  short* xw2_bf = (short*)(ws + 50460000);     // 50000 x 128 bf16 (3.2M fl)
  float* h2     = ws + 53660000;               // 50000 x 128 fp32 (6.4M fl)
  float* dinv   = ws + 60060000;               // 50,000
  int*   cnt      = (int*)(ws + 60110016);     // 40,000
  int*   rowstart = (int*)(ws + 60150016);     // 40,000
  int*   cursor   = (int*)(ws + 60190016);     // 40,000
  int*   srcs     = (int*)(ws + 60230016);     // 800,000
  float* norms    = ws + 61030016;             // 800,000
  int*   gcount   = (int*)(ws + 61830016);     // 1

  const float* gene_x = x;                          // rows 0..39999, lda=4096
  const float* goid_x = x + (size_t)kNGene * kGDim; // rows 40000..49999

  auto gb = [](int M, int Ncol) { return dim3((unsigned)(Ncol / 128), (unsigned)((M + 127) / 128)); };
  auto gf = [](int M, int Ncol) { return dim3((unsigned)((Ncol + 63) / 64), (unsigned)((M + 63) / 64)); };

  // 0) converts: goid_x -> bf16; weights -> bf16 transposed
  k_cvt_rows<<<2048, 256, 0, stream>>>(goid_x, kGDim, goidx_bf, kNGoid, kGDim);
  k_wtrans<<<dim3(kD1 / 32, kGDim / 32), 256, 0, stream>>>(Wd1, Wd1t, kGDim, kD1);
  k_wtrans<<<dim3(kInDim / 32, kD1 / 32), 256, 0, stream>>>(Wd2, Wd2t, kD1, kInDim);
  k_wtrans<<<dim3(kH1 / 32, kInDim / 32), 256, 0, stream>>>(W1, W1t, kInDim, kH1);
  k_wtrans<<<dim3(kH1 / 32, kInDim / 32), 256, 0, stream>>>(Wp1, Wp1t, kInDim, kH1);
  k_wtrans<<<dim3(kH2 / 32, kH1 / 32), 256, 0, stream>>>(W2, W2t, kH1, kH2);

  // 1) degrees + CSR (parallel offset assignment, no serial scan)
  k_deg_init<<<(kN + 255) / 256, 256, 0, stream>>>(dinv, gcount);
  k_zero_i<<<(kNGene + 255) / 256, 256, 0, stream>>>(cnt, kNGene);
  k_deg_hist<<<(kE + 255) / 256, 256, 0, stream>>>(ei, dinv, cnt);
  k_rsqrt<<<(kN + 255) / 256, 256, 0, stream>>>(dinv);
  k_rowassign<<<(kNGene + 255) / 256, 256, 0, stream>>>(cnt, rowstart, cursor, gcount);
  k_fill<<<(kE + 255) / 256, 256, 0, stream>>>(ei, dinv, cursor, srcs, norms);

  // 2) GOID MLP (gld-staged bf16 MFMA)
  k_gemm_bf16a<1,1><<<gb(kNGoid, kD1), 256, 0, stream>>>(goidx_bf, kGDim, Wd1t, bd1,
                                                         h1tmp_bf, kD1, nullptr, kNGoid, kGDim);
  k_gemm_bf16a<1,1><<<gb(kNGoid, kInDim), 256, 0, stream>>>(h1tmp_bf, kD1, Wd2t, bd2,
                                                            goidt_bf, kInDim, nullptr, kNGoid, kD1);

  // 3) xw1 = x_t @ W1 -> bf16 message table
  //    gene slice: fp32-A single-pass N=256 kernel (A read once)
  k_gemm_bf16f_n256<0,1><<<dim3((kNGene + 127) / 128), 256, 0, stream>>>(
      gene_x, kGDim, W1t, nullptr, xw1_bf, kH1, kNGene, kInDim);
  k_gemm_bf16a<0,1><<<gb(kNGoid, kH1), 256, 0, stream>>>(goidt_bf, kInDim, W1t, nullptr,
                                                         xw1_bf + (size_t)kNGene * kH1, kH1,
                                                         nullptr, kNGoid, kInDim);

  // 4) p1 = goid_t @ Wp1 + bp1 : fp32 p1 + dual bf16 write into h1 goid rows
  k_gemm_bf16a<0,0><<<gb(kNGoid, kH1), 256, 0, stream>>>(goidt_bf, kInDim, Wp1t, bp1,
                                                         p1, kH1,
                                                         h1bf + (size_t)kNGene * kH1,
                                                         kNGoid, kInDim);

  // 5) conv1: gather (bf16 messages) -> h1 bf16 gene rows
  k_gather_bf<kH1,1><<<(kNGene * 64 + 255) / 256, 256, 0, stream>>>(
      xw1_bf, dinv, rowstart, cnt, srcs, norms, b1, h1bf);

  // 6) xw2 = h1 @ W2 -> bf16 message table
  k_gemm_bf16a<0,1><<<gb(kN, kH2), 256, 0, stream>>>(h1bf, kH1, W2t, nullptr,
                                                     xw2_bf, kH2, nullptr, kN, kH1);

  // 7) conv2: gather -> h2 fp32 gene rows; goid rows = p1@Wp2+bp2 (fp32)
  k_gather_bf<kH2,0><<<(kNGene * 64 + 255) / 256, 256, 0, stream>>>(
      xw2_bf, dinv, rowstart, cnt, srcs, norms, b2, h2);
  k_gemm_f32<<<gf(kNGoid, kH2), 256, 0, stream>>>(p1, kH1, Wp2, kH2, bp2,
                                                  h2 + (size_t)kNGene * kH2, kH2,
                                                  kNGoid, kH2, kH1, 0);

  // 8) out = h2 @ Wf + bf
  k_gemm_f32<<<gf(kN, kOut), 256, 0, stream>>>(h2, kH2, Wf, kOut, bf_, out, kOut,
                                               kN, kOut, kH2, 0);
}

// Round 8
// 872.962 us; speedup vs baseline: 1.1968x; 1.1968x over previous
//
#include <hip/hip_runtime.h>

// Problem constants (from reference)
constexpr int kNGene = 40000;
constexpr int kNGoid = 10000;
constexpr int kN     = 50000;
constexpr int kE     = 800000;
constexpr int kInDim = 1280;
constexpr int kH1    = 256;
constexpr int kH2    = 128;
constexpr int kOut   = 64;
constexpr int kGDim  = 4096;
constexpr int kD1    = 1024;

typedef short bf16x8 __attribute__((ext_vector_type(8)));
typedef float f32x4  __attribute__((ext_vector_type(4)));

static __device__ __forceinline__ short f2bf(float f) {
  union { float f; unsigned u; } v; v.f = f;
  unsigned r = v.u + 0x7FFF + ((v.u >> 16) & 1);   // RNE; inputs are finite
  return (short)(r >> 16);
}
static __device__ __forceinline__ float bf2f(short s) {
  union { unsigned u; float f; } v;
  v.u = ((unsigned)(unsigned short)s) << 16;
  return v.f;
}

// ---------------- fp32 -> bf16 row-block convert ----------------
__global__ __launch_bounds__(256)
void k_cvt_rows(const float* __restrict__ src, int lda, short* __restrict__ dst,
                int rows, int cols) {
  int chunks_per_row = cols >> 3;
  long long total = (long long)rows * chunks_per_row;
  long long stride = (long long)gridDim.x * blockDim.x;
  for (long long i = blockIdx.x * (long long)blockDim.x + threadIdx.x; i < total; i += stride) {
    int r = (int)(i / chunks_per_row);
    int c = (int)(i - (long long)r * chunks_per_row) << 3;
    const float* sp = src + (size_t)r * lda + c;
    float4 v0 = *reinterpret_cast<const float4*>(sp);
    float4 v1 = *reinterpret_cast<const float4*>(sp + 4);
    bf16x8 t;
    t[0]=f2bf(v0.x); t[1]=f2bf(v0.y); t[2]=f2bf(v0.z); t[3]=f2bf(v0.w);
    t[4]=f2bf(v1.x); t[5]=f2bf(v1.y); t[6]=f2bf(v1.z); t[7]=f2bf(v1.w);
    *reinterpret_cast<bf16x8*>(dst + (size_t)r * cols + c) = t;
  }
}

// ---------------- degree / norm / CSR ----------------
__global__ void k_deg_init(float* deg, int* gcount) {
  int i = blockIdx.x * blockDim.x + threadIdx.x;
  if (i < kN) deg[i] = 1.0f;  // self-loop
  if (i == 0) *gcount = 0;
}
__global__ void k_zero_i(int* p, int n) {
  int i = blockIdx.x * blockDim.x + threadIdx.x;
  if (i < n) p[i] = 0;
}
// fused: degree count (all dst) + gene-dst histogram
__global__ void k_deg_hist(const int* __restrict__ ei, float* __restrict__ deg,
                           int* __restrict__ cnt) {
  int e = blockIdx.x * blockDim.x + threadIdx.x;
  if (e >= kE) return;
  int dst = ei[kE + e];
  atomicAdd(&deg[dst], 1.0f);
  if (dst < kNGene) atomicAdd(&cnt[dst], 1);
}
__global__ void k_rsqrt(float* deg) {
  int i = blockIdx.x * blockDim.x + threadIdx.x;
  if (i < kN) deg[i] = rsqrtf(deg[i]);
}
// parallel segment assignment: wave-level prefix of cnt + one atomic per wave.
// Segment ORDER across waves is arbitrary (disjoint ranges), which is fine.
__global__ void k_rowassign(const int* __restrict__ cnt, int* __restrict__ rowstart,
                            int* __restrict__ cursor, int* __restrict__ gcount) {
  int i = blockIdx.x * blockDim.x + threadIdx.x;
  int lane = threadIdx.x & 63;
  int c = (i < kNGene) ? cnt[i] : 0;
  int incl = c;
#pragma unroll
  for (int off = 1; off < 64; off <<= 1) {
    int t = __shfl_up(incl, off, 64);
    if (lane >= off) incl += t;
  }
  int total = __shfl(incl, 63, 64);
  int base = 0;
  if (lane == 63) base = atomicAdd(gcount, total);
  base = __shfl(base, 63, 64);
  if (i < kNGene) {
    int s = base + incl - c;
    rowstart[i] = s;
    cursor[i] = s;
  }
}
__global__ void k_fill(const int* __restrict__ ei, const float* __restrict__ dinv,
                       int* __restrict__ cursor, int* __restrict__ srcs,
                       float* __restrict__ norms) {
  int e = blockIdx.x * blockDim.x + threadIdx.x;
  if (e >= kE) return;
  int dst = ei[kE + e];
  if (dst >= kNGene) return;  // those rows are overwritten later
  int src = ei[e];
  int pos = atomicAdd(&cursor[dst], 1);
  srcs[pos] = src;
  norms[pos] = dinv[src] * dinv[dst];
}

// ---------------- fused gather aggregation (bf16 messages) ------------------
// one wave per dst row; lane owns F/64 consecutive features. OBF: bf16 output.
template <int F, int OBF>
__global__ __launch_bounds__(256)
void k_gather_bf(const short* __restrict__ xw, const float* __restrict__ dinv,
                 const int* __restrict__ rowstart, const int* __restrict__ cnt,
                 const int* __restrict__ srcs, const float* __restrict__ norms,
                 const float* __restrict__ bias, void* __restrict__ hv) {
  constexpr int VEC = F / 64;
  int row = (blockIdx.x * blockDim.x + threadIdx.x) >> 6;
  int lane = threadIdx.x & 63;
  if (row >= kNGene) return;
  float d = dinv[row];
  float acc[VEC];
  {
    const short* xr = xw + (size_t)row * F + lane * VEC;
    if constexpr (VEC == 4) {
      short4 s = *reinterpret_cast<const short4*>(xr);
      acc[0] = bf2f(s.x) * d * d; acc[1] = bf2f(s.y) * d * d;
      acc[2] = bf2f(s.z) * d * d; acc[3] = bf2f(s.w) * d * d;
    } else {
      short2 s = *reinterpret_cast<const short2*>(xr);
      acc[0] = bf2f(s.x) * d * d; acc[1] = bf2f(s.y) * d * d;
    }
  }
  int e0 = rowstart[row], e1 = e0 + cnt[row];
  for (int e = e0; e < e1; ++e) {
    int src = srcs[e];
    float nrm = norms[e];
    const short* xs = xw + (size_t)src * F + lane * VEC;
    if constexpr (VEC == 4) {
      short4 s = *reinterpret_cast<const short4*>(xs);
      acc[0] += bf2f(s.x) * nrm; acc[1] += bf2f(s.y) * nrm;
      acc[2] += bf2f(s.z) * nrm; acc[3] += bf2f(s.w) * nrm;
    } else {
      short2 s = *reinterpret_cast<const short2*>(xs);
      acc[0] += bf2f(s.x) * nrm; acc[1] += bf2f(s.y) * nrm;
    }
  }
#pragma unroll
  for (int v = 0; v < VEC; ++v) acc[v] = fmaxf(acc[v] + bias[lane * VEC + v], 0.f);
  if constexpr (OBF) {
    short* hp = (short*)hv + (size_t)row * F + lane * VEC;
    if constexpr (VEC == 4) {
      short4 o; o.x = f2bf(acc[0]); o.y = f2bf(acc[1]); o.z = f2bf(acc[2]); o.w = f2bf(acc[3]);
      *reinterpret_cast<short4*>(hp) = o;
    } else {
      short2 o; o.x = f2bf(acc[0]); o.y = f2bf(acc[1]);
      *reinterpret_cast<short2*>(hp) = o;
    }
  } else {
    float* hp = (float*)hv + (size_t)row * F + lane * VEC;
    if constexpr (VEC == 4) {
      float4 o; o.x = acc[0]; o.y = acc[1]; o.z = acc[2]; o.w = acc[3];
      *reinterpret_cast<float4*>(hp) = o;
    } else {
      float2 o; o.x = acc[0]; o.y = acc[1];
      *reinterpret_cast<float2*>(hp) = o;
    }
  }
}

// ---------------- weight transpose fp32[K][N] -> bf16[N][K] ----------------
__global__ __launch_bounds__(256)
void k_wtrans(const float* __restrict__ W, short* __restrict__ Wt, int K, int N) {
  __shared__ float t[32][33];
  int tx = threadIdx.x & 31, ty = threadIdx.x >> 5;  // 32 x 8
  int n0 = blockIdx.x * 32, k0 = blockIdx.y * 32;
#pragma unroll
  for (int p = 0; p < 4; ++p)
    t[ty + 8 * p][tx] = W[(size_t)(k0 + ty + 8 * p) * N + n0 + tx];
  __syncthreads();
#pragma unroll
  for (int p = 0; p < 4; ++p)
    Wt[(size_t)(n0 + ty + 8 * p) * K + k0 + tx] = f2bf(t[tx][ty + 8 * p]);
}

// ---------------- bf16 MFMA GEMM, A already bf16 (reg-staged, pad-40) -------
// C[M,N] = A[M,K] @ B ; A bf16 row-major stride lda, Bt bf16 [N][K].
// N multiple of 128, K multiple of 32. Tile 128x128, BK=32, 4 waves.
// OBF=1 -> bf16 C; else fp32 C (+ optional dual bf16 copy C2).
template <int RELU, int OBF>
__global__ __launch_bounds__(256)
void k_gemm_bf16a(const short* __restrict__ A, int lda,
                  const short* __restrict__ Bt,
                  const float* __restrict__ bias,
                  void* __restrict__ Cv, int ldc,
                  short* __restrict__ C2,
                  int M, int K)
{
  __shared__ short As[128 * 40];
  __shared__ short Bs[128 * 40];
  const int tid  = threadIdx.x;
  const int lane = tid & 63;
  const int wid  = tid >> 6;
  const int wr = wid >> 1, wc = wid & 1;
  const int row0 = blockIdx.y * 128;
  const int col0 = blockIdx.x * 128;
  const int l15 = lane & 15, l4 = lane >> 4;

  f32x4 acc[4][4] = {};
  const int sr = tid >> 2;   // 0..63
  const int sc = tid & 3;    // 16B chunk

  for (int k0 = 0; k0 < K; k0 += 32) {
#pragma unroll
    for (int p = 0; p < 2; ++p) {
      int r = p * 64 + sr;
      int grow = row0 + r;
      bf16x8 t = {};
      if (grow < M)
        t = *reinterpret_cast<const bf16x8*>(A + (size_t)grow * lda + k0 + sc * 8);
      *reinterpret_cast<bf16x8*>(&As[r * 40 + sc * 8]) = t;
    }
#pragma unroll
    for (int p = 0; p < 2; ++p) {
      int c = p * 64 + sr;
      *reinterpret_cast<bf16x8*>(&Bs[c * 40 + sc * 8]) =
          *reinterpret_cast<const bf16x8*>(Bt + (size_t)(col0 + c) * K + k0 + sc * 8);
    }
    __syncthreads();

    bf16x8 af[4], bfr[4];
#pragma unroll
    for (int m = 0; m < 4; ++m)
      af[m] = *reinterpret_cast<bf16x8*>(&As[(wr * 64 + m * 16 + l15) * 40 + l4 * 8]);
#pragma unroll
    for (int n = 0; n < 4; ++n)
      bfr[n] = *reinterpret_cast<bf16x8*>(&Bs[(wc * 64 + n * 16 + l15) * 40 + l4 * 8]);
#pragma unroll
    for (int m = 0; m < 4; ++m)
#pragma unroll
      for (int n = 0; n < 4; ++n)
        acc[m][n] = __builtin_amdgcn_mfma_f32_16x16x32_bf16(af[m], bfr[n], acc[m][n], 0, 0, 0);
    __syncthreads();
  }

#pragma unroll
  for (int n = 0; n < 4; ++n) {
    int col = col0 + wc * 64 + n * 16 + l15;
    float bv = bias ? bias[col] : 0.f;
#pragma unroll
    for (int m = 0; m < 4; ++m) {
      int rb = row0 + wr * 64 + m * 16 + l4 * 4;
#pragma unroll
      for (int e = 0; e < 4; ++e) {
        int r = rb + e;
        if (r < M) {
          float v = acc[m][n][e] + bv;
          if (RELU) v = fmaxf(v, 0.f);
          size_t idx = (size_t)r * ldc + col;
          if constexpr (OBF) ((short*)Cv)[idx] = f2bf(v);
          else {
            ((float*)Cv)[idx] = v;
            if (C2) C2[idx] = f2bf(v);
          }
        }
      }
    }
  }
}

// ---------------- bf16 MFMA GEMM, A fp32 converted on the fly ----------------
template <int RELU, int OBF>
__global__ __launch_bounds__(256)
void k_gemm_bf16f(const float* __restrict__ A, int lda,
                  const short* __restrict__ Bt,
                  const float* __restrict__ bias,
                  void* __restrict__ Cv, int ldc,
                  int M, int K)
{
  __shared__ short As[128 * 40];
  __shared__ short Bs[128 * 40];
  const int tid  = threadIdx.x;
  const int lane = tid & 63;
  const int wid  = tid >> 6;
  const int wr = wid >> 1, wc = wid & 1;
  const int row0 = blockIdx.y * 128;
  const int col0 = blockIdx.x * 128;
  const int l15 = lane & 15, l4 = lane >> 4;

  f32x4 acc[4][4] = {};
  const int sr = tid >> 2;
  const int sc = tid & 3;

  for (int k0 = 0; k0 < K; k0 += 32) {
#pragma unroll
    for (int p = 0; p < 2; ++p) {
      int r = p * 64 + sr;
      int grow = row0 + r;
      float4 v0 = make_float4(0.f,0.f,0.f,0.f), v1 = v0;
      if (grow < M) {
        const float* ap = A + (size_t)grow * lda + k0 + sc * 8;
        v0 = *reinterpret_cast<const float4*>(ap);
        v1 = *reinterpret_cast<const float4*>(ap + 4);
      }
      bf16x8 t;
      t[0]=f2bf(v0.x); t[1]=f2bf(v0.y); t[2]=f2bf(v0.z); t[3]=f2bf(v0.w);
      t[4]=f2bf(v1.x); t[5]=f2bf(v1.y); t[6]=f2bf(v1.z); t[7]=f2bf(v1.w);
      *reinterpret_cast<bf16x8*>(&As[r * 40 + sc * 8]) = t;
    }
#pragma unroll
    for (int p = 0; p < 2; ++p) {
      int c = p * 64 + sr;
      *reinterpret_cast<bf16x8*>(&Bs[c * 40 + sc * 8]) =
          *reinterpret_cast<const bf16x8*>(Bt + (size_t)(col0 + c) * K + k0 + sc * 8);
    }
    __syncthreads();

    bf16x8 af[4], bfr[4];
#pragma unroll
    for (int m = 0; m < 4; ++m)
      af[m] = *reinterpret_cast<bf16x8*>(&As[(wr * 64 + m * 16 + l15) * 40 + l4 * 8]);
#pragma unroll
    for (int n = 0; n < 4; ++n)
      bfr[n] = *reinterpret_cast<bf16x8*>(&Bs[(wc * 64 + n * 16 + l15) * 40 + l4 * 8]);
#pragma unroll
    for (int m = 0; m < 4; ++m)
#pragma unroll
      for (int n = 0; n < 4; ++n)
        acc[m][n] = __builtin_amdgcn_mfma_f32_16x16x32_bf16(af[m], bfr[n], acc[m][n], 0, 0, 0);
    __syncthreads();
  }

#pragma unroll
  for (int n = 0; n < 4; ++n) {
    int col = col0 + wc * 64 + n * 16 + l15;
    float bv = bias ? bias[col] : 0.f;
#pragma unroll
    for (int m = 0; m < 4; ++m) {
      int rb = row0 + wr * 64 + m * 16 + l4 * 4;
#pragma unroll
      for (int e = 0; e < 4; ++e) {
        int r = rb + e;
        if (r < M) {
          float v = acc[m][n][e] + bv;
          if (RELU) v = fmaxf(v, 0.f);
          size_t idx = (size_t)r * ldc + col;
          if constexpr (OBF) ((short*)Cv)[idx] = f2bf(v);
          else               ((float*)Cv)[idx] = v;
        }
      }
    }
  }
}

// ---------------- fp32 tiled GEMM (small output-path layers) ----------------
__global__ __launch_bounds__(256)
void k_gemm_f32(const float* __restrict__ A, int lda,
                const float* __restrict__ B, int ldb,
                const float* __restrict__ bias,
                float* __restrict__ C, int ldc,
                int M, int Ncol, int K, int do_relu)
{
  __shared__ float As[16][65];
  __shared__ float Bs[16][68];
  const int tid = threadIdx.x;
  const int tx = tid & 15, ty = tid >> 4;
  const int row0 = blockIdx.y * 64;
  const int col0 = blockIdx.x * 64;
  float acc[4][4] = {};
  for (int k0 = 0; k0 < K; k0 += 16) {
    {
      int r = tid >> 2;
      int c = (tid & 3) << 2;
      int grow = row0 + r;
      float4 v = make_float4(0.f, 0.f, 0.f, 0.f);
      if (grow < M)
        v = *reinterpret_cast<const float4*>(A + (size_t)grow * lda + k0 + c);
      As[c + 0][r] = v.x; As[c + 1][r] = v.y; As[c + 2][r] = v.z; As[c + 3][r] = v.w;
    }
    {
      int r = tid >> 4;
      int c = (tid & 15) << 2;
      int gcol = col0 + c;
      float4 v = make_float4(0.f, 0.f, 0.f, 0.f);
      if (gcol < Ncol)
        v = *reinterpret_cast<const float4*>(B + (size_t)(k0 + r) * ldb + gcol);
      *reinterpret_cast<float4*>(&Bs[r][c]) = v;
    }
    __syncthreads();
#pragma unroll
    for (int k = 0; k < 16; ++k) {
      float a[4], b[4];
#pragma unroll
      for (int i = 0; i < 4; ++i) a[i] = As[k][ty + 16 * i];
#pragma unroll
      for (int j = 0; j < 4; ++j) b[j] = Bs[k][tx + 16 * j];
#pragma unroll
      for (int i = 0; i < 4; ++i)
#pragma unroll
        for (int j = 0; j < 4; ++j)
          acc[i][j] = fmaf(a[i], b[j], acc[i][j]);
    }
    __syncthreads();
  }
#pragma unroll
  for (int i = 0; i < 4; ++i) {
    int r = row0 + ty + 16 * i;
    if (r >= M) continue;
#pragma unroll
    for (int j = 0; j < 4; ++j) {
      int ccol = col0 + tx + 16 * j;
      if (ccol >= Ncol) continue;
      float v = acc[i][j];
      if (bias) v += bias[ccol];
      if (do_relu) v = fmaxf(v, 0.f);
      C[(size_t)r * ldc + ccol] = v;
    }
  }
}

extern "C" void kernel_launch(void* const* d_in, const int* in_sizes, int n_in,
                              void* d_out, int out_size, void* d_ws, size_t ws_size,
                              hipStream_t stream) {
  const float* x   = (const float*)d_in[0];
  const int*   ei  = (const int*)d_in[1];
  const float* Wd1 = (const float*)d_in[3];
  const float* bd1 = (const float*)d_in[4];
  const float* Wd2 = (const float*)d_in[5];
  const float* bd2 = (const float*)d_in[6];
  const float* W1  = (const float*)d_in[7];
  const float* b1  = (const float*)d_in[8];
  const float* W2  = (const float*)d_in[9];
  const float* b2  = (const float*)d_in[10];
  const float* Wp1 = (const float*)d_in[11];
  const float* bp1 = (const float*)d_in[12];
  const float* Wp2 = (const float*)d_in[13];
  const float* bp2 = (const float*)d_in[14];
  const float* Wf  = (const float*)d_in[15];
  const float* bf_ = (const float*)d_in[16];
  float* out = (float*)d_out;
  float* ws  = (float*)d_ws;

  // workspace (float offsets), non-overlapping, all 16B-aligned; ~247 MB total
  short* goidx_bf = (short*)(ws + 0);          // 10000 x 4096 bf16
  short* goidt_bf = (short*)(ws + 20480000);   // 10000 x 1280 bf16
  short* h1tmp_bf = (short*)(ws + 26880000);   // 10000 x 1024 bf16
  short* Wd1t = (short*)(ws + 32000000);       // 1024 x 4096
  short* Wd2t = (short*)(ws + 34097152);       // 1280 x 1024
  short* W1t  = (short*)(ws + 34752512);       //  256 x 1280
  short* Wp1t = (short*)(ws + 34916352);       //  256 x 1280
  short* W2t  = (short*)(ws + 35080192);       //  128 x 256 (ends 35,096,576)
  short* xw1_bf = (short*)(ws + 35100000);     // 50000 x 256 bf16
  short* h1bf   = (short*)(ws + 41500000);     // 50000 x 256 bf16
  float* p1     = ws + 47900000;               // 10000 x 256 fp32
  short* xw2_bf = (short*)(ws + 50460000);     // 50000 x 128 bf16
  float* h2     = ws + 53660000;               // 50000 x 128 fp32
  float* dinv   = ws + 60060000;               // 50,000
  int*   cnt      = (int*)(ws + 60110016);     // 40,000
  int*   rowstart = (int*)(ws + 60150016);     // 40,000
  int*   cursor   = (int*)(ws + 60190016);     // 40,000
  int*   srcs     = (int*)(ws + 60230016);     // 800,000
  float* norms    = ws + 61030016;             // 800,000
  int*   gcount   = (int*)(ws + 61830016);     // 1

  const float* gene_x = x;                          // rows 0..39999, lda=4096
  const float* goid_x = x + (size_t)kNGene * kGDim; // rows 40000..49999

  auto gb = [](int M, int Ncol) { return dim3((unsigned)(Ncol / 128), (unsigned)((M + 127) / 128)); };
  auto gf = [](int M, int Ncol) { return dim3((unsigned)((Ncol + 63) / 64), (unsigned)((M + 63) / 64)); };

  // 0) converts: goid_x -> bf16; weights -> bf16 transposed
  k_cvt_rows<<<2048, 256, 0, stream>>>(goid_x, kGDim, goidx_bf, kNGoid, kGDim);
  k_wtrans<<<dim3(kD1 / 32, kGDim / 32), 256, 0, stream>>>(Wd1, Wd1t, kGDim, kD1);
  k_wtrans<<<dim3(kInDim / 32, kD1 / 32), 256, 0, stream>>>(Wd2, Wd2t, kD1, kInDim);
  k_wtrans<<<dim3(kH1 / 32, kInDim / 32), 256, 0, stream>>>(W1, W1t, kInDim, kH1);
  k_wtrans<<<dim3(kH1 / 32, kInDim / 32), 256, 0, stream>>>(Wp1, Wp1t, kInDim, kH1);
  k_wtrans<<<dim3(kH2 / 32, kH1 / 32), 256, 0, stream>>>(W2, W2t, kH1, kH2);

  // 1) degrees + CSR (parallel offset assignment, no serial scan)
  k_deg_init<<<(kN + 255) / 256, 256, 0, stream>>>(dinv, gcount);
  k_zero_i<<<(kNGene + 255) / 256, 256, 0, stream>>>(cnt, kNGene);
  k_deg_hist<<<(kE + 255) / 256, 256, 0, stream>>>(ei, dinv, cnt);
  k_rsqrt<<<(kN + 255) / 256, 256, 0, stream>>>(dinv);
  k_rowassign<<<(kNGene + 255) / 256, 256, 0, stream>>>(cnt, rowstart, cursor, gcount);
  k_fill<<<(kE + 255) / 256, 256, 0, stream>>>(ei, dinv, cursor, srcs, norms);

  // 2) GOID MLP (reg-staged bf16 MFMA)
  k_gemm_bf16a<1,1><<<gb(kNGoid, kD1), 256, 0, stream>>>(goidx_bf, kGDim, Wd1t, bd1,
                                                         h1tmp_bf, kD1, nullptr, kNGoid, kGDim);
  k_gemm_bf16a<1,1><<<gb(kNGoid, kInDim), 256, 0, stream>>>(h1tmp_bf, kD1, Wd2t, bd2,
                                                            goidt_bf, kInDim, nullptr, kNGoid, kD1);

  // 3) xw1 = x_t @ W1 -> bf16 message table
  k_gemm_bf16f<0,1><<<gb(kNGene, kH1), 256, 0, stream>>>(gene_x, kGDim, W1t, nullptr,
                                                         xw1_bf, kH1, kNGene, kInDim);
  k_gemm_bf16a<0,1><<<gb(kNGoid, kH1), 256, 0, stream>>>(goidt_bf, kInDim, W1t, nullptr,
                                                         xw1_bf + (size_t)kNGene * kH1, kH1,
                                                         nullptr, kNGoid, kInDim);

  // 4) p1 = goid_t @ Wp1 + bp1 : fp32 p1 + dual bf16 write into h1 goid rows
  k_gemm_bf16a<0,0><<<gb(kNGoid, kH1), 256, 0, stream>>>(goidt_bf, kInDim, Wp1t, bp1,
                                                         p1, kH1,
                                                         h1bf + (size_t)kNGene * kH1,
                                                         kNGoid, kInDim);

  // 5) conv1: gather (bf16 messages) -> h1 bf16 gene rows
  k_gather_bf<kH1,1><<<(kNGene * 64 + 255) / 256, 256, 0, stream>>>(
      xw1_bf, dinv, rowstart, cnt, srcs, norms, b1, h1bf);

  // 6) xw2 = h1 @ W2 -> bf16 message table
  k_gemm_bf16a<0,1><<<gb(kN, kH2), 256, 0, stream>>>(h1bf, kH1, W2t, nullptr,
                                                     xw2_bf, kH2, nullptr, kN, kH1);

  // 7) conv2: gather -> h2 fp32 gene rows; goid rows = p1@Wp2+bp2 (fp32)
  k_gather_bf<kH2,0><<<(kNGene * 64 + 255) / 256, 256, 0, stream>>>(
      xw2_bf, dinv, rowstart, cnt, srcs, norms, b2, h2);
  k_gemm_f32<<<gf(kNGoid, kH2), 256, 0, stream>>>(p1, kH1, Wp2, kH2, bp2,
                                                  h2 + (size_t)kNGene * kH2, kH2,
                                                  kNGoid, kH2, kH1, 0);

  // 8) out = h2 @ Wf + bf
  k_gemm_f32<<<gf(kN, kOut), 256, 0, stream>>>(h2, kH2, Wf, kOut, bf_, out, kOut,
                                               kN, kOut, kH2, 0);
}

// Round 9
// 818.588 us; speedup vs baseline: 1.2763x; 1.0664x over previous
//
#include <hip/hip_runtime.h>

// Problem constants (from reference)
constexpr int kNGene = 40000;
constexpr int kNGoid = 10000;
constexpr int kN     = 50000;
constexpr int kE     = 800000;
constexpr int kInDim = 1280;
constexpr int kH1    = 256;
constexpr int kH2    = 128;
constexpr int kOut   = 64;
constexpr int kGDim  = 4096;
constexpr int kD1    = 1024;

typedef short bf16x8 __attribute__((ext_vector_type(8)));
typedef float f32x4  __attribute__((ext_vector_type(4)));

static __device__ __forceinline__ short f2bf(float f) {
  union { float f; unsigned u; } v; v.f = f;
  unsigned r = v.u + 0x7FFF + ((v.u >> 16) & 1);   // RNE; inputs are finite
  return (short)(r >> 16);
}
static __device__ __forceinline__ float bf2f(short s) {
  union { unsigned u; float f; } v;
  v.u = ((unsigned)(unsigned short)s) << 16;
  return v.f;
}
// async global->LDS, 16B/lane; LDS dest = base + lane*16 (wave-linear).
// Global source is per-lane; caller must make lanes 64B-run coalesced.
static __device__ __forceinline__ void gld16(const void* g, void* l) {
  __builtin_amdgcn_global_load_lds(
      (const __attribute__((address_space(1))) void*)g,
      (__attribute__((address_space(3))) void*)l, 16, 0, 0);
}

// ---------------- fp32 -> bf16 row-block convert ----------------
__global__ __launch_bounds__(256)
void k_cvt_rows(const float* __restrict__ src, int lda, short* __restrict__ dst,
                int rows, int cols) {
  int chunks_per_row = cols >> 3;
  long long total = (long long)rows * chunks_per_row;
  long long stride = (long long)gridDim.x * blockDim.x;
  for (long long i = blockIdx.x * (long long)blockDim.x + threadIdx.x; i < total; i += stride) {
    int r = (int)(i / chunks_per_row);
    int c = (int)(i - (long long)r * chunks_per_row) << 3;
    const float* sp = src + (size_t)r * lda + c;
    float4 v0 = *reinterpret_cast<const float4*>(sp);
    float4 v1 = *reinterpret_cast<const float4*>(sp + 4);
    bf16x8 t;
    t[0]=f2bf(v0.x); t[1]=f2bf(v0.y); t[2]=f2bf(v0.z); t[3]=f2bf(v0.w);
    t[4]=f2bf(v1.x); t[5]=f2bf(v1.y); t[6]=f2bf(v1.z); t[7]=f2bf(v1.w);
    *reinterpret_cast<bf16x8*>(dst + (size_t)r * cols + c) = t;
  }
}

// ---------------- degree / norm / CSR ----------------
__global__ void k_deg_init(float* deg, int* gcount) {
  int i = blockIdx.x * blockDim.x + threadIdx.x;
  if (i < kN) deg[i] = 1.0f;  // self-loop
  if (i == 0) *gcount = 0;
}
__global__ void k_zero_i(int* p, int n) {
  int i = blockIdx.x * blockDim.x + threadIdx.x;
  if (i < n) p[i] = 0;
}
// fused: degree count (all dst) + gene-dst histogram
__global__ void k_deg_hist(const int* __restrict__ ei, float* __restrict__ deg,
                           int* __restrict__ cnt) {
  int e = blockIdx.x * blockDim.x + threadIdx.x;
  if (e >= kE) return;
  int dst = ei[kE + e];
  atomicAdd(&deg[dst], 1.0f);
  if (dst < kNGene) atomicAdd(&cnt[dst], 1);
}
__global__ void k_rsqrt(float* deg) {
  int i = blockIdx.x * blockDim.x + threadIdx.x;
  if (i < kN) deg[i] = rsqrtf(deg[i]);
}
// parallel segment assignment: wave-level prefix of cnt + one atomic per wave.
__global__ void k_rowassign(const int* __restrict__ cnt, int* __restrict__ rowstart,
                            int* __restrict__ cursor, int* __restrict__ gcount) {
  int i = blockIdx.x * blockDim.x + threadIdx.x;
  int lane = threadIdx.x & 63;
  int c = (i < kNGene) ? cnt[i] : 0;
  int incl = c;
#pragma unroll
  for (int off = 1; off < 64; off <<= 1) {
    int t = __shfl_up(incl, off, 64);
    if (lane >= off) incl += t;
  }
  int total = __shfl(incl, 63, 64);
  int base = 0;
  if (lane == 63) base = atomicAdd(gcount, total);
  base = __shfl(base, 63, 64);
  if (i < kNGene) {
    int s = base + incl - c;
    rowstart[i] = s;
    cursor[i] = s;
  }
}
__global__ void k_fill(const int* __restrict__ ei, const float* __restrict__ dinv,
                       int* __restrict__ cursor, int* __restrict__ srcs,
                       float* __restrict__ norms) {
  int e = blockIdx.x * blockDim.x + threadIdx.x;
  if (e >= kE) return;
  int dst = ei[kE + e];
  if (dst >= kNGene) return;  // those rows are overwritten later
  int src = ei[e];
  int pos = atomicAdd(&cursor[dst], 1);
  srcs[pos] = src;
  norms[pos] = dinv[src] * dinv[dst];
}

// ---------------- fused gather aggregation (bf16 messages) ------------------
template <int F, int OBF>
__global__ __launch_bounds__(256)
void k_gather_bf(const short* __restrict__ xw, const float* __restrict__ dinv,
                 const int* __restrict__ rowstart, const int* __restrict__ cnt,
                 const int* __restrict__ srcs, const float* __restrict__ norms,
                 const float* __restrict__ bias, void* __restrict__ hv) {
  constexpr int VEC = F / 64;
  int row = (blockIdx.x * blockDim.x + threadIdx.x) >> 6;
  int lane = threadIdx.x & 63;
  if (row >= kNGene) return;
  float d = dinv[row];
  float acc[VEC];
  {
    const short* xr = xw + (size_t)row * F + lane * VEC;
    if constexpr (VEC == 4) {
      short4 s = *reinterpret_cast<const short4*>(xr);
      acc[0] = bf2f(s.x) * d * d; acc[1] = bf2f(s.y) * d * d;
      acc[2] = bf2f(s.z) * d * d; acc[3] = bf2f(s.w) * d * d;
    } else {
      short2 s = *reinterpret_cast<const short2*>(xr);
      acc[0] = bf2f(s.x) * d * d; acc[1] = bf2f(s.y) * d * d;
    }
  }
  int e0 = rowstart[row], e1 = e0 + cnt[row];
  for (int e = e0; e < e1; ++e) {
    int src = srcs[e];
    float nrm = norms[e];
    const short* xs = xw + (size_t)src * F + lane * VEC;
    if constexpr (VEC == 4) {
      short4 s = *reinterpret_cast<const short4*>(xs);
      acc[0] += bf2f(s.x) * nrm; acc[1] += bf2f(s.y) * nrm;
      acc[2] += bf2f(s.z) * nrm; acc[3] += bf2f(s.w) * nrm;
    } else {
      short2 s = *reinterpret_cast<const short2*>(xs);
      acc[0] += bf2f(s.x) * nrm; acc[1] += bf2f(s.y) * nrm;
    }
  }
#pragma unroll
  for (int v = 0; v < VEC; ++v) acc[v] = fmaxf(acc[v] + bias[lane * VEC + v], 0.f);
  if constexpr (OBF) {
    short* hp = (short*)hv + (size_t)row * F + lane * VEC;
    if constexpr (VEC == 4) {
      short4 o; o.x = f2bf(acc[0]); o.y = f2bf(acc[1]); o.z = f2bf(acc[2]); o.w = f2bf(acc[3]);
      *reinterpret_cast<short4*>(hp) = o;
    } else {
      short2 o; o.x = f2bf(acc[0]); o.y = f2bf(acc[1]);
      *reinterpret_cast<short2*>(hp) = o;
    }
  } else {
    float* hp = (float*)hv + (size_t)row * F + lane * VEC;
    if constexpr (VEC == 4) {
      float4 o; o.x = acc[0]; o.y = acc[1]; o.z = acc[2]; o.w = acc[3];
      *reinterpret_cast<float4*>(hp) = o;
    } else {
      float2 o; o.x = acc[0]; o.y = acc[1];
      *reinterpret_cast<float2*>(hp) = o;
    }
  }
}

// ---------------- weight transpose fp32[K][N] -> bf16[N][K] ----------------
__global__ __launch_bounds__(256)
void k_wtrans(const float* __restrict__ W, short* __restrict__ Wt, int K, int N) {
  __shared__ float t[32][33];
  int tx = threadIdx.x & 31, ty = threadIdx.x >> 5;  // 32 x 8
  int n0 = blockIdx.x * 32, k0 = blockIdx.y * 32;
#pragma unroll
  for (int p = 0; p < 4; ++p)
    t[ty + 8 * p][tx] = W[(size_t)(k0 + ty + 8 * p) * N + n0 + tx];
  __syncthreads();
#pragma unroll
  for (int p = 0; p < 4; ++p)
    Wt[(size_t)(n0 + ty + 8 * p) * K + k0 + tx] = f2bf(t[tx][ty + 8 * p]);
}

// ---------------- bf16 MFMA GEMM, A bf16, global_load_lds staging -----------
// C[M,N] = A[M,K] @ B ; A bf16 row-major stride lda, Bt bf16 [N][K].
// N multiple of 128, K multiple of 32, lda multiple of 8 (16B).
// Tile 128x128, BK=32, 4 waves. LDS linear [row][32]: lane l of segment seg
// covers row seg*16+(l>>2), chunk l&3 -> 64B-coalesced global, LDS = base+l*16.
template <int RELU, int OBF>
__global__ __launch_bounds__(256)
void k_gemm_bf16a(const short* __restrict__ A, int lda,
                  const short* __restrict__ Bt,
                  const float* __restrict__ bias,
                  void* __restrict__ Cv, int ldc,
                  short* __restrict__ C2,
                  int M, int K)
{
  __shared__ __align__(16) short As[128 * 32];
  __shared__ __align__(16) short Bs[128 * 32];
  const int tid  = threadIdx.x;
  const int lane = tid & 63;
  const int wid  = tid >> 6;
  const int wr = wid >> 1, wc = wid & 1;
  const int row0 = blockIdx.y * 128;
  const int col0 = blockIdx.x * 128;
  const int l15 = lane & 15, l4 = lane >> 4;

  f32x4 acc[4][4] = {};
  const int srow   = lane >> 2;   // 0..15 within 16-row segment
  const int schunk = lane & 3;    // 16B chunk within row

  for (int k0 = 0; k0 < K; k0 += 32) {
#pragma unroll
    for (int q = 0; q < 2; ++q) {
      int seg = wid * 2 + q;              // 0..7
      int r = seg * 16 + srow;
      int grow = row0 + r;
      if (grow >= M) grow = M - 1;        // duplicate; epilogue masks
      gld16(A + (size_t)grow * lda + k0 + schunk * 8, &As[seg * 512]);
      int gcol = col0 + r;                // N % 128 == 0: always in range
      gld16(Bt + (size_t)gcol * K + k0 + schunk * 8, &Bs[seg * 512]);
    }
    __syncthreads();   // drains vmcnt before barrier (compiler-emitted)

    bf16x8 af[4], bfr[4];
#pragma unroll
    for (int m = 0; m < 4; ++m)
      af[m] = *reinterpret_cast<bf16x8*>(&As[(wr * 64 + m * 16 + l15) * 32 + l4 * 8]);
#pragma unroll
    for (int n = 0; n < 4; ++n)
      bfr[n] = *reinterpret_cast<bf16x8*>(&Bs[(wc * 64 + n * 16 + l15) * 32 + l4 * 8]);
#pragma unroll
    for (int m = 0; m < 4; ++m)
#pragma unroll
      for (int n = 0; n < 4; ++n)
        acc[m][n] = __builtin_amdgcn_mfma_f32_16x16x32_bf16(af[m], bfr[n], acc[m][n], 0, 0, 0);
    __syncthreads();
  }

#pragma unroll
  for (int n = 0; n < 4; ++n) {
    int col = col0 + wc * 64 + n * 16 + l15;
    float bv = bias ? bias[col] : 0.f;
#pragma unroll
    for (int m = 0; m < 4; ++m) {
      int rb = row0 + wr * 64 + m * 16 + l4 * 4;
#pragma unroll
      for (int e = 0; e < 4; ++e) {
        int r = rb + e;
        if (r < M) {
          float v = acc[m][n][e] + bv;
          if (RELU) v = fmaxf(v, 0.f);
          size_t idx = (size_t)r * ldc + col;
          if constexpr (OBF) ((short*)Cv)[idx] = f2bf(v);
          else {
            ((float*)Cv)[idx] = v;
            if (C2) C2[idx] = f2bf(v);
          }
        }
      }
    }
  }
}

// ---------------- gene xw1: fp32-A single-pass, tile 128x256, 8 waves -------
// A fp32 stride lda (VALU-staged to pad-40 bf16 LDS); Bt[256][K] via gld16.
// C written bf16 (message table), no bias/relu.
__global__ __launch_bounds__(512)
void k_gemm_gene(const float* __restrict__ A, int lda,
                 const short* __restrict__ Bt,
                 short* __restrict__ C,   // [M][256] bf16
                 int M, int K)
{
  __shared__ short As[128 * 40];                 // pad-40 (80B rows, 16B-multiple)
  __shared__ __align__(16) short Bs[256 * 32];   // linear [col][32]
  const int tid  = threadIdx.x;
  const int lane = tid & 63;
  const int wid  = tid >> 6;        // 0..7
  const int wr = wid >> 2;          // 0..1  (64-row half)
  const int wc = wid & 3;           // 0..3  (64-col quarter of 256)
  const int row0 = blockIdx.x * 128;
  const int l15 = lane & 15, l4 = lane >> 4;

  f32x4 acc[4][4] = {};
  const int sr = tid >> 2;          // 0..127 (A staging row)
  const int sc = tid & 3;           // 16B chunk
  const int srow = lane >> 2, schunk = lane & 3;

  for (int k0 = 0; k0 < K; k0 += 32) {
    // B: 16 segments of 16 cols; wave wid stages segments wid*2, wid*2+1
#pragma unroll
    for (int q = 0; q < 2; ++q) {
      int seg = wid * 2 + q;              // 0..15
      int gcol = seg * 16 + srow;         // 0..255
      gld16(Bt + (size_t)gcol * K + k0 + schunk * 8, &Bs[seg * 512]);
    }
    // A: fp32 -> bf16 VALU staging (512 threads cover 128 rows x 4 chunks)
    {
      int grow = row0 + sr;
      float4 v0 = make_float4(0.f,0.f,0.f,0.f), v1 = v0;
      if (grow < M) {
        const float* ap = A + (size_t)grow * lda + k0 + sc * 8;
        v0 = *reinterpret_cast<const float4*>(ap);
        v1 = *reinterpret_cast<const float4*>(ap + 4);
      }
      bf16x8 t;
      t[0]=f2bf(v0.x); t[1]=f2bf(v0.y); t[2]=f2bf(v0.z); t[3]=f2bf(v0.w);
      t[4]=f2bf(v1.x); t[5]=f2bf(v1.y); t[6]=f2bf(v1.z); t[7]=f2bf(v1.w);
      *reinterpret_cast<bf16x8*>(&As[sr * 40 + sc * 8]) = t;
    }
    __syncthreads();

    bf16x8 af[4], bfr[4];
#pragma unroll
    for (int m = 0; m < 4; ++m)
      af[m] = *reinterpret_cast<bf16x8*>(&As[(wr * 64 + m * 16 + l15) * 40 + l4 * 8]);
#pragma unroll
    for (int n = 0; n < 4; ++n)
      bfr[n] = *reinterpret_cast<bf16x8*>(&Bs[(wc * 64 + n * 16 + l15) * 32 + l4 * 8]);
#pragma unroll
    for (int m = 0; m < 4; ++m)
#pragma unroll
      for (int n = 0; n < 4; ++n)
        acc[m][n] = __builtin_amdgcn_mfma_f32_16x16x32_bf16(af[m], bfr[n], acc[m][n], 0, 0, 0);
    __syncthreads();
  }

#pragma unroll
  for (int n = 0; n < 4; ++n) {
    int col = wc * 64 + n * 16 + l15;
#pragma unroll
    for (int m = 0; m < 4; ++m) {
      int rb = row0 + wr * 64 + m * 16 + l4 * 4;
#pragma unroll
      for (int e = 0; e < 4; ++e) {
        int r = rb + e;
        if (r < M) C[(size_t)r * 256 + col] = f2bf(acc[m][n][e]);
      }
    }
  }
}

// ---------------- fp32 tiled GEMM (small output-path layers) ----------------
__global__ __launch_bounds__(256)
void k_gemm_f32(const float* __restrict__ A, int lda,
                const float* __restrict__ B, int ldb,
                const float* __restrict__ bias,
                float* __restrict__ C, int ldc,
                int M, int Ncol, int K, int do_relu)
{
  __shared__ float As[16][65];
  __shared__ float Bs[16][68];
  const int tid = threadIdx.x;
  const int tx = tid & 15, ty = tid >> 4;
  const int row0 = blockIdx.y * 64;
  const int col0 = blockIdx.x * 64;
  float acc[4][4] = {};
  for (int k0 = 0; k0 < K; k0 += 16) {
    {
      int r = tid >> 2;
      int c = (tid & 3) << 2;
      int grow = row0 + r;
      float4 v = make_float4(0.f, 0.f, 0.f, 0.f);
      if (grow < M)
        v = *reinterpret_cast<const float4*>(A + (size_t)grow * lda + k0 + c);
      As[c + 0][r] = v.x; As[c + 1][r] = v.y; As[c + 2][r] = v.z; As[c + 3][r] = v.w;
    }
    {
      int r = tid >> 4;
      int c = (tid & 15) << 2;
      int gcol = col0 + c;
      float4 v = make_float4(0.f, 0.f, 0.f, 0.f);
      if (gcol < Ncol)
        v = *reinterpret_cast<const float4*>(B + (size_t)(k0 + r) * ldb + gcol);
      *reinterpret_cast<float4*>(&Bs[r][c]) = v;
    }
    __syncthreads();
#pragma unroll
    for (int k = 0; k < 16; ++k) {
      float a[4], b[4];
#pragma unroll
      for (int i = 0; i < 4; ++i) a[i] = As[k][ty + 16 * i];
#pragma unroll
      for (int j = 0; j < 4; ++j) b[j] = Bs[k][tx + 16 * j];
#pragma unroll
      for (int i = 0; i < 4; ++i)
#pragma unroll
        for (int j = 0; j < 4; ++j)
          acc[i][j] = fmaf(a[i], b[j], acc[i][j]);
    }
    __syncthreads();
  }
#pragma unroll
  for (int i = 0; i < 4; ++i) {
    int r = row0 + ty + 16 * i;
    if (r >= M) continue;
#pragma unroll
    for (int j = 0; j < 4; ++j) {
      int ccol = col0 + tx + 16 * j;
      if (ccol >= Ncol) continue;
      float v = acc[i][j];
      if (bias) v += bias[ccol];
      if (do_relu) v = fmaxf(v, 0.f);
      C[(size_t)r * ldc + ccol] = v;
    }
  }
}

extern "C" void kernel_launch(void* const* d_in, const int* in_sizes, int n_in,
                              void* d_out, int out_size, void* d_ws, size_t ws_size,
                              hipStream_t stream) {
  const float* x   = (const float*)d_in[0];
  const int*   ei  = (const int*)d_in[1];
  const float* Wd1 = (const float*)d_in[3];
  const float* bd1 = (const float*)d_in[4];
  const float* Wd2 = (const float*)d_in[5];
  const float* bd2 = (const float*)d_in[6];
  const float* W1  = (const float*)d_in[7];
  const float* b1  = (const float*)d_in[8];
  const float* W2  = (const float*)d_in[9];
  const float* b2  = (const float*)d_in[10];
  const float* Wp1 = (const float*)d_in[11];
  const float* bp1 = (const float*)d_in[12];
  const float* Wp2 = (const float*)d_in[13];
  const float* bp2 = (const float*)d_in[14];
  const float* Wf  = (const float*)d_in[15];
  const float* bf_ = (const float*)d_in[16];
  float* out = (float*)d_out;
  float* ws  = (float*)d_ws;

  // workspace (float offsets), non-overlapping, all 16B-aligned
  short* goidx_bf = (short*)(ws + 0);          // 10000 x 4096 bf16
  short* goidt_bf = (short*)(ws + 20480000);   // 10000 x 1280 bf16
  short* h1tmp_bf = (short*)(ws + 26880000);   // 10000 x 1024 bf16
  short* Wd1t = (short*)(ws + 32000000);       // 1024 x 4096
  short* Wd2t = (short*)(ws + 34097152);       // 1280 x 1024
  short* W1t  = (short*)(ws + 34752512);       //  256 x 1280
  short* Wp1t = (short*)(ws + 34916352);       //  256 x 1280
  short* W2t  = (short*)(ws + 35080192);       //  128 x 256
  short* xw1_bf = (short*)(ws + 35100000);     // 50000 x 256 bf16
  short* h1bf   = (short*)(ws + 41500000);     // 50000 x 256 bf16
  float* p1     = ws + 47900000;               // 10000 x 256 fp32
  short* xw2_bf = (short*)(ws + 50460000);     // 50000 x 128 bf16
  float* h2     = ws + 53660000;               // 50000 x 128 fp32
  float* dinv   = ws + 60060000;               // 50,000
  int*   cnt      = (int*)(ws + 60110016);     // 40,000
  int*   rowstart = (int*)(ws + 60150016);     // 40,000
  int*   cursor   = (int*)(ws + 60190016);     // 40,000
  int*   srcs     = (int*)(ws + 60230016);     // 800,000
  float* norms    = ws + 61030016;             // 800,000
  int*   gcount   = (int*)(ws + 61830016);     // 1

  const float* gene_x = x;                          // rows 0..39999, lda=4096
  const float* goid_x = x + (size_t)kNGene * kGDim; // rows 40000..49999

  auto gb = [](int M, int Ncol) { return dim3((unsigned)(Ncol / 128), (unsigned)((M + 127) / 128)); };
  auto gf = [](int M, int Ncol) { return dim3((unsigned)((Ncol + 63) / 64), (unsigned)((M + 63) / 64)); };

  // 0) converts: goid_x -> bf16; weights -> bf16 transposed
  k_cvt_rows<<<2048, 256, 0, stream>>>(goid_x, kGDim, goidx_bf, kNGoid, kGDim);
  k_wtrans<<<dim3(kD1 / 32, kGDim / 32), 256, 0, stream>>>(Wd1, Wd1t, kGDim, kD1);
  k_wtrans<<<dim3(kInDim / 32, kD1 / 32), 256, 0, stream>>>(Wd2, Wd2t, kD1, kInDim);
  k_wtrans<<<dim3(kH1 / 32, kInDim / 32), 256, 0, stream>>>(W1, W1t, kInDim, kH1);
  k_wtrans<<<dim3(kH1 / 32, kInDim / 32), 256, 0, stream>>>(Wp1, Wp1t, kInDim, kH1);
  k_wtrans<<<dim3(kH2 / 32, kH1 / 32), 256, 0, stream>>>(W2, W2t, kH1, kH2);

  // 1) degrees + CSR (parallel offset assignment)
  k_deg_init<<<(kN + 255) / 256, 256, 0, stream>>>(dinv, gcount);
  k_zero_i<<<(kNGene + 255) / 256, 256, 0, stream>>>(cnt, kNGene);
  k_deg_hist<<<(kE + 255) / 256, 256, 0, stream>>>(ei, dinv, cnt);
  k_rsqrt<<<(kN + 255) / 256, 256, 0, stream>>>(dinv);
  k_rowassign<<<(kNGene + 255) / 256, 256, 0, stream>>>(cnt, rowstart, cursor, gcount);
  k_fill<<<(kE + 255) / 256, 256, 0, stream>>>(ei, dinv, cursor, srcs, norms);

  // 2) GOID MLP (gld16-staged bf16 MFMA)
  k_gemm_bf16a<1,1><<<gb(kNGoid, kD1), 256, 0, stream>>>(goidx_bf, kGDim, Wd1t, bd1,
                                                         h1tmp_bf, kD1, nullptr, kNGoid, kGDim);
  k_gemm_bf16a<1,1><<<gb(kNGoid, kInDim), 256, 0, stream>>>(h1tmp_bf, kD1, Wd2t, bd2,
                                                            goidt_bf, kInDim, nullptr, kNGoid, kD1);

  // 3) xw1 = x_t @ W1 -> bf16 message table (gene: single-pass 128x256 tile)
  k_gemm_gene<<<dim3((kNGene + 127) / 128), 512, 0, stream>>>(gene_x, kGDim, W1t,
                                                              xw1_bf, kNGene, kInDim);
  k_gemm_bf16a<0,1><<<gb(kNGoid, kH1), 256, 0, stream>>>(goidt_bf, kInDim, W1t, nullptr,
                                                         xw1_bf + (size_t)kNGene * kH1, kH1,
                                                         nullptr, kNGoid, kInDim);

  // 4) p1 = goid_t @ Wp1 + bp1 : fp32 p1 + dual bf16 write into h1 goid rows
  k_gemm_bf16a<0,0><<<gb(kNGoid, kH1), 256, 0, stream>>>(goidt_bf, kInDim, Wp1t, bp1,
                                                         p1, kH1,
                                                         h1bf + (size_t)kNGene * kH1,
                                                         kNGoid, kInDim);

  // 5) conv1: gather (bf16 messages) -> h1 bf16 gene rows
  k_gather_bf<kH1,1><<<(kNGene * 64 + 255) / 256, 256, 0, stream>>>(
      xw1_bf, dinv, rowstart, cnt, srcs, norms, b1, h1bf);

  // 6) xw2 = h1 @ W2 -> bf16 message table
  k_gemm_bf16a<0,1><<<gb(kN, kH2), 256, 0, stream>>>(h1bf, kH1, W2t, nullptr,
                                                     xw2_bf, kH2, nullptr, kN, kH1);

  // 7) conv2: gather -> h2 fp32 gene rows; goid rows = p1@Wp2+bp2 (fp32)
  k_gather_bf<kH2,0><<<(kNGene * 64 + 255) / 256, 256, 0, stream>>>(
      xw2_bf, dinv, rowstart, cnt, srcs, norms, b2, h2);
  k_gemm_f32<<<gf(kNGoid, kH2), 256, 0, stream>>>(p1, kH1, Wp2, kH2, bp2,
                                                  h2 + (size_t)kNGene * kH2, kH2,
                                                  kNGoid, kH2, kH1, 0);

  // 8) out = h2 @ Wf + bf
  k_gemm_f32<<<gf(kN, kOut), 256, 0, stream>>>(h2, kH2, Wf, kOut, bf_, out, kOut,
                                               kN, kOut, kH2, 0);
}

// Round 10
// 684.051 us; speedup vs baseline: 1.5273x; 1.1967x over previous
//
#include <hip/hip_runtime.h>

// Problem constants (from reference)
constexpr int kNGene = 40000;
constexpr int kNGoid = 10000;
constexpr int kN     = 50000;
constexpr int kE     = 800000;
constexpr int kInDim = 1280;
constexpr int kH1    = 256;
constexpr int kH2    = 128;
constexpr int kOut   = 64;
constexpr int kGDim  = 4096;
constexpr int kD1    = 1024;

typedef short bf16x8 __attribute__((ext_vector_type(8)));
typedef float f32x4  __attribute__((ext_vector_type(4)));

static __device__ __forceinline__ short f2bf(float f) {
  union { float f; unsigned u; } v; v.f = f;
  unsigned r = v.u + 0x7FFF + ((v.u >> 16) & 1);   // RNE; inputs are finite
  return (short)(r >> 16);
}
static __device__ __forceinline__ float bf2f(short s) {
  union { unsigned u; float f; } v;
  v.u = ((unsigned)(unsigned short)s) << 16;
  return v.f;
}
// async global->LDS, 16B/lane; LDS dest = base + lane*16 (wave-linear).
static __device__ __forceinline__ void gld16(const void* g, void* l) {
  __builtin_amdgcn_global_load_lds(
      (const __attribute__((address_space(1))) void*)g,
      (__attribute__((address_space(3))) void*)l, 16, 0, 0);
}

// ---------------- fp32 -> bf16 row-block convert ----------------
__global__ __launch_bounds__(256)
void k_cvt_rows(const float* __restrict__ src, int lda, short* __restrict__ dst,
                int rows, int cols) {
  int chunks_per_row = cols >> 3;
  long long total = (long long)rows * chunks_per_row;
  long long stride = (long long)gridDim.x * blockDim.x;
  for (long long i = blockIdx.x * (long long)blockDim.x + threadIdx.x; i < total; i += stride) {
    int r = (int)(i / chunks_per_row);
    int c = (int)(i - (long long)r * chunks_per_row) << 3;
    const float* sp = src + (size_t)r * lda + c;
    float4 v0 = *reinterpret_cast<const float4*>(sp);
    float4 v1 = *reinterpret_cast<const float4*>(sp + 4);
    bf16x8 t;
    t[0]=f2bf(v0.x); t[1]=f2bf(v0.y); t[2]=f2bf(v0.z); t[3]=f2bf(v0.w);
    t[4]=f2bf(v1.x); t[5]=f2bf(v1.y); t[6]=f2bf(v1.z); t[7]=f2bf(v1.w);
    *reinterpret_cast<bf16x8*>(dst + (size_t)r * cols + c) = t;
  }
}

// ---------------- degree / CSR ----------------
// deg[i] = 1 (self-loop) + indegree; gene-row edge count = deg-1.
__global__ void k_init(float* deg, int* gcount) {
  int i = blockIdx.x * blockDim.x + threadIdx.x;
  if (i < kN) deg[i] = 1.0f;
  if (i == 0) *gcount = 0;
}
__global__ void k_deg_hist(const int* __restrict__ ei, float* __restrict__ deg) {
  int e = blockIdx.x * blockDim.x + threadIdx.x;
  if (e < kE) atomicAdd(&deg[ei[kE + e]], 1.0f);
}
// parallel segment assignment: wave prefix of (deg-1) + one atomic per wave.
__global__ void k_rowassign(const float* __restrict__ deg, int* __restrict__ rowstart,
                            int* __restrict__ cursor, int* __restrict__ gcount) {
  int i = blockIdx.x * blockDim.x + threadIdx.x;
  int lane = threadIdx.x & 63;
  int c = (i < kNGene) ? ((int)deg[i] - 1) : 0;
  int incl = c;
#pragma unroll
  for (int off = 1; off < 64; off <<= 1) {
    int t = __shfl_up(incl, off, 64);
    if (lane >= off) incl += t;
  }
  int total = __shfl(incl, 63, 64);
  int base = 0;
  if (lane == 63) base = atomicAdd(gcount, total);
  base = __shfl(base, 63, 64);
  if (i < kNGene) {
    int s = base + incl - c;
    rowstart[i] = s;
    cursor[i] = s;
  }
}
// packed edge record: {src, norm_bits}; norm = rsqrt(deg[src]*deg[dst])
__global__ void k_fill(const int* __restrict__ ei, const float* __restrict__ deg,
                       int* __restrict__ cursor, int2* __restrict__ edges) {
  int e = blockIdx.x * blockDim.x + threadIdx.x;
  if (e >= kE) return;
  int dst = ei[kE + e];
  if (dst >= kNGene) return;  // those rows are overwritten later
  int src = ei[e];
  int pos = atomicAdd(&cursor[dst], 1);
  float nrm = rsqrtf(deg[src] * deg[dst]);
  edges[pos] = make_int2(src, __float_as_int(nrm));
}

// ---------------- fused gather aggregation (bf16 messages, packed edges) ----
template <int F, int OBF>
__global__ __launch_bounds__(256)
void k_gather_bf(const short* __restrict__ xw, const float* __restrict__ deg,
                 const int* __restrict__ rowstart, const int2* __restrict__ edges,
                 const float* __restrict__ bias, void* __restrict__ hv) {
  constexpr int VEC = F / 64;
  int row = (blockIdx.x * blockDim.x + threadIdx.x) >> 6;
  int lane = threadIdx.x & 63;
  if (row >= kNGene) return;
  float dg = deg[row];
  float inv = 1.0f / dg;
  float acc[VEC];
  {
    const short* xr = xw + (size_t)row * F + lane * VEC;
    if constexpr (VEC == 4) {
      short4 s = *reinterpret_cast<const short4*>(xr);
      acc[0] = bf2f(s.x) * inv; acc[1] = bf2f(s.y) * inv;
      acc[2] = bf2f(s.z) * inv; acc[3] = bf2f(s.w) * inv;
    } else {
      short2 s = *reinterpret_cast<const short2*>(xr);
      acc[0] = bf2f(s.x) * inv; acc[1] = bf2f(s.y) * inv;
    }
  }
  const int2* ep = edges + rowstart[row];
  int n = (int)dg - 1;
  int e = 0;
  for (; e + 1 < n; e += 2) {   // unroll-2: two row loads in flight
    int2 p0 = ep[e], p1 = ep[e + 1];
    float n0 = __int_as_float(p0.y), n1 = __int_as_float(p1.y);
    const short* x0 = xw + (size_t)p0.x * F + lane * VEC;
    const short* x1 = xw + (size_t)p1.x * F + lane * VEC;
    if constexpr (VEC == 4) {
      short4 s0 = *reinterpret_cast<const short4*>(x0);
      short4 s1 = *reinterpret_cast<const short4*>(x1);
      acc[0] += bf2f(s0.x) * n0; acc[1] += bf2f(s0.y) * n0;
      acc[2] += bf2f(s0.z) * n0; acc[3] += bf2f(s0.w) * n0;
      acc[0] += bf2f(s1.x) * n1; acc[1] += bf2f(s1.y) * n1;
      acc[2] += bf2f(s1.z) * n1; acc[3] += bf2f(s1.w) * n1;
    } else {
      short2 s0 = *reinterpret_cast<const short2*>(x0);
      short2 s1 = *reinterpret_cast<const short2*>(x1);
      acc[0] += bf2f(s0.x) * n0; acc[1] += bf2f(s0.y) * n0;
      acc[0] += bf2f(s1.x) * n1; acc[1] += bf2f(s1.y) * n1;
    }
  }
  if (e < n) {
    int2 p0 = ep[e];
    float n0 = __int_as_float(p0.y);
    const short* x0 = xw + (size_t)p0.x * F + lane * VEC;
    if constexpr (VEC == 4) {
      short4 s0 = *reinterpret_cast<const short4*>(x0);
      acc[0] += bf2f(s0.x) * n0; acc[1] += bf2f(s0.y) * n0;
      acc[2] += bf2f(s0.z) * n0; acc[3] += bf2f(s0.w) * n0;
    } else {
      short2 s0 = *reinterpret_cast<const short2*>(x0);
      acc[0] += bf2f(s0.x) * n0; acc[1] += bf2f(s0.y) * n0;
    }
  }
#pragma unroll
  for (int v = 0; v < VEC; ++v) acc[v] = fmaxf(acc[v] + bias[lane * VEC + v], 0.f);
  if constexpr (OBF) {
    short* hp = (short*)hv + (size_t)row * F + lane * VEC;
    if constexpr (VEC == 4) {
      short4 o; o.x = f2bf(acc[0]); o.y = f2bf(acc[1]); o.z = f2bf(acc[2]); o.w = f2bf(acc[3]);
      *reinterpret_cast<short4*>(hp) = o;
    } else {
      short2 o; o.x = f2bf(acc[0]); o.y = f2bf(acc[1]);
      *reinterpret_cast<short2*>(hp) = o;
    }
  } else {
    float* hp = (float*)hv + (size_t)row * F + lane * VEC;
    if constexpr (VEC == 4) {
      float4 o; o.x = acc[0]; o.y = acc[1]; o.z = acc[2]; o.w = acc[3];
      *reinterpret_cast<float4*>(hp) = o;
    } else {
      float2 o; o.x = acc[0]; o.y = acc[1];
      *reinterpret_cast<float2*>(hp) = o;
    }
  }
}

// ---------------- weight transpose fp32[K][N] -> bf16[N][K] ----------------
__global__ __launch_bounds__(256)
void k_wtrans(const float* __restrict__ W, short* __restrict__ Wt, int K, int N) {
  __shared__ float t[32][33];
  int tx = threadIdx.x & 31, ty = threadIdx.x >> 5;  // 32 x 8
  int n0 = blockIdx.x * 32, k0 = blockIdx.y * 32;
#pragma unroll
  for (int p = 0; p < 4; ++p)
    t[ty + 8 * p][tx] = W[(size_t)(k0 + ty + 8 * p) * N + n0 + tx];
  __syncthreads();
#pragma unroll
  for (int p = 0; p < 4; ++p)
    Wt[(size_t)(n0 + ty + 8 * p) * K + k0 + tx] = f2bf(t[tx][ty + 8 * p]);
}

// ---------------- bf16 MFMA GEMM, gld16 + 2-phase prefetch double-buffer ----
// C[M,N] = A[M,K] @ B ; A bf16 stride lda, Bt bf16 [N][K].
// N %128==0, K %32==0. Tile 128x128, BK=32, 4 waves, LDS linear [row][32].
template <int RELU, int OBF>
__global__ __launch_bounds__(256)
void k_gemm_bf16a(const short* __restrict__ A, int lda,
                  const short* __restrict__ Bt,
                  const float* __restrict__ bias,
                  void* __restrict__ Cv, int ldc,
                  short* __restrict__ C2,
                  int M, int K)
{
  __shared__ __align__(16) short As[2][128 * 32];
  __shared__ __align__(16) short Bs[2][128 * 32];
  const int tid  = threadIdx.x;
  const int lane = tid & 63;
  const int wid  = tid >> 6;
  const int wr = wid >> 1, wc = wid & 1;
  const int row0 = blockIdx.y * 128;
  const int col0 = blockIdx.x * 128;
  const int l15 = lane & 15, l4 = lane >> 4;
  const int srow = lane >> 2, schunk = lane & 3;

  f32x4 acc[4][4] = {};

  auto stage = [&](int buf, int k0) {
#pragma unroll
    for (int q = 0; q < 2; ++q) {
      int seg = wid * 2 + q;                // 0..7
      int r = seg * 16 + srow;
      int grow = row0 + r;
      if (grow >= M) grow = M - 1;          // duplicate; epilogue masks
      gld16(A + (size_t)grow * lda + k0 + schunk * 8, &As[buf][seg * 512]);
      int gcol = col0 + r;                  // N%128==0: in range
      gld16(Bt + (size_t)gcol * K + k0 + schunk * 8, &Bs[buf][seg * 512]);
    }
  };

  stage(0, 0);
  __syncthreads();
  int cur = 0;
  for (int k0 = 0; k0 < K; k0 += 32) {
    if (k0 + 32 < K) stage(cur ^ 1, k0 + 32);   // loads fly during MFMA phase
    bf16x8 af[4], bfr[4];
#pragma unroll
    for (int m = 0; m < 4; ++m)
      af[m] = *reinterpret_cast<bf16x8*>(&As[cur][(wr * 64 + m * 16 + l15) * 32 + l4 * 8]);
#pragma unroll
    for (int n = 0; n < 4; ++n)
      bfr[n] = *reinterpret_cast<bf16x8*>(&Bs[cur][(wc * 64 + n * 16 + l15) * 32 + l4 * 8]);
#pragma unroll
    for (int m = 0; m < 4; ++m)
#pragma unroll
      for (int n = 0; n < 4; ++n)
        acc[m][n] = __builtin_amdgcn_mfma_f32_16x16x32_bf16(af[m], bfr[n], acc[m][n], 0, 0, 0);
    __syncthreads();   // drains vmcnt(0): prefetch buffer ready; reads of cur done
    cur ^= 1;
  }

#pragma unroll
  for (int n = 0; n < 4; ++n) {
    int col = col0 + wc * 64 + n * 16 + l15;
    float bv = bias ? bias[col] : 0.f;
#pragma unroll
    for (int m = 0; m < 4; ++m) {
      int rb = row0 + wr * 64 + m * 16 + l4 * 4;
#pragma unroll
      for (int e = 0; e < 4; ++e) {
        int r = rb + e;
        if (r < M) {
          float v = acc[m][n][e] + bv;
          if (RELU) v = fmaxf(v, 0.f);
          size_t idx = (size_t)r * ldc + col;
          if constexpr (OBF) ((short*)Cv)[idx] = f2bf(v);
          else {
            ((float*)Cv)[idx] = v;
            if (C2) C2[idx] = f2bf(v);
          }
        }
      }
    }
  }
}

// ---------------- combined goid GEMM: [xw1_goid | p1] in one pass ----------
// A = goidt [10000][1280] bf16; Bt = [512][1280] (W1t rows 0-255, Wp1t 256-511).
// col-tile < 256 -> X1 bf16 (no bias); col-tile >= 256 -> P1 fp32 + H1 bf16, +bp1.
__global__ __launch_bounds__(256)
void k_gemm_combo(const short* __restrict__ A, int lda,
                  const short* __restrict__ Bt,
                  const float* __restrict__ bp1,
                  short* __restrict__ X1, float* __restrict__ P1,
                  short* __restrict__ H1, int M, int K)
{
  __shared__ __align__(16) short As[2][128 * 32];
  __shared__ __align__(16) short Bs[2][128 * 32];
  const int tid  = threadIdx.x;
  const int lane = tid & 63;
  const int wid  = tid >> 6;
  const int wr = wid >> 1, wc = wid & 1;
  const int row0 = blockIdx.y * 128;
  const int col0 = blockIdx.x * 128;
  const int l15 = lane & 15, l4 = lane >> 4;
  const int srow = lane >> 2, schunk = lane & 3;

  f32x4 acc[4][4] = {};

  auto stage = [&](int buf, int k0) {
#pragma unroll
    for (int q = 0; q < 2; ++q) {
      int seg = wid * 2 + q;
      int r = seg * 16 + srow;
      int grow = row0 + r;
      if (grow >= M) grow = M - 1;
      gld16(A + (size_t)grow * lda + k0 + schunk * 8, &As[buf][seg * 512]);
      int gcol = col0 + r;
      gld16(Bt + (size_t)gcol * K + k0 + schunk * 8, &Bs[buf][seg * 512]);
    }
  };

  stage(0, 0);
  __syncthreads();
  int cur = 0;
  for (int k0 = 0; k0 < K; k0 += 32) {
    if (k0 + 32 < K) stage(cur ^ 1, k0 + 32);
    bf16x8 af[4], bfr[4];
#pragma unroll
    for (int m = 0; m < 4; ++m)
      af[m] = *reinterpret_cast<bf16x8*>(&As[cur][(wr * 64 + m * 16 + l15) * 32 + l4 * 8]);
#pragma unroll
    for (int n = 0; n < 4; ++n)
      bfr[n] = *reinterpret_cast<bf16x8*>(&Bs[cur][(wc * 64 + n * 16 + l15) * 32 + l4 * 8]);
#pragma unroll
    for (int m = 0; m < 4; ++m)
#pragma unroll
      for (int n = 0; n < 4; ++n)
        acc[m][n] = __builtin_amdgcn_mfma_f32_16x16x32_bf16(af[m], bfr[n], acc[m][n], 0, 0, 0);
    __syncthreads();
    cur ^= 1;
  }

  const int is_p1 = (col0 >= 256);   // block-uniform (128 | 256)
#pragma unroll
  for (int n = 0; n < 4; ++n) {
    int col = col0 + wc * 64 + n * 16 + l15;
    int cl = col - (is_p1 ? 256 : 0);
    float bv = is_p1 ? bp1[cl] : 0.f;
#pragma unroll
    for (int m = 0; m < 4; ++m) {
      int rb = row0 + wr * 64 + m * 16 + l4 * 4;
#pragma unroll
      for (int e = 0; e < 4; ++e) {
        int r = rb + e;
        if (r < M) {
          float v = acc[m][n][e] + bv;
          size_t idx = (size_t)r * 256 + cl;
          if (is_p1) { P1[idx] = v; H1[idx] = f2bf(v); }
          else       { X1[idx] = f2bf(v); }
        }
      }
    }
  }
}

// ---------------- gene xw1: fp32-A single-pass, tile 128x256, 8 waves -------
__global__ __launch_bounds__(512)
void k_gemm_gene(const float* __restrict__ A, int lda,
                 const short* __restrict__ Bt,
                 short* __restrict__ C,   // [M][256] bf16
                 int M, int K)
{
  __shared__ short As[128 * 40];                 // pad-40
  __shared__ __align__(16) short Bs[256 * 32];   // linear [col][32]
  const int tid  = threadIdx.x;
  const int lane = tid & 63;
  const int wid  = tid >> 6;        // 0..7
  const int wr = wid >> 2;          // 0..1
  const int wc = wid & 3;           // 0..3
  const int row0 = blockIdx.x * 128;
  const int l15 = lane & 15, l4 = lane >> 4;

  f32x4 acc[4][4] = {};
  const int sr = tid >> 2;
  const int sc = tid & 3;
  const int srow = lane >> 2, schunk = lane & 3;

  for (int k0 = 0; k0 < K; k0 += 32) {
#pragma unroll
    for (int q = 0; q < 2; ++q) {
      int seg = wid * 2 + q;              // 0..15
      int gcol = seg * 16 + srow;
      gld16(Bt + (size_t)gcol * K + k0 + schunk * 8, &Bs[seg * 512]);
    }
    {
      int grow = row0 + sr;
      float4 v0 = make_float4(0.f,0.f,0.f,0.f), v1 = v0;
      if (grow < M) {
        const float* ap = A + (size_t)grow * lda + k0 + sc * 8;
        v0 = *reinterpret_cast<const float4*>(ap);
        v1 = *reinterpret_cast<const float4*>(ap + 4);
      }
      bf16x8 t;
      t[0]=f2bf(v0.x); t[1]=f2bf(v0.y); t[2]=f2bf(v0.z); t[3]=f2bf(v0.w);
      t[4]=f2bf(v1.x); t[5]=f2bf(v1.y); t[6]=f2bf(v1.z); t[7]=f2bf(v1.w);
      *reinterpret_cast<bf16x8*>(&As[sr * 40 + sc * 8]) = t;
    }
    __syncthreads();

    bf16x8 af[4], bfr[4];
#pragma unroll
    for (int m = 0; m < 4; ++m)
      af[m] = *reinterpret_cast<bf16x8*>(&As[(wr * 64 + m * 16 + l15) * 40 + l4 * 8]);
#pragma unroll
    for (int n = 0; n < 4; ++n)
      bfr[n] = *reinterpret_cast<bf16x8*>(&Bs[(wc * 64 + n * 16 + l15) * 32 + l4 * 8]);
#pragma unroll
    for (int m = 0; m < 4; ++m)
#pragma unroll
      for (int n = 0; n < 4; ++n)
        acc[m][n] = __builtin_amdgcn_mfma_f32_16x16x32_bf16(af[m], bfr[n], acc[m][n], 0, 0, 0);
    __syncthreads();
  }

#pragma unroll
  for (int n = 0; n < 4; ++n) {
    int col = wc * 64 + n * 16 + l15;
#pragma unroll
    for (int m = 0; m < 4; ++m) {
      int rb = row0 + wr * 64 + m * 16 + l4 * 4;
#pragma unroll
      for (int e = 0; e < 4; ++e) {
        int r = rb + e;
        if (r < M) C[(size_t)r * 256 + col] = f2bf(acc[m][n][e]);
      }
    }
  }
}

// ---------------- fp32 tiled GEMM (small output-path layers) ----------------
__global__ __launch_bounds__(256)
void k_gemm_f32(const float* __restrict__ A, int lda,
                const float* __restrict__ B, int ldb,
                const float* __restrict__ bias,
                float* __restrict__ C, int ldc,
                int M, int Ncol, int K, int do_relu)
{
  __shared__ float As[16][65];
  __shared__ float Bs[16][68];
  const int tid = threadIdx.x;
  const int tx = tid & 15, ty = tid >> 4;
  const int row0 = blockIdx.y * 64;
  const int col0 = blockIdx.x * 64;
  float acc[4][4] = {};
  for (int k0 = 0; k0 < K; k0 += 16) {
    {
      int r = tid >> 2;
      int c = (tid & 3) << 2;
      int grow = row0 + r;
      float4 v = make_float4(0.f, 0.f, 0.f, 0.f);
      if (grow < M)
        v = *reinterpret_cast<const float4*>(A + (size_t)grow * lda + k0 + c);
      As[c + 0][r] = v.x; As[c + 1][r] = v.y; As[c + 2][r] = v.z; As[c + 3][r] = v.w;
    }
    {
      int r = tid >> 4;
      int c = (tid & 15) << 2;
      int gcol = col0 + c;
      float4 v = make_float4(0.f, 0.f, 0.f, 0.f);
      if (gcol < Ncol)
        v = *reinterpret_cast<const float4*>(B + (size_t)(k0 + r) * ldb + gcol);
      *reinterpret_cast<float4*>(&Bs[r][c]) = v;
    }
    __syncthreads();
#pragma unroll
    for (int k = 0; k < 16; ++k) {
      float a[4], b[4];
#pragma unroll
      for (int i = 0; i < 4; ++i) a[i] = As[k][ty + 16 * i];
#pragma unroll
      for (int j = 0; j < 4; ++j) b[j] = Bs[k][tx + 16 * j];
#pragma unroll
      for (int i = 0; i < 4; ++i)
#pragma unroll
        for (int j = 0; j < 4; ++j)
          acc[i][j] = fmaf(a[i], b[j], acc[i][j]);
    }
    __syncthreads();
  }
#pragma unroll
  for (int i = 0; i < 4; ++i) {
    int r = row0 + ty + 16 * i;
    if (r >= M) continue;
#pragma unroll
    for (int j = 0; j < 4; ++j) {
      int ccol = col0 + tx + 16 * j;
      if (ccol >= Ncol) continue;
      float v = acc[i][j];
      if (bias) v += bias[ccol];
      if (do_relu) v = fmaxf(v, 0.f);
      C[(size_t)r * ldc + ccol] = v;
    }
  }
}

extern "C" void kernel_launch(void* const* d_in, const int* in_sizes, int n_in,
                              void* d_out, int out_size, void* d_ws, size_t ws_size,
                              hipStream_t stream) {
  const float* x   = (const float*)d_in[0];
  const int*   ei  = (const int*)d_in[1];
  const float* Wd1 = (const float*)d_in[3];
  const float* bd1 = (const float*)d_in[4];
  const float* Wd2 = (const float*)d_in[5];
  const float* bd2 = (const float*)d_in[6];
  const float* W1  = (const float*)d_in[7];
  const float* b1  = (const float*)d_in[8];
  const float* W2  = (const float*)d_in[9];
  const float* b2  = (const float*)d_in[10];
  const float* Wp1 = (const float*)d_in[11];
  const float* bp1 = (const float*)d_in[12];
  const float* Wp2 = (const float*)d_in[13];
  const float* bp2 = (const float*)d_in[14];
  const float* Wf  = (const float*)d_in[15];
  const float* bf_ = (const float*)d_in[16];
  float* out = (float*)d_out;
  float* ws  = (float*)d_ws;

  // workspace (float offsets), non-overlapping, 16B-aligned
  short* goidx_bf = (short*)(ws + 0);          // 10000 x 4096 bf16
  short* goidt_bf = (short*)(ws + 20480000);   // 10000 x 1280 bf16
  short* h1tmp_bf = (short*)(ws + 26880000);   // 10000 x 1024 bf16
  short* Wd1t = (short*)(ws + 32000000);       // 1024 x 4096
  short* Wd2t = (short*)(ws + 34097152);       // 1280 x 1024
  short* W1t  = (short*)(ws + 34752512);       //  256 x 1280 \ contiguous ->
  short* Wp1t = (short*)(ws + 34916352);       //  256 x 1280 / Wcomb[512][1280]
  short* W2t  = (short*)(ws + 35080192);       //  128 x 256
  short* xw1_bf = (short*)(ws + 35100000);     // 50000 x 256 bf16
  short* h1bf   = (short*)(ws + 41500000);     // 50000 x 256 bf16
  float* p1     = ws + 47900000;               // 10000 x 256 fp32
  short* xw2_bf = (short*)(ws + 50460000);     // 50000 x 128 bf16
  float* h2     = ws + 53660000;               // 50000 x 128 fp32
  float* deg    = ws + 60060000;               // 50,000
  int*   rowstart = (int*)(ws + 60150016);     // 40,000
  int*   cursor   = (int*)(ws + 60190016);     // 40,000
  int2*  edges    = (int2*)(ws + 60230016);    // 800,000 x 8B
  int*   gcount   = (int*)(ws + 61830016);     // 1

  const float* gene_x = x;                          // rows 0..39999, lda=4096
  const float* goid_x = x + (size_t)kNGene * kGDim; // rows 40000..49999

  auto gb = [](int M, int Ncol) { return dim3((unsigned)(Ncol / 128), (unsigned)((M + 127) / 128)); };
  auto gf = [](int M, int Ncol) { return dim3((unsigned)((Ncol + 63) / 64), (unsigned)((M + 63) / 64)); };

  // 0) converts: goid_x -> bf16; weights -> bf16 transposed
  k_cvt_rows<<<2048, 256, 0, stream>>>(goid_x, kGDim, goidx_bf, kNGoid, kGDim);
  k_wtrans<<<dim3(kD1 / 32, kGDim / 32), 256, 0, stream>>>(Wd1, Wd1t, kGDim, kD1);
  k_wtrans<<<dim3(kInDim / 32, kD1 / 32), 256, 0, stream>>>(Wd2, Wd2t, kD1, kInDim);
  k_wtrans<<<dim3(kH1 / 32, kInDim / 32), 256, 0, stream>>>(W1, W1t, kInDim, kH1);
  k_wtrans<<<dim3(kH1 / 32, kInDim / 32), 256, 0, stream>>>(Wp1, Wp1t, kInDim, kH1);
  k_wtrans<<<dim3(kH2 / 32, kH1 / 32), 256, 0, stream>>>(W2, W2t, kH1, kH2);

  // 1) degrees + CSR (cnt == deg-1 identity; packed edges)
  k_init<<<(kN + 255) / 256, 256, 0, stream>>>(deg, gcount);
  k_deg_hist<<<(kE + 255) / 256, 256, 0, stream>>>(ei, deg);
  k_rowassign<<<(kNGene + 255) / 256, 256, 0, stream>>>(deg, rowstart, cursor, gcount);
  k_fill<<<(kE + 255) / 256, 256, 0, stream>>>(ei, deg, cursor, edges);

  // 2) GOID MLP (gld16 + 2-phase dbuf)
  k_gemm_bf16a<1,1><<<gb(kNGoid, kD1), 256, 0, stream>>>(goidx_bf, kGDim, Wd1t, bd1,
                                                         h1tmp_bf, kD1, nullptr, kNGoid, kGDim);
  k_gemm_bf16a<1,1><<<gb(kNGoid, kInDim), 256, 0, stream>>>(h1tmp_bf, kD1, Wd2t, bd2,
                                                            goidt_bf, kInDim, nullptr, kNGoid, kD1);

  // 3) gene xw1 (single pass over gene_x)
  k_gemm_gene<<<dim3((kNGene + 127) / 128), 512, 0, stream>>>(gene_x, kGDim, W1t,
                                                              xw1_bf, kNGene, kInDim);

  // 4) combined goid GEMM: xw1 goid rows + p1 (+ h1 goid rows) in one pass
  k_gemm_combo<<<dim3(4, (kNGoid + 127) / 128), 256, 0, stream>>>(
      goidt_bf, kInDim, W1t /*=Wcomb[512][1280]*/, bp1,
      xw1_bf + (size_t)kNGene * kH1, p1, h1bf + (size_t)kNGene * kH1,
      kNGoid, kInDim);

  // 5) conv1: gather -> h1 bf16 gene rows
  k_gather_bf<kH1,1><<<(kNGene * 64 + 255) / 256, 256, 0, stream>>>(
      xw1_bf, deg, rowstart, edges, b1, h1bf);

  // 6) xw2 = h1 @ W2 -> bf16 message table
  k_gemm_bf16a<0,1><<<gb(kN, kH2), 256, 0, stream>>>(h1bf, kH1, W2t, nullptr,
                                                     xw2_bf, kH2, nullptr, kN, kH1);

  // 7) conv2: gather -> h2 fp32 gene rows; goid rows = p1@Wp2+bp2
  k_gather_bf<kH2,0><<<(kNGene * 64 + 255) / 256, 256, 0, stream>>>(
      xw2_bf, deg, rowstart, edges, b2, h2);
  k_gemm_f32<<<gf(kNGoid, kH2), 256, 0, stream>>>(p1, kH1, Wp2, kH2, bp2,
                                                  h2 + (size_t)kNGene * kH2, kH2,
                                                  kNGoid, kH2, kH1, 0);

  // 8) out = h2 @ Wf + bf
  k_gemm_f32<<<gf(kN, kOut), 256, 0, stream>>>(h2, kH2, Wf, kOut, bf_, out, kOut,
                                               kN, kOut, kH2, 0);
}

// Round 11
// 610.647 us; speedup vs baseline: 1.7109x; 1.1202x over previous
//
#include <hip/hip_runtime.h>

// Problem constants (from reference)
constexpr int kNGene = 40000;
constexpr int kNGoid = 10000;
constexpr int kN     = 50000;
constexpr int kE     = 800000;
constexpr int kInDim = 1280;
constexpr int kH1    = 256;
constexpr int kH2    = 128;
constexpr int kOut   = 64;
constexpr int kGDim  = 4096;
constexpr int kD1    = 1024;

typedef short bf16x8 __attribute__((ext_vector_type(8)));
typedef float f32x4  __attribute__((ext_vector_type(4)));

static __device__ __forceinline__ short f2bf(float f) {
  union { float f; unsigned u; } v; v.f = f;
  unsigned r = v.u + 0x7FFF + ((v.u >> 16) & 1);   // RNE; inputs are finite
  return (short)(r >> 16);
}
static __device__ __forceinline__ float bf2f(short s) {
  union { unsigned u; float f; } v;
  v.u = ((unsigned)(unsigned short)s) << 16;
  return v.f;
}
// async global->LDS, 16B/lane; LDS dest = base + lane*16 (wave-linear).
static __device__ __forceinline__ void gld16(const void* g, void* l) {
  __builtin_amdgcn_global_load_lds(
      (const __attribute__((address_space(1))) void*)g,
      (__attribute__((address_space(3))) void*)l, 16, 0, 0);
}

// ---------------- fp32 -> bf16 row-block convert ----------------
__global__ __launch_bounds__(256)
void k_cvt_rows(const float* __restrict__ src, int lda, short* __restrict__ dst,
                int rows, int cols) {
  int chunks_per_row = cols >> 3;
  long long total = (long long)rows * chunks_per_row;
  long long stride = (long long)gridDim.x * blockDim.x;
  for (long long i = blockIdx.x * (long long)blockDim.x + threadIdx.x; i < total; i += stride) {
    int r = (int)(i / chunks_per_row);
    int c = (int)(i - (long long)r * chunks_per_row) << 3;
    const float* sp = src + (size_t)r * lda + c;
    float4 v0 = *reinterpret_cast<const float4*>(sp);
    float4 v1 = *reinterpret_cast<const float4*>(sp + 4);
    bf16x8 t;
    t[0]=f2bf(v0.x); t[1]=f2bf(v0.y); t[2]=f2bf(v0.z); t[3]=f2bf(v0.w);
    t[4]=f2bf(v1.x); t[5]=f2bf(v1.y); t[6]=f2bf(v1.z); t[7]=f2bf(v1.w);
    *reinterpret_cast<bf16x8*>(dst + (size_t)r * cols + c) = t;
  }
}

// ---------------- degree / CSR ----------------
__global__ void k_init(float* deg, int* gcount) {
  int i = blockIdx.x * blockDim.x + threadIdx.x;
  if (i < kN) deg[i] = 1.0f;
  if (i == 0) *gcount = 0;
}
__global__ void k_deg_hist(const int* __restrict__ ei, float* __restrict__ deg) {
  int e = blockIdx.x * blockDim.x + threadIdx.x;
  if (e < kE) atomicAdd(&deg[ei[kE + e]], 1.0f);
}
__global__ void k_rowassign(const float* __restrict__ deg, int* __restrict__ rowstart,
                            int* __restrict__ cursor, int* __restrict__ gcount) {
  int i = blockIdx.x * blockDim.x + threadIdx.x;
  int lane = threadIdx.x & 63;
  int c = (i < kNGene) ? ((int)deg[i] - 1) : 0;
  int incl = c;
#pragma unroll
  for (int off = 1; off < 64; off <<= 1) {
    int t = __shfl_up(incl, off, 64);
    if (lane >= off) incl += t;
  }
  int total = __shfl(incl, 63, 64);
  int base = 0;
  if (lane == 63) base = atomicAdd(gcount, total);
  base = __shfl(base, 63, 64);
  if (i < kNGene) {
    int s = base + incl - c;
    rowstart[i] = s;
    cursor[i] = s;
  }
}
__global__ void k_fill(const int* __restrict__ ei, const float* __restrict__ deg,
                       int* __restrict__ cursor, int2* __restrict__ edges) {
  int e = blockIdx.x * blockDim.x + threadIdx.x;
  if (e >= kE) return;
  int dst = ei[kE + e];
  if (dst >= kNGene) return;
  int src = ei[e];
  int pos = atomicAdd(&cursor[dst], 1);
  float nrm = rsqrtf(deg[src] * deg[dst]);
  edges[pos] = make_int2(src, __float_as_int(nrm));
}

// ---------------- fused gather aggregation (bf16 messages, packed edges) ----
template <int F, int OBF>
__global__ __launch_bounds__(256)
void k_gather_bf(const short* __restrict__ xw, const float* __restrict__ deg,
                 const int* __restrict__ rowstart, const int2* __restrict__ edges,
                 const float* __restrict__ bias, void* __restrict__ hv) {
  constexpr int VEC = F / 64;
  int row = (blockIdx.x * blockDim.x + threadIdx.x) >> 6;
  int lane = threadIdx.x & 63;
  if (row >= kNGene) return;
  float dg = deg[row];
  float inv = 1.0f / dg;
  float acc[VEC];
  {
    const short* xr = xw + (size_t)row * F + lane * VEC;
    if constexpr (VEC == 4) {
      short4 s = *reinterpret_cast<const short4*>(xr);
      acc[0] = bf2f(s.x) * inv; acc[1] = bf2f(s.y) * inv;
      acc[2] = bf2f(s.z) * inv; acc[3] = bf2f(s.w) * inv;
    } else {
      short2 s = *reinterpret_cast<const short2*>(xr);
      acc[0] = bf2f(s.x) * inv; acc[1] = bf2f(s.y) * inv;
    }
  }
  const int2* ep = edges + rowstart[row];
  int n = (int)dg - 1;
  int e = 0;
  for (; e + 1 < n; e += 2) {
    int2 p0 = ep[e], p1 = ep[e + 1];
    float n0 = __int_as_float(p0.y), n1 = __int_as_float(p1.y);
    const short* x0 = xw + (size_t)p0.x * F + lane * VEC;
    const short* x1 = xw + (size_t)p1.x * F + lane * VEC;
    if constexpr (VEC == 4) {
      short4 s0 = *reinterpret_cast<const short4*>(x0);
      short4 s1 = *reinterpret_cast<const short4*>(x1);
      acc[0] += bf2f(s0.x) * n0; acc[1] += bf2f(s0.y) * n0;
      acc[2] += bf2f(s0.z) * n0; acc[3] += bf2f(s0.w) * n0;
      acc[0] += bf2f(s1.x) * n1; acc[1] += bf2f(s1.y) * n1;
      acc[2] += bf2f(s1.z) * n1; acc[3] += bf2f(s1.w) * n1;
    } else {
      short2 s0 = *reinterpret_cast<const short2*>(x0);
      short2 s1 = *reinterpret_cast<const short2*>(x1);
      acc[0] += bf2f(s0.x) * n0; acc[1] += bf2f(s0.y) * n0;
      acc[0] += bf2f(s1.x) * n1; acc[1] += bf2f(s1.y) * n1;
    }
  }
  if (e < n) {
    int2 p0 = ep[e];
    float n0 = __int_as_float(p0.y);
    const short* x0 = xw + (size_t)p0.x * F + lane * VEC;
    if constexpr (VEC == 4) {
      short4 s0 = *reinterpret_cast<const short4*>(x0);
      acc[0] += bf2f(s0.x) * n0; acc[1] += bf2f(s0.y) * n0;
      acc[2] += bf2f(s0.z) * n0; acc[3] += bf2f(s0.w) * n0;
    } else {
      short2 s0 = *reinterpret_cast<const short2*>(x0);
      acc[0] += bf2f(s0.x) * n0; acc[1] += bf2f(s0.y) * n0;
    }
  }
#pragma unroll
  for (int v = 0; v < VEC; ++v) acc[v] = fmaxf(acc[v] + bias[lane * VEC + v], 0.f);
  if constexpr (OBF) {
    short* hp = (short*)hv + (size_t)row * F + lane * VEC;
    if constexpr (VEC == 4) {
      short4 o; o.x = f2bf(acc[0]); o.y = f2bf(acc[1]); o.z = f2bf(acc[2]); o.w = f2bf(acc[3]);
      *reinterpret_cast<short4*>(hp) = o;
    } else {
      short2 o; o.x = f2bf(acc[0]); o.y = f2bf(acc[1]);
      *reinterpret_cast<short2*>(hp) = o;
    }
  } else {
    float* hp = (float*)hv + (size_t)row * F + lane * VEC;
    if constexpr (VEC == 4) {
      float4 o; o.x = acc[0]; o.y = acc[1]; o.z = acc[2]; o.w = acc[3];
      *reinterpret_cast<float4*>(hp) = o;
    } else {
      float2 o; o.x = acc[0]; o.y = acc[1];
      *reinterpret_cast<float2*>(hp) = o;
    }
  }
}

// ---------------- batched weight transposes (one launch) --------------------
// fp32[K][N] -> bf16[N][K] for all six weights.
__global__ __launch_bounds__(256)
void k_wtrans_all(const float* __restrict__ Wd1, short* __restrict__ Wd1t,
                  const float* __restrict__ Wd2, short* __restrict__ Wd2t,
                  const float* __restrict__ W1,  short* __restrict__ W1t,
                  const float* __restrict__ Wp1, short* __restrict__ Wp1t,
                  const float* __restrict__ W2,  short* __restrict__ W2t,
                  const float* __restrict__ Wp2, short* __restrict__ Wp2t) {
  __shared__ float t[32][33];
  int b = blockIdx.x;
  const float* W; short* Wt; int K, N, bi;
  if (b < 4096)      { W = Wd1; Wt = Wd1t; K = 4096; N = 1024; bi = b; }
  else if (b < 5376) { W = Wd2; Wt = Wd2t; K = 1024; N = 1280; bi = b - 4096; }
  else if (b < 5696) { W = W1;  Wt = W1t;  K = 1280; N = 256;  bi = b - 5376; }
  else if (b < 6016) { W = Wp1; Wt = Wp1t; K = 1280; N = 256;  bi = b - 5696; }
  else if (b < 6048) { W = W2;  Wt = W2t;  K = 256;  N = 128;  bi = b - 6016; }
  else               { W = Wp2; Wt = Wp2t; K = 256;  N = 128;  bi = b - 6048; }
  int nbx = N >> 5;
  int n0 = (bi % nbx) * 32, k0 = (bi / nbx) * 32;
  int tx = threadIdx.x & 31, ty = threadIdx.x >> 5;
#pragma unroll
  for (int p = 0; p < 4; ++p)
    t[ty + 8 * p][tx] = W[(size_t)(k0 + ty + 8 * p) * N + n0 + tx];
  __syncthreads();
#pragma unroll
  for (int p = 0; p < 4; ++p)
    Wt[(size_t)(n0 + ty + 8 * p) * K + k0 + tx] = f2bf(t[tx][ty + 8 * p]);
}

// ---------------- bf16 MFMA GEMM, 128x128 tile, gld16 + dbuf ----------------
template <int RELU, int OBF>
__global__ __launch_bounds__(256)
void k_gemm_bf16a(const short* __restrict__ A, int lda,
                  const short* __restrict__ Bt,
                  const float* __restrict__ bias,
                  void* __restrict__ Cv, int ldc,
                  int M, int K)
{
  __shared__ __align__(16) short As[2][128 * 32];
  __shared__ __align__(16) short Bs[2][128 * 32];
  const int tid  = threadIdx.x;
  const int lane = tid & 63;
  const int wid  = tid >> 6;
  const int wr = wid >> 1, wc = wid & 1;
  const int row0 = blockIdx.y * 128;
  const int col0 = blockIdx.x * 128;
  const int l15 = lane & 15, l4 = lane >> 4;
  const int srow = lane >> 2, schunk = lane & 3;

  f32x4 acc[4][4] = {};

  auto stage = [&](int buf, int k0) {
#pragma unroll
    for (int q = 0; q < 2; ++q) {
      int seg = wid * 2 + q;
      int r = seg * 16 + srow;
      int grow = row0 + r;
      if (grow >= M) grow = M - 1;
      gld16(A + (size_t)grow * lda + k0 + schunk * 8, &As[buf][seg * 512]);
      int gcol = col0 + r;
      gld16(Bt + (size_t)gcol * K + k0 + schunk * 8, &Bs[buf][seg * 512]);
    }
  };

  stage(0, 0);
  __syncthreads();
  int cur = 0;
  for (int k0 = 0; k0 < K; k0 += 32) {
    if (k0 + 32 < K) stage(cur ^ 1, k0 + 32);
    bf16x8 af[4], bfr[4];
#pragma unroll
    for (int m = 0; m < 4; ++m)
      af[m] = *reinterpret_cast<bf16x8*>(&As[cur][(wr * 64 + m * 16 + l15) * 32 + l4 * 8]);
#pragma unroll
    for (int n = 0; n < 4; ++n)
      bfr[n] = *reinterpret_cast<bf16x8*>(&Bs[cur][(wc * 64 + n * 16 + l15) * 32 + l4 * 8]);
#pragma unroll
    for (int m = 0; m < 4; ++m)
#pragma unroll
      for (int n = 0; n < 4; ++n)
        acc[m][n] = __builtin_amdgcn_mfma_f32_16x16x32_bf16(af[m], bfr[n], acc[m][n], 0, 0, 0);
    __syncthreads();
    cur ^= 1;
  }

#pragma unroll
  for (int n = 0; n < 4; ++n) {
    int col = col0 + wc * 64 + n * 16 + l15;
    float bv = bias ? bias[col] : 0.f;
#pragma unroll
    for (int m = 0; m < 4; ++m) {
      int rb = row0 + wr * 64 + m * 16 + l4 * 4;
#pragma unroll
      for (int e = 0; e < 4; ++e) {
        int r = rb + e;
        if (r < M) {
          float v = acc[m][n][e] + bv;
          if (RELU) v = fmaxf(v, 0.f);
          size_t idx = (size_t)r * ldc + col;
          if constexpr (OBF) ((short*)Cv)[idx] = f2bf(v);
          else               ((float*)Cv)[idx] = v;
        }
      }
    }
  }
}

// ---------------- bf16 MFMA GEMM, 128x256 tile, 8 waves, gld16 + dbuf -------
// N multiple of 256. XCD-bijective block swizzle for A-panel L2 locality.
template <int RELU, int OBF>
__global__ __launch_bounds__(512)
void k_gemm_wide(const short* __restrict__ A, int lda,
                 const short* __restrict__ Bt,
                 const float* __restrict__ bias,
                 void* __restrict__ Cv, int ldc,
                 int M, int K)
{
  __shared__ __align__(16) short As[2][128 * 32];
  __shared__ __align__(16) short Bs[2][256 * 32];
  const int tid  = threadIdx.x;
  const int lane = tid & 63;
  const int wid  = tid >> 6;        // 0..7
  const int wr = wid >> 2, wc = wid & 3;
  // bijective XCD swizzle (m204)
  int nwg = gridDim.x * gridDim.y;
  int b0 = blockIdx.y * gridDim.x + blockIdx.x;
  int qq = nwg >> 3, rr = nwg & 7, xcd = b0 & 7, j = b0 >> 3;
  int swz = ((xcd < rr) ? xcd * (qq + 1) : rr * (qq + 1) + (xcd - rr) * qq) + j;
  const int row0 = (swz / gridDim.x) * 128;
  const int col0 = (swz % gridDim.x) * 256;
  const int l15 = lane & 15, l4 = lane >> 4;
  const int srow = lane >> 2, schunk = lane & 3;

  f32x4 acc[4][4] = {};

  auto stage = [&](int buf, int k0) {
#pragma unroll
    for (int q = 0; q < 3; ++q) {
      int s = wid * 3 + q;                 // 0..23
      if (s < 8) {
        int grow = row0 + s * 16 + srow;
        if (grow >= M) grow = M - 1;
        gld16(A + (size_t)grow * lda + k0 + schunk * 8, &As[buf][s * 512]);
      } else {
        int gcol = col0 + (s - 8) * 16 + srow;
        gld16(Bt + (size_t)gcol * K + k0 + schunk * 8, &Bs[buf][(s - 8) * 512]);
      }
    }
  };

  stage(0, 0);
  __syncthreads();
  int cur = 0;
  for (int k0 = 0; k0 < K; k0 += 32) {
    if (k0 + 32 < K) stage(cur ^ 1, k0 + 32);
    bf16x8 af[4], bfr[4];
#pragma unroll
    for (int m = 0; m < 4; ++m)
      af[m] = *reinterpret_cast<bf16x8*>(&As[cur][(wr * 64 + m * 16 + l15) * 32 + l4 * 8]);
#pragma unroll
    for (int n = 0; n < 4; ++n)
      bfr[n] = *reinterpret_cast<bf16x8*>(&Bs[cur][(wc * 64 + n * 16 + l15) * 32 + l4 * 8]);
#pragma unroll
    for (int m = 0; m < 4; ++m)
#pragma unroll
      for (int n = 0; n < 4; ++n)
        acc[m][n] = __builtin_amdgcn_mfma_f32_16x16x32_bf16(af[m], bfr[n], acc[m][n], 0, 0, 0);
    __syncthreads();
    cur ^= 1;
  }

#pragma unroll
  for (int n = 0; n < 4; ++n) {
    int col = col0 + wc * 64 + n * 16 + l15;
    float bv = bias ? bias[col] : 0.f;
#pragma unroll
    for (int m = 0; m < 4; ++m) {
      int rb = row0 + wr * 64 + m * 16 + l4 * 4;
#pragma unroll
      for (int e = 0; e < 4; ++e) {
        int r = rb + e;
        if (r < M) {
          float v = acc[m][n][e] + bv;
          if (RELU) v = fmaxf(v, 0.f);
          size_t idx = (size_t)r * ldc + col;
          if constexpr (OBF) ((short*)Cv)[idx] = f2bf(v);
          else               ((float*)Cv)[idx] = v;
        }
      }
    }
  }
}

// ---------------- combined goid GEMM (128x256 tile, 8 waves) ----------------
// Bt = [512][1280]: rows 0-255 = W1t, rows 256-511 = Wp1t.
// col-tile 0 -> X1 (xw1 goid rows, bf16, no bias); col-tile 1 -> H1 (bf16(p1)+bp1).
__global__ __launch_bounds__(512)
void k_combo_wide(const short* __restrict__ A, int lda,
                  const short* __restrict__ Bt,
                  const float* __restrict__ bp1,
                  short* __restrict__ X1, short* __restrict__ H1,
                  int M, int K)
{
  __shared__ __align__(16) short As[2][128 * 32];
  __shared__ __align__(16) short Bs[2][256 * 32];
  const int tid  = threadIdx.x;
  const int lane = tid & 63;
  const int wid  = tid >> 6;
  const int wr = wid >> 2, wc = wid & 3;
  const int row0 = blockIdx.y * 128;
  const int col0 = blockIdx.x * 256;
  const int l15 = lane & 15, l4 = lane >> 4;
  const int srow = lane >> 2, schunk = lane & 3;

  f32x4 acc[4][4] = {};

  auto stage = [&](int buf, int k0) {
#pragma unroll
    for (int q = 0; q < 3; ++q) {
      int s = wid * 3 + q;
      if (s < 8) {
        int grow = row0 + s * 16 + srow;
        if (grow >= M) grow = M - 1;
        gld16(A + (size_t)grow * lda + k0 + schunk * 8, &As[buf][s * 512]);
      } else {
        int gcol = col0 + (s - 8) * 16 + srow;
        gld16(Bt + (size_t)gcol * K + k0 + schunk * 8, &Bs[buf][(s - 8) * 512]);
      }
    }
  };

  stage(0, 0);
  __syncthreads();
  int cur = 0;
  for (int k0 = 0; k0 < K; k0 += 32) {
    if (k0 + 32 < K) stage(cur ^ 1, k0 + 32);
    bf16x8 af[4], bfr[4];
#pragma unroll
    for (int m = 0; m < 4; ++m)
      af[m] = *reinterpret_cast<bf16x8*>(&As[cur][(wr * 64 + m * 16 + l15) * 32 + l4 * 8]);
#pragma unroll
    for (int n = 0; n < 4; ++n)
      bfr[n] = *reinterpret_cast<bf16x8*>(&Bs[cur][(wc * 64 + n * 16 + l15) * 32 + l4 * 8]);
#pragma unroll
    for (int m = 0; m < 4; ++m)
#pragma unroll
      for (int n = 0; n < 4; ++n)
        acc[m][n] = __builtin_amdgcn_mfma_f32_16x16x32_bf16(af[m], bfr[n], acc[m][n], 0, 0, 0);
    __syncthreads();
    cur ^= 1;
  }

  const int is_p1 = (col0 >= 256);   // block-uniform
  short* dstp = is_p1 ? H1 : X1;
#pragma unroll
  for (int n = 0; n < 4; ++n) {
    int cl = wc * 64 + n * 16 + l15;   // col within 256-tile
    float bv = is_p1 ? bp1[cl] : 0.f;
#pragma unroll
    for (int m = 0; m < 4; ++m) {
      int rb = row0 + wr * 64 + m * 16 + l4 * 4;
#pragma unroll
      for (int e = 0; e < 4; ++e) {
        int r = rb + e;
        if (r < M) dstp[(size_t)r * 256 + cl] = f2bf(acc[m][n][e] + bv);
      }
    }
  }
}

// ---------------- gene xw1: fp32-A, 128x256, 8 waves, dbuf ------------------
__global__ __launch_bounds__(512)
void k_gemm_gene(const float* __restrict__ A, int lda,
                 const short* __restrict__ Bt,
                 short* __restrict__ C,   // [M][256] bf16
                 int M, int K)
{
  __shared__ short As[2][128 * 40];              // pad-40 (VALU-staged)
  __shared__ __align__(16) short Bs[2][256 * 32];
  const int tid  = threadIdx.x;
  const int lane = tid & 63;
  const int wid  = tid >> 6;
  const int wr = wid >> 2, wc = wid & 3;
  const int row0 = blockIdx.x * 128;
  const int l15 = lane & 15, l4 = lane >> 4;
  const int sr = tid >> 2, sc = tid & 3;
  const int srow = lane >> 2, schunk = lane & 3;

  f32x4 acc[4][4] = {};

  auto stageB = [&](int buf, int k0) {
#pragma unroll
    for (int q = 0; q < 2; ++q) {
      int seg = wid * 2 + q;              // 0..15
      int gcol = seg * 16 + srow;
      gld16(Bt + (size_t)gcol * K + k0 + schunk * 8, &Bs[buf][seg * 512]);
    }
  };
  auto stageA = [&](int buf, int k0) {
    int grow = row0 + sr;
    float4 v0 = make_float4(0.f,0.f,0.f,0.f), v1 = v0;
    if (grow < M) {
      const float* ap = A + (size_t)grow * lda + k0 + sc * 8;
      v0 = *reinterpret_cast<const float4*>(ap);
      v1 = *reinterpret_cast<const float4*>(ap + 4);
    }
    bf16x8 t;
    t[0]=f2bf(v0.x); t[1]=f2bf(v0.y); t[2]=f2bf(v0.z); t[3]=f2bf(v0.w);
    t[4]=f2bf(v1.x); t[5]=f2bf(v1.y); t[6]=f2bf(v1.z); t[7]=f2bf(v1.w);
    *reinterpret_cast<bf16x8*>(&As[buf][sr * 40 + sc * 8]) = t;
  };

  stageB(0, 0); stageA(0, 0);
  __syncthreads();
  int cur = 0;
  for (int k0 = 0; k0 < K; k0 += 32) {
    if (k0 + 32 < K) { stageB(cur ^ 1, k0 + 32); stageA(cur ^ 1, k0 + 32); }
    bf16x8 af[4], bfr[4];
#pragma unroll
    for (int m = 0; m < 4; ++m)
      af[m] = *reinterpret_cast<bf16x8*>(&As[cur][(wr * 64 + m * 16 + l15) * 40 + l4 * 8]);
#pragma unroll
    for (int n = 0; n < 4; ++n)
      bfr[n] = *reinterpret_cast<bf16x8*>(&Bs[cur][(wc * 64 + n * 16 + l15) * 32 + l4 * 8]);
#pragma unroll
    for (int m = 0; m < 4; ++m)
#pragma unroll
      for (int n = 0; n < 4; ++n)
        acc[m][n] = __builtin_amdgcn_mfma_f32_16x16x32_bf16(af[m], bfr[n], acc[m][n], 0, 0, 0);
    __syncthreads();
    cur ^= 1;
  }

#pragma unroll
  for (int n = 0; n < 4; ++n) {
    int col = wc * 64 + n * 16 + l15;
#pragma unroll
    for (int m = 0; m < 4; ++m) {
      int rb = row0 + wr * 64 + m * 16 + l4 * 4;
#pragma unroll
      for (int e = 0; e < 4; ++e) {
        int r = rb + e;
        if (r < M) C[(size_t)r * 256 + col] = f2bf(acc[m][n][e]);
      }
    }
  }
}

// ---------------- fp32 tiled GEMM (final out layer) ----------------
__global__ __launch_bounds__(256)
void k_gemm_f32(const float* __restrict__ A, int lda,
                const float* __restrict__ B, int ldb,
                const float* __restrict__ bias,
                float* __restrict__ C, int ldc,
                int M, int Ncol, int K, int do_relu)
{
  __shared__ float As[16][65];
  __shared__ float Bs[16][68];
  const int tid = threadIdx.x;
  const int tx = tid & 15, ty = tid >> 4;
  const int row0 = blockIdx.y * 64;
  const int col0 = blockIdx.x * 64;
  float acc[4][4] = {};
  for (int k0 = 0; k0 < K; k0 += 16) {
    {
      int r = tid >> 2;
      int c = (tid & 3) << 2;
      int grow = row0 + r;
      float4 v = make_float4(0.f, 0.f, 0.f, 0.f);
      if (grow < M)
        v = *reinterpret_cast<const float4*>(A + (size_t)grow * lda + k0 + c);
      As[c + 0][r] = v.x; As[c + 1][r] = v.y; As[c + 2][r] = v.z; As[c + 3][r] = v.w;
    }
    {
      int r = tid >> 4;
      int c = (tid & 15) << 2;
      int gcol = col0 + c;
      float4 v = make_float4(0.f, 0.f, 0.f, 0.f);
      if (gcol < Ncol)
        v = *reinterpret_cast<const float4*>(B + (size_t)(k0 + r) * ldb + gcol);
      *reinterpret_cast<float4*>(&Bs[r][c]) = v;
    }
    __syncthreads();
#pragma unroll
    for (int k = 0; k < 16; ++k) {
      float a[4], b[4];
#pragma unroll
      for (int i = 0; i < 4; ++i) a[i] = As[k][ty + 16 * i];
#pragma unroll
      for (int j = 0; j < 4; ++j) b[j] = Bs[k][tx + 16 * j];
#pragma unroll
      for (int i = 0; i < 4; ++i)
#pragma unroll
        for (int j = 0; j < 4; ++j)
          acc[i][j] = fmaf(a[i], b[j], acc[i][j]);
    }
    __syncthreads();
  }
#pragma unroll
  for (int i = 0; i < 4; ++i) {
    int r = row0 + ty + 16 * i;
    if (r >= M) continue;
#pragma unroll
    for (int j = 0; j < 4; ++j) {
      int ccol = col0 + tx + 16 * j;
      if (ccol >= Ncol) continue;
      float v = acc[i][j];
      if (bias) v += bias[ccol];
      if (do_relu) v = fmaxf(v, 0.f);
      C[(size_t)r * ldc + ccol] = v;
    }
  }
}

extern "C" void kernel_launch(void* const* d_in, const int* in_sizes, int n_in,
                              void* d_out, int out_size, void* d_ws, size_t ws_size,
                              hipStream_t stream) {
  const float* x   = (const float*)d_in[0];
  const int*   ei  = (const int*)d_in[1];
  const float* Wd1 = (const float*)d_in[3];
  const float* bd1 = (const float*)d_in[4];
  const float* Wd2 = (const float*)d_in[5];
  const float* bd2 = (const float*)d_in[6];
  const float* W1  = (const float*)d_in[7];
  const float* b1  = (const float*)d_in[8];
  const float* W2  = (const float*)d_in[9];
  const float* b2  = (const float*)d_in[10];
  const float* Wp1 = (const float*)d_in[11];
  const float* bp1 = (const float*)d_in[12];
  const float* Wp2 = (const float*)d_in[13];
  const float* bp2 = (const float*)d_in[14];
  const float* Wf  = (const float*)d_in[15];
  const float* bf_ = (const float*)d_in[16];
  float* out = (float*)d_out;
  float* ws  = (float*)d_ws;

  // workspace (float offsets), non-overlapping, 16B-aligned
  short* goidx_bf = (short*)(ws + 0);          // 10000 x 4096 bf16
  short* goidt_bf = (short*)(ws + 20480000);   // 10000 x 1280 bf16
  short* h1tmp_bf = (short*)(ws + 26880000);   // 10000 x 1024 bf16
  short* Wd1t = (short*)(ws + 32000000);       // 1024 x 4096
  short* Wd2t = (short*)(ws + 34097152);       // 1280 x 1024
  short* W1t  = (short*)(ws + 34752512);       //  256 x 1280 \ contiguous ->
  short* Wp1t = (short*)(ws + 34916352);       //  256 x 1280 / Wcomb[512][1280]
  short* W2t  = (short*)(ws + 35080192);       //  128 x 256
  short* xw1_bf = (short*)(ws + 35100000);     // 50000 x 256 bf16
  short* h1bf   = (short*)(ws + 41500000);     // 50000 x 256 bf16
  short* xw2_bf = (short*)(ws + 50460000);     // 50000 x 128 bf16
  float* h2     = ws + 53660000;               // 50000 x 128 fp32
  float* deg    = ws + 60060000;               // 50,000
  int*   rowstart = (int*)(ws + 60150016);     // 40,000
  int*   cursor   = (int*)(ws + 60190016);     // 40,000
  int2*  edges    = (int2*)(ws + 60230016);    // 800,000 x 8B
  int*   gcount   = (int*)(ws + 61830016);     // 1
  short* Wp2t = (short*)(ws + 61830032);       //  128 x 256

  const float* gene_x = x;                          // rows 0..39999, lda=4096
  const float* goid_x = x + (size_t)kNGene * kGDim; // rows 40000..49999

  auto gb = [](int M, int Ncol) { return dim3((unsigned)(Ncol / 128), (unsigned)((M + 127) / 128)); };
  auto gw = [](int M, int Ncol) { return dim3((unsigned)(Ncol / 256), (unsigned)((M + 127) / 128)); };
  auto gf = [](int M, int Ncol) { return dim3((unsigned)((Ncol + 63) / 64), (unsigned)((M + 63) / 64)); };

  // 0) converts: goid_x -> bf16; all six weight transposes in one launch
  k_cvt_rows<<<2048, 256, 0, stream>>>(goid_x, kGDim, goidx_bf, kNGoid, kGDim);
  k_wtrans_all<<<6080, 256, 0, stream>>>(Wd1, Wd1t, Wd2, Wd2t, W1, W1t,
                                         Wp1, Wp1t, W2, W2t, Wp2, Wp2t);

  // 1) degrees + CSR
  k_init<<<(kN + 255) / 256, 256, 0, stream>>>(deg, gcount);
  k_deg_hist<<<(kE + 255) / 256, 256, 0, stream>>>(ei, deg);
  k_rowassign<<<(kNGene + 255) / 256, 256, 0, stream>>>(deg, rowstart, cursor, gcount);
  k_fill<<<(kE + 255) / 256, 256, 0, stream>>>(ei, deg, cursor, edges);

  // 2) GOID MLP (wide 128x256 tiles, dbuf, XCD swizzle)
  k_gemm_wide<1,1><<<gw(kNGoid, kD1), 512, 0, stream>>>(goidx_bf, kGDim, Wd1t, bd1,
                                                        h1tmp_bf, kD1, kNGoid, kGDim);
  k_gemm_wide<1,1><<<gw(kNGoid, kInDim), 512, 0, stream>>>(h1tmp_bf, kD1, Wd2t, bd2,
                                                           goidt_bf, kInDim, kNGoid, kD1);

  // 3) gene xw1 (single pass over gene_x, dbuf)
  k_gemm_gene<<<dim3((kNGene + 127) / 128), 512, 0, stream>>>(gene_x, kGDim, W1t,
                                                              xw1_bf, kNGene, kInDim);

  // 4) combined goid GEMM: xw1 goid rows + bf16(p1) -> h1 goid rows
  k_combo_wide<<<dim3(2, (kNGoid + 127) / 128), 512, 0, stream>>>(
      goidt_bf, kInDim, W1t /*=Wcomb[512][1280]*/, bp1,
      xw1_bf + (size_t)kNGene * kH1, h1bf + (size_t)kNGene * kH1,
      kNGoid, kInDim);

  // 5) conv1: gather -> h1 bf16 gene rows
  k_gather_bf<kH1,1><<<(kNGene * 64 + 255) / 256, 256, 0, stream>>>(
      xw1_bf, deg, rowstart, edges, b1, h1bf);

  // 6) xw2 = h1 @ W2 -> bf16 message table
  k_gemm_bf16a<0,1><<<gb(kN, kH2), 256, 0, stream>>>(h1bf, kH1, W2t, nullptr,
                                                     xw2_bf, kH2, kN, kH1);

  // 7) conv2: gather -> h2 fp32 gene rows; goid rows = bf16(p1)@Wp2+bp2
  k_gather_bf<kH2,0><<<(kNGene * 64 + 255) / 256, 256, 0, stream>>>(
      xw2_bf, deg, rowstart, edges, b2, h2);
  k_gemm_bf16a<0,0><<<gb(kNGoid, kH2), 256, 0, stream>>>(
      h1bf + (size_t)kNGene * kH1, kH1, Wp2t, bp2,
      h2 + (size_t)kNGene * kH2, kH2, kNGoid, kH1);

  // 8) out = h2 @ Wf + bf
  k_gemm_f32<<<gf(kN, kOut), 256, 0, stream>>>(h2, kH2, Wf, kOut, bf_, out, kOut,
                                               kN, kOut, kH2, 0);
}

// Round 12
// 609.283 us; speedup vs baseline: 1.7147x; 1.0022x over previous
//
#include <hip/hip_runtime.h>

// Problem constants (from reference)
constexpr int kNGene = 40000;
constexpr int kNGoid = 10000;
constexpr int kN     = 50000;
constexpr int kE     = 800000;
constexpr int kInDim = 1280;
constexpr int kH1    = 256;
constexpr int kH2    = 128;
constexpr int kOut   = 64;
constexpr int kGDim  = 4096;
constexpr int kD1    = 1024;

typedef short bf16x8 __attribute__((ext_vector_type(8)));
typedef float f32x4  __attribute__((ext_vector_type(4)));

static __device__ __forceinline__ short f2bf(float f) {
  union { float f; unsigned u; } v; v.f = f;
  unsigned r = v.u + 0x7FFF + ((v.u >> 16) & 1);   // RNE; inputs are finite
  return (short)(r >> 16);
}
static __device__ __forceinline__ float bf2f(short s) {
  union { unsigned u; float f; } v;
  v.u = ((unsigned)(unsigned short)s) << 16;
  return v.f;
}
// async global->LDS, 16B/lane; LDS dest = base + lane*16 (wave-linear).
static __device__ __forceinline__ void gld16(const void* g, void* l) {
  __builtin_amdgcn_global_load_lds(
      (const __attribute__((address_space(1))) void*)g,
      (__attribute__((address_space(3))) void*)l, 16, 0, 0);
}
// counted-vmcnt pipeline barrier: wait own loads down to N outstanding,
// raw barrier, then a compiler fence so post-barrier LDS reads can't hoist.
template <int N>
static __device__ __forceinline__ void wait_barrier() {
  if constexpr (N == 0)      asm volatile("s_waitcnt vmcnt(0)" ::: "memory");
  else if constexpr (N == 3) asm volatile("s_waitcnt vmcnt(3)" ::: "memory");
  else                       asm volatile("s_waitcnt vmcnt(4)" ::: "memory");
  __builtin_amdgcn_s_barrier();
  asm volatile("" ::: "memory");
}

// ---------------- fused prep: goidx cvt + 7 weight transposes + deg init ----
constexpr int kCvtBlocks   = 20000;  // 10000*4096/8/256
constexpr int kTransBlocks = 6088;   // 4096+1280+320+320+32+32+8
constexpr int kInitBlocks  = 196;    // ceil(50000/256)

__global__ __launch_bounds__(256)
void k_prep(const float* __restrict__ goid_x, short* __restrict__ goidx_bf,
            const float* __restrict__ Wd1, short* __restrict__ Wd1t,
            const float* __restrict__ Wd2, short* __restrict__ Wd2t,
            const float* __restrict__ W1,  short* __restrict__ W1t,
            const float* __restrict__ Wp1, short* __restrict__ Wp1t,
            const float* __restrict__ W2,  short* __restrict__ W2t,
            const float* __restrict__ Wp2, short* __restrict__ Wp2t,
            const float* __restrict__ Wf,  short* __restrict__ Wft,
            float* __restrict__ deg, int* __restrict__ gcount)
{
  __shared__ float t[32][33];
  int b = blockIdx.x;
  if (b < kCvtBlocks) {                       // goid_x -> bf16
    int idx = b * 256 + threadIdx.x;          // chunk of 8
    int r = idx >> 9;                         // 512 chunks per 4096-row
    int c = (idx & 511) << 3;
    const float* sp = goid_x + (size_t)r * kGDim + c;
    float4 v0 = *reinterpret_cast<const float4*>(sp);
    float4 v1 = *reinterpret_cast<const float4*>(sp + 4);
    bf16x8 o;
    o[0]=f2bf(v0.x); o[1]=f2bf(v0.y); o[2]=f2bf(v0.z); o[3]=f2bf(v0.w);
    o[4]=f2bf(v1.x); o[5]=f2bf(v1.y); o[6]=f2bf(v1.z); o[7]=f2bf(v1.w);
    *reinterpret_cast<bf16x8*>(goidx_bf + (size_t)r * kGDim + c) = o;
    return;
  }
  if (b >= kCvtBlocks + kTransBlocks) {       // deg init
    int i = (b - kCvtBlocks - kTransBlocks) * 256 + threadIdx.x;
    if (i < kN) deg[i] = 1.0f;
    if (i == 0) *gcount = 0;
    return;
  }
  // weight transpose fp32[K][N] -> bf16[N][K]
  int b2 = b - kCvtBlocks;
  const float* W; short* Wt; int K, N, bi;
  if (b2 < 4096)      { W = Wd1; Wt = Wd1t; K = 4096; N = 1024; bi = b2; }
  else if (b2 < 5376) { W = Wd2; Wt = Wd2t; K = 1024; N = 1280; bi = b2 - 4096; }
  else if (b2 < 5696) { W = W1;  Wt = W1t;  K = 1280; N = 256;  bi = b2 - 5376; }
  else if (b2 < 6016) { W = Wp1; Wt = Wp1t; K = 1280; N = 256;  bi = b2 - 5696; }
  else if (b2 < 6048) { W = W2;  Wt = W2t;  K = 256;  N = 128;  bi = b2 - 6016; }
  else if (b2 < 6080) { W = Wp2; Wt = Wp2t; K = 256;  N = 128;  bi = b2 - 6048; }
  else                { W = Wf;  Wt = Wft;  K = 128;  N = 64;   bi = b2 - 6080; }
  int nbx = N >> 5;
  int n0 = (bi % nbx) * 32, k0 = (bi / nbx) * 32;
  int tx = threadIdx.x & 31, ty = threadIdx.x >> 5;
#pragma unroll
  for (int p = 0; p < 4; ++p)
    t[ty + 8 * p][tx] = W[(size_t)(k0 + ty + 8 * p) * N + n0 + tx];
  __syncthreads();
#pragma unroll
  for (int p = 0; p < 4; ++p)
    Wt[(size_t)(n0 + ty + 8 * p) * K + k0 + tx] = f2bf(t[tx][ty + 8 * p]);
}

// ---------------- degree / CSR ----------------
__global__ void k_deg_hist(const int* __restrict__ ei, float* __restrict__ deg) {
  int e = blockIdx.x * blockDim.x + threadIdx.x;
  if (e < kE) atomicAdd(&deg[ei[kE + e]], 1.0f);
}
__global__ void k_rowassign(const float* __restrict__ deg, int* __restrict__ rowstart,
                            int* __restrict__ cursor, int* __restrict__ gcount) {
  int i = blockIdx.x * blockDim.x + threadIdx.x;
  int lane = threadIdx.x & 63;
  int c = (i < kNGene) ? ((int)deg[i] - 1) : 0;
  int incl = c;
#pragma unroll
  for (int off = 1; off < 64; off <<= 1) {
    int t = __shfl_up(incl, off, 64);
    if (lane >= off) incl += t;
  }
  int total = __shfl(incl, 63, 64);
  int base = 0;
  if (lane == 63) base = atomicAdd(gcount, total);
  base = __shfl(base, 63, 64);
  if (i < kNGene) {
    int s = base + incl - c;
    rowstart[i] = s;
    cursor[i] = s;
  }
}
__global__ void k_fill(const int* __restrict__ ei, const float* __restrict__ deg,
                       int* __restrict__ cursor, int2* __restrict__ edges) {
  int e = blockIdx.x * blockDim.x + threadIdx.x;
  if (e >= kE) return;
  int dst = ei[kE + e];
  if (dst >= kNGene) return;
  int src = ei[e];
  int pos = atomicAdd(&cursor[dst], 1);
  float nrm = rsqrtf(deg[src] * deg[dst]);
  edges[pos] = make_int2(src, __float_as_int(nrm));
}

// ---------------- fused gather aggregation (bf16 messages, packed edges) ----
template <int F, int OBF>
__global__ __launch_bounds__(256)
void k_gather_bf(const short* __restrict__ xw, const float* __restrict__ deg,
                 const int* __restrict__ rowstart, const int2* __restrict__ edges,
                 const float* __restrict__ bias, void* __restrict__ hv) {
  constexpr int VEC = F / 64;
  int row = (blockIdx.x * blockDim.x + threadIdx.x) >> 6;
  int lane = threadIdx.x & 63;
  if (row >= kNGene) return;
  float dg = deg[row];
  float inv = 1.0f / dg;
  float acc[VEC];
  {
    const short* xr = xw + (size_t)row * F + lane * VEC;
    if constexpr (VEC == 4) {
      short4 s = *reinterpret_cast<const short4*>(xr);
      acc[0] = bf2f(s.x) * inv; acc[1] = bf2f(s.y) * inv;
      acc[2] = bf2f(s.z) * inv; acc[3] = bf2f(s.w) * inv;
    } else {
      short2 s = *reinterpret_cast<const short2*>(xr);
      acc[0] = bf2f(s.x) * inv; acc[1] = bf2f(s.y) * inv;
    }
  }
  const int2* ep = edges + rowstart[row];
  int n = (int)dg - 1;
  int e = 0;
  for (; e + 1 < n; e += 2) {
    int2 p0 = ep[e], p1 = ep[e + 1];
    float n0 = __int_as_float(p0.y), n1 = __int_as_float(p1.y);
    const short* x0 = xw + (size_t)p0.x * F + lane * VEC;
    const short* x1 = xw + (size_t)p1.x * F + lane * VEC;
    if constexpr (VEC == 4) {
      short4 s0 = *reinterpret_cast<const short4*>(x0);
      short4 s1 = *reinterpret_cast<const short4*>(x1);
      acc[0] += bf2f(s0.x) * n0; acc[1] += bf2f(s0.y) * n0;
      acc[2] += bf2f(s0.z) * n0; acc[3] += bf2f(s0.w) * n0;
      acc[0] += bf2f(s1.x) * n1; acc[1] += bf2f(s1.y) * n1;
      acc[2] += bf2f(s1.z) * n1; acc[3] += bf2f(s1.w) * n1;
    } else {
      short2 s0 = *reinterpret_cast<const short2*>(x0);
      short2 s1 = *reinterpret_cast<const short2*>(x1);
      acc[0] += bf2f(s0.x) * n0; acc[1] += bf2f(s0.y) * n0;
      acc[0] += bf2f(s1.x) * n1; acc[1] += bf2f(s1.y) * n1;
    }
  }
  if (e < n) {
    int2 p0 = ep[e];
    float n0 = __int_as_float(p0.y);
    const short* x0 = xw + (size_t)p0.x * F + lane * VEC;
    if constexpr (VEC == 4) {
      short4 s0 = *reinterpret_cast<const short4*>(x0);
      acc[0] += bf2f(s0.x) * n0; acc[1] += bf2f(s0.y) * n0;
      acc[2] += bf2f(s0.z) * n0; acc[3] += bf2f(s0.w) * n0;
    } else {
      short2 s0 = *reinterpret_cast<const short2*>(x0);
      acc[0] += bf2f(s0.x) * n0; acc[1] += bf2f(s0.y) * n0;
    }
  }
#pragma unroll
  for (int v = 0; v < VEC; ++v) acc[v] = fmaxf(acc[v] + bias[lane * VEC + v], 0.f);
  if constexpr (OBF) {
    short* hp = (short*)hv + (size_t)row * F + lane * VEC;
    if constexpr (VEC == 4) {
      short4 o; o.x = f2bf(acc[0]); o.y = f2bf(acc[1]); o.z = f2bf(acc[2]); o.w = f2bf(acc[3]);
      *reinterpret_cast<short4*>(hp) = o;
    } else {
      short2 o; o.x = f2bf(acc[0]); o.y = f2bf(acc[1]);
      *reinterpret_cast<short2*>(hp) = o;
    }
  } else {
    float* hp = (float*)hv + (size_t)row * F + lane * VEC;
    if constexpr (VEC == 4) {
      float4 o; o.x = acc[0]; o.y = acc[1]; o.z = acc[2]; o.w = acc[3];
      *reinterpret_cast<float4*>(hp) = o;
    } else {
      float2 o; o.x = acc[0]; o.y = acc[1];
      *reinterpret_cast<float2*>(hp) = o;
    }
  }
}

// ---------------- bf16 MFMA GEMM, 128x128, 3-buffer counted-vmcnt pipeline --
template <int RELU, int OBF>
__global__ __launch_bounds__(256)
void k_gemm_bf16a(const short* __restrict__ A, int lda,
                  const short* __restrict__ Bt,
                  const float* __restrict__ bias,
                  void* __restrict__ Cv, int ldc,
                  int M, int K)
{
  __shared__ __align__(16) short As[3][128 * 32];
  __shared__ __align__(16) short Bs[3][128 * 32];
  const int tid  = threadIdx.x;
  const int lane = tid & 63;
  const int wid  = tid >> 6;
  const int wr = wid >> 1, wc = wid & 1;
  const int row0 = blockIdx.y * 128;
  const int col0 = blockIdx.x * 128;
  const int l15 = lane & 15, l4 = lane >> 4;
  const int srow = lane >> 2, schunk = lane & 3;

  f32x4 acc[4][4] = {};

  auto stage = [&](int buf, int k0) {   // 4 gld16 per wave
#pragma unroll
    for (int q = 0; q < 2; ++q) {
      int seg = wid * 2 + q;
      int r = seg * 16 + srow;
      int grow = row0 + r;
      if (grow >= M) grow = M - 1;
      gld16(A + (size_t)grow * lda + k0 + schunk * 8, &As[buf][seg * 512]);
      int gcol = col0 + r;
      gld16(Bt + (size_t)gcol * K + k0 + schunk * 8, &Bs[buf][seg * 512]);
    }
  };

  const int nt = K >> 5;
  stage(0, 0);
  if (nt > 1) { stage(1, 32); wait_barrier<4>(); }
  else        { wait_barrier<0>(); }

  for (int t = 0; t < nt; ++t) {
    if (t + 2 < nt) stage((t + 2) % 3, (t + 2) * 32);
    const int cur = t % 3;
    bf16x8 af[4], bfr[4];
#pragma unroll
    for (int m = 0; m < 4; ++m)
      af[m] = *reinterpret_cast<bf16x8*>(&As[cur][(wr * 64 + m * 16 + l15) * 32 + l4 * 8]);
#pragma unroll
    for (int n = 0; n < 4; ++n)
      bfr[n] = *reinterpret_cast<bf16x8*>(&Bs[cur][(wc * 64 + n * 16 + l15) * 32 + l4 * 8]);
#pragma unroll
    for (int m = 0; m < 4; ++m)
#pragma unroll
      for (int n = 0; n < 4; ++n)
        acc[m][n] = __builtin_amdgcn_mfma_f32_16x16x32_bf16(af[m], bfr[n], acc[m][n], 0, 0, 0);
    if (t + 1 < nt) {
      if (t + 2 < nt) wait_barrier<4>(); else wait_barrier<0>();
    }
  }

#pragma unroll
  for (int n = 0; n < 4; ++n) {
    int col = col0 + wc * 64 + n * 16 + l15;
    float bv = bias ? bias[col] : 0.f;
#pragma unroll
    for (int m = 0; m < 4; ++m) {
      int rb = row0 + wr * 64 + m * 16 + l4 * 4;
#pragma unroll
      for (int e = 0; e < 4; ++e) {
        int r = rb + e;
        if (r < M) {
          float v = acc[m][n][e] + bv;
          if (RELU) v = fmaxf(v, 0.f);
          size_t idx = (size_t)r * ldc + col;
          if constexpr (OBF) ((short*)Cv)[idx] = f2bf(v);
          else               ((float*)Cv)[idx] = v;
        }
      }
    }
  }
}

// ---------------- bf16 MFMA GEMM, 128x256, 8 waves, 3-buffer pipeline -------
template <int RELU, int OBF>
__global__ __launch_bounds__(512)
void k_gemm_wide(const short* __restrict__ A, int lda,
                 const short* __restrict__ Bt,
                 const float* __restrict__ bias,
                 void* __restrict__ Cv, int ldc,
                 int M, int K)
{
  __shared__ __align__(16) short As[3][128 * 32];
  __shared__ __align__(16) short Bs[3][256 * 32];
  const int tid  = threadIdx.x;
  const int lane = tid & 63;
  const int wid  = tid >> 6;
  const int wr = wid >> 2, wc = wid & 3;
  // bijective XCD swizzle (m204)
  int nwg = gridDim.x * gridDim.y;
  int b0 = blockIdx.y * gridDim.x + blockIdx.x;
  int qq = nwg >> 3, rr = nwg & 7, xcd = b0 & 7, j = b0 >> 3;
  int swz = ((xcd < rr) ? xcd * (qq + 1) : rr * (qq + 1) + (xcd - rr) * qq) + j;
  const int row0 = (swz / gridDim.x) * 128;
  const int col0 = (swz % gridDim.x) * 256;
  const int l15 = lane & 15, l4 = lane >> 4;
  const int srow = lane >> 2, schunk = lane & 3;

  f32x4 acc[4][4] = {};

  auto stage = [&](int buf, int k0) {   // 3 gld16 per wave
#pragma unroll
    for (int q = 0; q < 3; ++q) {
      int s = wid * 3 + q;
      if (s < 8) {
        int grow = row0 + s * 16 + srow;
        if (grow >= M) grow = M - 1;
        gld16(A + (size_t)grow * lda + k0 + schunk * 8, &As[buf][s * 512]);
      } else {
        int gcol = col0 + (s - 8) * 16 + srow;
        gld16(Bt + (size_t)gcol * K + k0 + schunk * 8, &Bs[buf][(s - 8) * 512]);
      }
    }
  };

  const int nt = K >> 5;
  stage(0, 0);
  if (nt > 1) { stage(1, 32); wait_barrier<3>(); }
  else        { wait_barrier<0>(); }

  for (int t = 0; t < nt; ++t) {
    if (t + 2 < nt) stage((t + 2) % 3, (t + 2) * 32);
    const int cur = t % 3;
    bf16x8 af[4], bfr[4];
#pragma unroll
    for (int m = 0; m < 4; ++m)
      af[m] = *reinterpret_cast<bf16x8*>(&As[cur][(wr * 64 + m * 16 + l15) * 32 + l4 * 8]);
#pragma unroll
    for (int n = 0; n < 4; ++n)
      bfr[n] = *reinterpret_cast<bf16x8*>(&Bs[cur][(wc * 64 + n * 16 + l15) * 32 + l4 * 8]);
#pragma unroll
    for (int m = 0; m < 4; ++m)
#pragma unroll
      for (int n = 0; n < 4; ++n)
        acc[m][n] = __builtin_amdgcn_mfma_f32_16x16x32_bf16(af[m], bfr[n], acc[m][n], 0, 0, 0);
    if (t + 1 < nt) {
      if (t + 2 < nt) wait_barrier<3>(); else wait_barrier<0>();
    }
  }

#pragma unroll
  for (int n = 0; n < 4; ++n) {
    int col = col0 + wc * 64 + n * 16 + l15;
    float bv = bias ? bias[col] : 0.f;
#pragma unroll
    for (int m = 0; m < 4; ++m) {
      int rb = row0 + wr * 64 + m * 16 + l4 * 4;
#pragma unroll
      for (int e = 0; e < 4; ++e) {
        int r = rb + e;
        if (r < M) {
          float v = acc[m][n][e] + bv;
          if (RELU) v = fmaxf(v, 0.f);
          size_t idx = (size_t)r * ldc + col;
          if constexpr (OBF) ((short*)Cv)[idx] = f2bf(v);
          else               ((float*)Cv)[idx] = v;
        }
      }
    }
  }
}

// ---------------- combined goid GEMM (128x256 tile, 8 waves, 2-buf) ---------
__global__ __launch_bounds__(512)
void k_combo_wide(const short* __restrict__ A, int lda,
                  const short* __restrict__ Bt,
                  const float* __restrict__ bp1,
                  short* __restrict__ X1, short* __restrict__ H1,
                  int M, int K)
{
  __shared__ __align__(16) short As[2][128 * 32];
  __shared__ __align__(16) short Bs[2][256 * 32];
  const int tid  = threadIdx.x;
  const int lane = tid & 63;
  const int wid  = tid >> 6;
  const int wr = wid >> 2, wc = wid & 3;
  const int row0 = blockIdx.y * 128;
  const int col0 = blockIdx.x * 256;
  const int l15 = lane & 15, l4 = lane >> 4;
  const int srow = lane >> 2, schunk = lane & 3;

  f32x4 acc[4][4] = {};

  auto stage = [&](int buf, int k0) {
#pragma unroll
    for (int q = 0; q < 3; ++q) {
      int s = wid * 3 + q;
      if (s < 8) {
        int grow = row0 + s * 16 + srow;
        if (grow >= M) grow = M - 1;
        gld16(A + (size_t)grow * lda + k0 + schunk * 8, &As[buf][s * 512]);
      } else {
        int gcol = col0 + (s - 8) * 16 + srow;
        gld16(Bt + (size_t)gcol * K + k0 + schunk * 8, &Bs[buf][(s - 8) * 512]);
      }
    }
  };

  stage(0, 0);
  __syncthreads();
  int cur = 0;
  for (int k0 = 0; k0 < K; k0 += 32) {
    if (k0 + 32 < K) stage(cur ^ 1, k0 + 32);
    bf16x8 af[4], bfr[4];
#pragma unroll
    for (int m = 0; m < 4; ++m)
      af[m] = *reinterpret_cast<bf16x8*>(&As[cur][(wr * 64 + m * 16 + l15) * 32 + l4 * 8]);
#pragma unroll
    for (int n = 0; n < 4; ++n)
      bfr[n] = *reinterpret_cast<bf16x8*>(&Bs[cur][(wc * 64 + n * 16 + l15) * 32 + l4 * 8]);
#pragma unroll
    for (int m = 0; m < 4; ++m)
#pragma unroll
      for (int n = 0; n < 4; ++n)
        acc[m][n] = __builtin_amdgcn_mfma_f32_16x16x32_bf16(af[m], bfr[n], acc[m][n], 0, 0, 0);
    __syncthreads();
    cur ^= 1;
  }

  const int is_p1 = (col0 >= 256);
  short* dstp = is_p1 ? H1 : X1;
#pragma unroll
  for (int n = 0; n < 4; ++n) {
    int cl = wc * 64 + n * 16 + l15;
    float bv = is_p1 ? bp1[cl] : 0.f;
#pragma unroll
    for (int m = 0; m < 4; ++m) {
      int rb = row0 + wr * 64 + m * 16 + l4 * 4;
#pragma unroll
      for (int e = 0; e < 4; ++e) {
        int r = rb + e;
        if (r < M) dstp[(size_t)r * 256 + cl] = f2bf(acc[m][n][e] + bv);
      }
    }
  }
}

// ---------------- gene xw1: fp32-A, 128x256, 8 waves, 2-buf -----------------
__global__ __launch_bounds__(512)
void k_gemm_gene(const float* __restrict__ A, int lda,
                 const short* __restrict__ Bt,
                 short* __restrict__ C,   // [M][256] bf16
                 int M, int K)
{
  __shared__ short As[2][128 * 40];
  __shared__ __align__(16) short Bs[2][256 * 32];
  const int tid  = threadIdx.x;
  const int lane = tid & 63;
  const int wid  = tid >> 6;
  const int wr = wid >> 2, wc = wid & 3;
  const int row0 = blockIdx.x * 128;
  const int l15 = lane & 15, l4 = lane >> 4;
  const int sr = tid >> 2, sc = tid & 3;
  const int srow = lane >> 2, schunk = lane & 3;

  f32x4 acc[4][4] = {};

  auto stageB = [&](int buf, int k0) {
#pragma unroll
    for (int q = 0; q < 2; ++q) {
      int seg = wid * 2 + q;
      int gcol = seg * 16 + srow;
      gld16(Bt + (size_t)gcol * K + k0 + schunk * 8, &Bs[buf][seg * 512]);
    }
  };
  auto stageA = [&](int buf, int k0) {
    int grow = row0 + sr;
    float4 v0 = make_float4(0.f,0.f,0.f,0.f), v1 = v0;
    if (grow < M) {
      const float* ap = A + (size_t)grow * lda + k0 + sc * 8;
      v0 = *reinterpret_cast<const float4*>(ap);
      v1 = *reinterpret_cast<const float4*>(ap + 4);
    }
    bf16x8 t;
    t[0]=f2bf(v0.x); t[1]=f2bf(v0.y); t[2]=f2bf(v0.z); t[3]=f2bf(v0.w);
    t[4]=f2bf(v1.x); t[5]=f2bf(v1.y); t[6]=f2bf(v1.z); t[7]=f2bf(v1.w);
    *reinterpret_cast<bf16x8*>(&As[buf][sr * 40 + sc * 8]) = t;
  };

  stageB(0, 0); stageA(0, 0);
  __syncthreads();
  int cur = 0;
  for (int k0 = 0; k0 < K; k0 += 32) {
    if (k0 + 32 < K) { stageB(cur ^ 1, k0 + 32); stageA(cur ^ 1, k0 + 32); }
    bf16x8 af[4], bfr[4];
#pragma unroll
    for (int m = 0; m < 4; ++m)
      af[m] = *reinterpret_cast<bf16x8*>(&As[cur][(wr * 64 + m * 16 + l15) * 40 + l4 * 8]);
#pragma unroll
    for (int n = 0; n < 4; ++n)
      bfr[n] = *reinterpret_cast<bf16x8*>(&Bs[cur][(wc * 64 + n * 16 + l15) * 32 + l4 * 8]);
#pragma unroll
    for (int m = 0; m < 4; ++m)
#pragma unroll
      for (int n = 0; n < 4; ++n)
        acc[m][n] = __builtin_amdgcn_mfma_f32_16x16x32_bf16(af[m], bfr[n], acc[m][n], 0, 0, 0);
    __syncthreads();
    cur ^= 1;
  }

#pragma unroll
  for (int n = 0; n < 4; ++n) {
    int col = wc * 64 + n * 16 + l15;
#pragma unroll
    for (int m = 0; m < 4; ++m) {
      int rb = row0 + wr * 64 + m * 16 + l4 * 4;
#pragma unroll
      for (int e = 0; e < 4; ++e) {
        int r = rb + e;
        if (r < M) C[(size_t)r * 256 + col] = f2bf(acc[m][n][e]);
      }
    }
  }
}

// ---------------- out layer: h2bf[M][128] @ Wft[64][128] + bf -> out fp32 ----
// tile 256 rows x 64 cols, 4 waves (wave = 64 rows x 64 cols), 2-buf dbuf.
__global__ __launch_bounds__(256)
void k_gemm_out(const short* __restrict__ A,      // h2bf, lda=128
                const short* __restrict__ Bt,     // Wft [64][128]
                const float* __restrict__ bias,
                float* __restrict__ C,            // [M][64]
                int M)
{
  __shared__ __align__(16) short As[2][256 * 32];
  __shared__ __align__(16) short Bs[2][64 * 32];
  const int tid  = threadIdx.x;
  const int lane = tid & 63;
  const int wid  = tid >> 6;
  const int row0 = blockIdx.x * 256;
  const int l15 = lane & 15, l4 = lane >> 4;
  const int srow = lane >> 2, schunk = lane & 3;

  f32x4 acc[4][4] = {};

  auto stage = [&](int buf, int k0) {   // 5 gld16 per wave
#pragma unroll
    for (int q = 0; q < 4; ++q) {
      int seg = wid * 4 + q;            // 0..15
      int grow = row0 + seg * 16 + srow;
      if (grow >= M) grow = M - 1;
      gld16(A + (size_t)grow * 128 + k0 + schunk * 8, &As[buf][seg * 512]);
    }
    int gcol = wid * 16 + srow;         // 0..63
    gld16(Bt + (size_t)gcol * 128 + k0 + schunk * 8, &Bs[buf][wid * 512]);
  };

  stage(0, 0);
  __syncthreads();
  int cur = 0;
  for (int k0 = 0; k0 < 128; k0 += 32) {
    if (k0 + 32 < 128) stage(cur ^ 1, k0 + 32);
    bf16x8 af[4], bfr[4];
#pragma unroll
    for (int m = 0; m < 4; ++m)
      af[m] = *reinterpret_cast<bf16x8*>(&As[cur][(wid * 64 + m * 16 + l15) * 32 + l4 * 8]);
#pragma unroll
    for (int n = 0; n < 4; ++n)
      bfr[n] = *reinterpret_cast<bf16x8*>(&Bs[cur][(n * 16 + l15) * 32 + l4 * 8]);
#pragma unroll
    for (int m = 0; m < 4; ++m)
#pragma unroll
      for (int n = 0; n < 4; ++n)
        acc[m][n] = __builtin_amdgcn_mfma_f32_16x16x32_bf16(af[m], bfr[n], acc[m][n], 0, 0, 0);
    __syncthreads();
    cur ^= 1;
  }

#pragma unroll
  for (int n = 0; n < 4; ++n) {
    int col = n * 16 + l15;
    float bv = bias[col];
#pragma unroll
    for (int m = 0; m < 4; ++m) {
      int rb = row0 + wid * 64 + m * 16 + l4 * 4;
#pragma unroll
      for (int e = 0; e < 4; ++e) {
        int r = rb + e;
        if (r < M) C[(size_t)r * 64 + col] = acc[m][n][e] + bv;
      }
    }
  }
}

extern "C" void kernel_launch(void* const* d_in, const int* in_sizes, int n_in,
                              void* d_out, int out_size, void* d_ws, size_t ws_size,
                              hipStream_t stream) {
  const float* x   = (const float*)d_in[0];
  const int*   ei  = (const int*)d_in[1];
  const float* Wd1 = (const float*)d_in[3];
  const float* bd1 = (const float*)d_in[4];
  const float* Wd2 = (const float*)d_in[5];
  const float* bd2 = (const float*)d_in[6];
  const float* W1  = (const float*)d_in[7];
  const float* b1  = (const float*)d_in[8];
  const float* W2  = (const float*)d_in[9];
  const float* b2  = (const float*)d_in[10];
  const float* Wp1 = (const float*)d_in[11];
  const float* bp1 = (const float*)d_in[12];
  const float* Wp2 = (const float*)d_in[13];
  const float* bp2 = (const float*)d_in[14];
  const float* Wf  = (const float*)d_in[15];
  const float* bf_ = (const float*)d_in[16];
  float* out = (float*)d_out;
  float* ws  = (float*)d_ws;

  // workspace (float offsets), non-overlapping, 16B-aligned
  short* goidx_bf = (short*)(ws + 0);          // 10000 x 4096 bf16
  short* goidt_bf = (short*)(ws + 20480000);   // 10000 x 1280 bf16
  short* h1tmp_bf = (short*)(ws + 26880000);   // 10000 x 1024 bf16
  short* Wd1t = (short*)(ws + 32000000);       // 1024 x 4096
  short* Wd2t = (short*)(ws + 34097152);       // 1280 x 1024
  short* W1t  = (short*)(ws + 34752512);       //  256 x 1280 \ contiguous ->
  short* Wp1t = (short*)(ws + 34916352);       //  256 x 1280 / Wcomb[512][1280]
  short* W2t  = (short*)(ws + 35080192);       //  128 x 256
  short* xw1_bf = (short*)(ws + 35100000);     // 50000 x 256 bf16
  short* h1bf   = (short*)(ws + 41500000);     // 50000 x 256 bf16
  short* xw2_bf = (short*)(ws + 50460000);     // 50000 x 128 bf16
  short* h2bf   = (short*)(ws + 53660000);     // 50000 x 128 bf16
  float* deg    = ws + 60060000;               // 50,000
  int*   rowstart = (int*)(ws + 60150016);     // 40,000
  int*   cursor   = (int*)(ws + 60190016);     // 40,000
  int2*  edges    = (int2*)(ws + 60230016);    // 800,000 x 8B
  int*   gcount   = (int*)(ws + 61830016);     // 1
  short* Wp2t = (short*)(ws + 61830032);       // 128 x 256 (32768 shorts)
  short* Wft  = (short*)(ws + 61846416);       //  64 x 128 ( 8192 shorts)

  const float* gene_x = x;                          // rows 0..39999, lda=4096
  const float* goid_x = x + (size_t)kNGene * kGDim; // rows 40000..49999

  auto gb = [](int M, int Ncol) { return dim3((unsigned)(Ncol / 128), (unsigned)((M + 127) / 128)); };
  auto gw = [](int M, int Ncol) { return dim3((unsigned)(Ncol / 256), (unsigned)((M + 127) / 128)); };

  // 0) fused prep: goidx cvt + 7 weight transposes + deg init
  k_prep<<<kCvtBlocks + kTransBlocks + kInitBlocks, 256, 0, stream>>>(
      goid_x, goidx_bf, Wd1, Wd1t, Wd2, Wd2t, W1, W1t, Wp1, Wp1t,
      W2, W2t, Wp2, Wp2t, Wf, Wft, deg, gcount);

  // 1) degrees + CSR
  k_deg_hist<<<(kE + 255) / 256, 256, 0, stream>>>(ei, deg);
  k_rowassign<<<(kNGene + 255) / 256, 256, 0, stream>>>(deg, rowstart, cursor, gcount);
  k_fill<<<(kE + 255) / 256, 256, 0, stream>>>(ei, deg, cursor, edges);

  // 2) GOID MLP (wide tiles, 3-buffer counted-vmcnt pipeline)
  k_gemm_wide<1,1><<<gw(kNGoid, kD1), 512, 0, stream>>>(goidx_bf, kGDim, Wd1t, bd1,
                                                        h1tmp_bf, kD1, kNGoid, kGDim);
  k_gemm_wide<1,1><<<gw(kNGoid, kInDim), 512, 0, stream>>>(h1tmp_bf, kD1, Wd2t, bd2,
                                                           goidt_bf, kInDim, kNGoid, kD1);

  // 3) gene xw1 (single pass over gene_x)
  k_gemm_gene<<<dim3((kNGene + 127) / 128), 512, 0, stream>>>(gene_x, kGDim, W1t,
                                                              xw1_bf, kNGene, kInDim);

  // 4) combined goid GEMM: xw1 goid rows + bf16(p1) -> h1 goid rows
  k_combo_wide<<<dim3(2, (kNGoid + 127) / 128), 512, 0, stream>>>(
      goidt_bf, kInDim, W1t /*=Wcomb[512][1280]*/, bp1,
      xw1_bf + (size_t)kNGene * kH1, h1bf + (size_t)kNGene * kH1,
      kNGoid, kInDim);

  // 5) conv1: gather -> h1 bf16 gene rows
  k_gather_bf<kH1,1><<<(kNGene * 64 + 255) / 256, 256, 0, stream>>>(
      xw1_bf, deg, rowstart, edges, b1, h1bf);

  // 6) xw2 = h1 @ W2 -> bf16 message table (3-buffer pipeline)
  k_gemm_bf16a<0,1><<<gb(kN, kH2), 256, 0, stream>>>(h1bf, kH1, W2t, nullptr,
                                                     xw2_bf, kH2, kN, kH1);

  // 7) conv2: gather -> h2 bf16 gene rows; goid rows = h1goid@Wp2+bp2 (bf16)
  k_gather_bf<kH2,1><<<(kNGene * 64 + 255) / 256, 256, 0, stream>>>(
      xw2_bf, deg, rowstart, edges, b2, h2bf);
  k_gemm_bf16a<0,1><<<gb(kNGoid, kH2), 256, 0, stream>>>(
      h1bf + (size_t)kNGene * kH1, kH1, Wp2t, bp2,
      h2bf + (size_t)kNGene * kH2, kH2, kNGoid, kH1);

  // 8) out = h2 @ Wf + bf (bf16 MFMA, 256x64 tile)
  k_gemm_out<<<(kN + 255) / 256, 256, 0, stream>>>(h2bf, Wft, bf_, out, kN);
}

// Round 13
// 603.292 us; speedup vs baseline: 1.7318x; 1.0099x over previous
//
#include <hip/hip_runtime.h>

// Problem constants (from reference)
constexpr int kNGene = 40000;
constexpr int kNGoid = 10000;
constexpr int kN     = 50000;
constexpr int kE     = 800000;
constexpr int kInDim = 1280;
constexpr int kH1    = 256;
constexpr int kH2    = 128;
constexpr int kOut   = 64;
constexpr int kGDim  = 4096;
constexpr int kD1    = 1024;

typedef short bf16x8 __attribute__((ext_vector_type(8)));
typedef float f32x4  __attribute__((ext_vector_type(4)));

static __device__ __forceinline__ short f2bf(float f) {
  union { float f; unsigned u; } v; v.f = f;
  unsigned r = v.u + 0x7FFF + ((v.u >> 16) & 1);   // RNE; inputs are finite
  return (short)(r >> 16);
}
static __device__ __forceinline__ float bf2f(short s) {
  union { unsigned u; float f; } v;
  v.u = ((unsigned)(unsigned short)s) << 16;
  return v.f;
}
// async global->LDS, 16B/lane; LDS dest = base + lane*16 (wave-linear).
static __device__ __forceinline__ void gld16(const void* g, void* l) {
  __builtin_amdgcn_global_load_lds(
      (const __attribute__((address_space(1))) void*)g,
      (__attribute__((address_space(3))) void*)l, 16, 0, 0);
}
// counted-vmcnt pipeline barrier
template <int N>
static __device__ __forceinline__ void wait_barrier() {
  if constexpr (N == 0)      asm volatile("s_waitcnt vmcnt(0)" ::: "memory");
  else if constexpr (N == 3) asm volatile("s_waitcnt vmcnt(3)" ::: "memory");
  else                       asm volatile("s_waitcnt vmcnt(4)" ::: "memory");
  __builtin_amdgcn_s_barrier();
  asm volatile("" ::: "memory");
}
// LDS bank swizzle (rule #21: linear gld16 dest + permuted global source +
// permuted read). Within a 16-row/1024B segment, content of (row, chunk c)
// lands at slot s = c ^ ((row>>1)&3). Staging lane l covers (row l>>2,
// slot l&3) -> fetches global chunk (l&3)^((l>>3)&3) (still 64B-coalesced).
// Reader at (l15, l4) uses slot l4 ^ ((l15>>1)&3): 2 lanes/bank-quad.

// ---------------- fused prep: goidx cvt + 7 weight transposes + deg init ----
constexpr int kCvtBlocks   = 20000;  // 10000*4096/8/256
constexpr int kTransBlocks = 6088;   // 4096+1280+320+320+32+32+8
constexpr int kInitBlocks  = 196;    // ceil(50000/256)

__global__ __launch_bounds__(256)
void k_prep(const float* __restrict__ goid_x, short* __restrict__ goidx_bf,
            const float* __restrict__ Wd1, short* __restrict__ Wd1t,
            const float* __restrict__ Wd2, short* __restrict__ Wd2t,
            const float* __restrict__ W1,  short* __restrict__ W1t,
            const float* __restrict__ Wp1, short* __restrict__ Wp1t,
            const float* __restrict__ W2,  short* __restrict__ W2t,
            const float* __restrict__ Wp2, short* __restrict__ Wp2t,
            const float* __restrict__ Wf,  short* __restrict__ Wft,
            float* __restrict__ deg, int* __restrict__ gcount)
{
  __shared__ float t[32][33];
  int b = blockIdx.x;
  if (b < kCvtBlocks) {                       // goid_x -> bf16
    int idx = b * 256 + threadIdx.x;          // chunk of 8
    int r = idx >> 9;                         // 512 chunks per 4096-row
    int c = (idx & 511) << 3;
    const float* sp = goid_x + (size_t)r * kGDim + c;
    float4 v0 = *reinterpret_cast<const float4*>(sp);
    float4 v1 = *reinterpret_cast<const float4*>(sp + 4);
    bf16x8 o;
    o[0]=f2bf(v0.x); o[1]=f2bf(v0.y); o[2]=f2bf(v0.z); o[3]=f2bf(v0.w);
    o[4]=f2bf(v1.x); o[5]=f2bf(v1.y); o[6]=f2bf(v1.z); o[7]=f2bf(v1.w);
    *reinterpret_cast<bf16x8*>(goidx_bf + (size_t)r * kGDim + c) = o;
    return;
  }
  if (b >= kCvtBlocks + kTransBlocks) {       // deg init
    int i = (b - kCvtBlocks - kTransBlocks) * 256 + threadIdx.x;
    if (i < kN) deg[i] = 1.0f;
    if (i == 0) *gcount = 0;
    return;
  }
  // weight transpose fp32[K][N] -> bf16[N][K]
  int b2 = b - kCvtBlocks;
  const float* W; short* Wt; int K, N, bi;
  if (b2 < 4096)      { W = Wd1; Wt = Wd1t; K = 4096; N = 1024; bi = b2; }
  else if (b2 < 5376) { W = Wd2; Wt = Wd2t; K = 1024; N = 1280; bi = b2 - 4096; }
  else if (b2 < 5696) { W = W1;  Wt = W1t;  K = 1280; N = 256;  bi = b2 - 5376; }
  else if (b2 < 6016) { W = Wp1; Wt = Wp1t; K = 1280; N = 256;  bi = b2 - 5696; }
  else if (b2 < 6048) { W = W2;  Wt = W2t;  K = 256;  N = 128;  bi = b2 - 6016; }
  else if (b2 < 6080) { W = Wp2; Wt = Wp2t; K = 256;  N = 128;  bi = b2 - 6048; }
  else                { W = Wf;  Wt = Wft;  K = 128;  N = 64;   bi = b2 - 6080; }
  int nbx = N >> 5;
  int n0 = (bi % nbx) * 32, k0 = (bi / nbx) * 32;
  int tx = threadIdx.x & 31, ty = threadIdx.x >> 5;
#pragma unroll
  for (int p = 0; p < 4; ++p)
    t[ty + 8 * p][tx] = W[(size_t)(k0 + ty + 8 * p) * N + n0 + tx];
  __syncthreads();
#pragma unroll
  for (int p = 0; p < 4; ++p)
    Wt[(size_t)(n0 + ty + 8 * p) * K + k0 + tx] = f2bf(t[tx][ty + 8 * p]);
}

// ---------------- degree / CSR ----------------
__global__ void k_deg_hist(const int* __restrict__ ei, float* __restrict__ deg) {
  int e = blockIdx.x * blockDim.x + threadIdx.x;
  if (e < kE) atomicAdd(&deg[ei[kE + e]], 1.0f);
}
__global__ void k_rowassign(const float* __restrict__ deg, int* __restrict__ rowstart,
                            int* __restrict__ cursor, int* __restrict__ gcount) {
  int i = blockIdx.x * blockDim.x + threadIdx.x;
  int lane = threadIdx.x & 63;
  int c = (i < kNGene) ? ((int)deg[i] - 1) : 0;
  int incl = c;
#pragma unroll
  for (int off = 1; off < 64; off <<= 1) {
    int t = __shfl_up(incl, off, 64);
    if (lane >= off) incl += t;
  }
  int total = __shfl(incl, 63, 64);
  int base = 0;
  if (lane == 63) base = atomicAdd(gcount, total);
  base = __shfl(base, 63, 64);
  if (i < kNGene) {
    int s = base + incl - c;
    rowstart[i] = s;
    cursor[i] = s;
  }
}
__global__ void k_fill(const int* __restrict__ ei, const float* __restrict__ deg,
                       int* __restrict__ cursor, int2* __restrict__ edges) {
  int e = blockIdx.x * blockDim.x + threadIdx.x;
  if (e >= kE) return;
  int dst = ei[kE + e];
  if (dst >= kNGene) return;
  int src = ei[e];
  int pos = atomicAdd(&cursor[dst], 1);
  float nrm = rsqrtf(deg[src] * deg[dst]);
  edges[pos] = make_int2(src, __float_as_int(nrm));
}

// ---------------- fused gather aggregation (bf16 messages, packed edges) ----
template <int F, int OBF>
__global__ __launch_bounds__(256)
void k_gather_bf(const short* __restrict__ xw, const float* __restrict__ deg,
                 const int* __restrict__ rowstart, const int2* __restrict__ edges,
                 const float* __restrict__ bias, void* __restrict__ hv) {
  constexpr int VEC = F / 64;
  int row = (blockIdx.x * blockDim.x + threadIdx.x) >> 6;
  int lane = threadIdx.x & 63;
  if (row >= kNGene) return;
  float dg = deg[row];
  float inv = 1.0f / dg;
  float acc[VEC];
  {
    const short* xr = xw + (size_t)row * F + lane * VEC;
    if constexpr (VEC == 4) {
      short4 s = *reinterpret_cast<const short4*>(xr);
      acc[0] = bf2f(s.x) * inv; acc[1] = bf2f(s.y) * inv;
      acc[2] = bf2f(s.z) * inv; acc[3] = bf2f(s.w) * inv;
    } else {
      short2 s = *reinterpret_cast<const short2*>(xr);
      acc[0] = bf2f(s.x) * inv; acc[1] = bf2f(s.y) * inv;
    }
  }
  const int2* ep = edges + rowstart[row];
  int n = (int)dg - 1;
  int e = 0;
  for (; e + 1 < n; e += 2) {
    int2 p0 = ep[e], p1 = ep[e + 1];
    float n0 = __int_as_float(p0.y), n1 = __int_as_float(p1.y);
    const short* x0 = xw + (size_t)p0.x * F + lane * VEC;
    const short* x1 = xw + (size_t)p1.x * F + lane * VEC;
    if constexpr (VEC == 4) {
      short4 s0 = *reinterpret_cast<const short4*>(x0);
      short4 s1 = *reinterpret_cast<const short4*>(x1);
      acc[0] += bf2f(s0.x) * n0; acc[1] += bf2f(s0.y) * n0;
      acc[2] += bf2f(s0.z) * n0; acc[3] += bf2f(s0.w) * n0;
      acc[0] += bf2f(s1.x) * n1; acc[1] += bf2f(s1.y) * n1;
      acc[2] += bf2f(s1.z) * n1; acc[3] += bf2f(s1.w) * n1;
    } else {
      short2 s0 = *reinterpret_cast<const short2*>(x0);
      short2 s1 = *reinterpret_cast<const short2*>(x1);
      acc[0] += bf2f(s0.x) * n0; acc[1] += bf2f(s0.y) * n0;
      acc[0] += bf2f(s1.x) * n1; acc[1] += bf2f(s1.y) * n1;
    }
  }
  if (e < n) {
    int2 p0 = ep[e];
    float n0 = __int_as_float(p0.y);
    const short* x0 = xw + (size_t)p0.x * F + lane * VEC;
    if constexpr (VEC == 4) {
      short4 s0 = *reinterpret_cast<const short4*>(x0);
      acc[0] += bf2f(s0.x) * n0; acc[1] += bf2f(s0.y) * n0;
      acc[2] += bf2f(s0.z) * n0; acc[3] += bf2f(s0.w) * n0;
    } else {
      short2 s0 = *reinterpret_cast<const short2*>(x0);
      acc[0] += bf2f(s0.x) * n0; acc[1] += bf2f(s0.y) * n0;
    }
  }
#pragma unroll
  for (int v = 0; v < VEC; ++v) acc[v] = fmaxf(acc[v] + bias[lane * VEC + v], 0.f);
  if constexpr (OBF) {
    short* hp = (short*)hv + (size_t)row * F + lane * VEC;
    if constexpr (VEC == 4) {
      short4 o; o.x = f2bf(acc[0]); o.y = f2bf(acc[1]); o.z = f2bf(acc[2]); o.w = f2bf(acc[3]);
      *reinterpret_cast<short4*>(hp) = o;
    } else {
      short2 o; o.x = f2bf(acc[0]); o.y = f2bf(acc[1]);
      *reinterpret_cast<short2*>(hp) = o;
    }
  } else {
    float* hp = (float*)hv + (size_t)row * F + lane * VEC;
    if constexpr (VEC == 4) {
      float4 o; o.x = acc[0]; o.y = acc[1]; o.z = acc[2]; o.w = acc[3];
      *reinterpret_cast<float4*>(hp) = o;
    } else {
      float2 o; o.x = acc[0]; o.y = acc[1];
      *reinterpret_cast<float2*>(hp) = o;
    }
  }
}

// ---------------- bf16 MFMA GEMM, 128x128, 3-buffer pipeline, swizzled LDS --
template <int RELU, int OBF>
__global__ __launch_bounds__(256)
void k_gemm_bf16a(const short* __restrict__ A, int lda,
                  const short* __restrict__ Bt,
                  const float* __restrict__ bias,
                  void* __restrict__ Cv, int ldc,
                  int M, int K)
{
  __shared__ __align__(16) short As[3][128 * 32];
  __shared__ __align__(16) short Bs[3][128 * 32];
  const int tid  = threadIdx.x;
  const int lane = tid & 63;
  const int wid  = tid >> 6;
  const int wr = wid >> 1, wc = wid & 1;
  const int row0 = blockIdx.y * 128;
  const int col0 = blockIdx.x * 128;
  const int l15 = lane & 15, l4 = lane >> 4;
  const int srow = lane >> 2;
  const int schunk = (lane & 3) ^ ((lane >> 3) & 3);   // swizzled global source
  const int rslot8 = (l4 ^ ((l15 >> 1) & 3)) * 8;      // swizzled read slot

  f32x4 acc[4][4] = {};

  auto stage = [&](int buf, int k0) {   // 4 gld16 per wave
#pragma unroll
    for (int q = 0; q < 2; ++q) {
      int seg = wid * 2 + q;
      int r = seg * 16 + srow;
      int grow = row0 + r;
      if (grow >= M) grow = M - 1;
      gld16(A + (size_t)grow * lda + k0 + schunk * 8, &As[buf][seg * 512]);
      int gcol = col0 + r;
      gld16(Bt + (size_t)gcol * K + k0 + schunk * 8, &Bs[buf][seg * 512]);
    }
  };

  const int nt = K >> 5;
  stage(0, 0);
  if (nt > 1) { stage(1, 32); wait_barrier<4>(); }
  else        { wait_barrier<0>(); }

  for (int t = 0; t < nt; ++t) {
    if (t + 2 < nt) stage((t + 2) % 3, (t + 2) * 32);
    const int cur = t % 3;
    bf16x8 af[4], bfr[4];
#pragma unroll
    for (int m = 0; m < 4; ++m)
      af[m] = *reinterpret_cast<bf16x8*>(&As[cur][(wr * 64 + m * 16 + l15) * 32 + rslot8]);
#pragma unroll
    for (int n = 0; n < 4; ++n)
      bfr[n] = *reinterpret_cast<bf16x8*>(&Bs[cur][(wc * 64 + n * 16 + l15) * 32 + rslot8]);
#pragma unroll
    for (int m = 0; m < 4; ++m)
#pragma unroll
      for (int n = 0; n < 4; ++n)
        acc[m][n] = __builtin_amdgcn_mfma_f32_16x16x32_bf16(af[m], bfr[n], acc[m][n], 0, 0, 0);
    if (t + 1 < nt) {
      if (t + 2 < nt) wait_barrier<4>(); else wait_barrier<0>();
    }
  }

#pragma unroll
  for (int n = 0; n < 4; ++n) {
    int col = col0 + wc * 64 + n * 16 + l15;
    float bv = bias ? bias[col] : 0.f;
#pragma unroll
    for (int m = 0; m < 4; ++m) {
      int rb = row0 + wr * 64 + m * 16 + l4 * 4;
#pragma unroll
      for (int e = 0; e < 4; ++e) {
        int r = rb + e;
        if (r < M) {
          float v = acc[m][n][e] + bv;
          if (RELU) v = fmaxf(v, 0.f);
          size_t idx = (size_t)r * ldc + col;
          if constexpr (OBF) ((short*)Cv)[idx] = f2bf(v);
          else               ((float*)Cv)[idx] = v;
        }
      }
    }
  }
}

// ---------------- bf16 MFMA GEMM, 128x256, 8 waves, 3-buf, swizzled LDS -----
template <int RELU, int OBF>
__global__ __launch_bounds__(512)
void k_gemm_wide(const short* __restrict__ A, int lda,
                 const short* __restrict__ Bt,
                 const float* __restrict__ bias,
                 void* __restrict__ Cv, int ldc,
                 int M, int K)
{
  __shared__ __align__(16) short As[3][128 * 32];
  __shared__ __align__(16) short Bs[3][256 * 32];
  const int tid  = threadIdx.x;
  const int lane = tid & 63;
  const int wid  = tid >> 6;
  const int wr = wid >> 2, wc = wid & 3;
  // bijective XCD swizzle (m204)
  int nwg = gridDim.x * gridDim.y;
  int b0 = blockIdx.y * gridDim.x + blockIdx.x;
  int qq = nwg >> 3, rr = nwg & 7, xcd = b0 & 7, j = b0 >> 3;
  int swz = ((xcd < rr) ? xcd * (qq + 1) : rr * (qq + 1) + (xcd - rr) * qq) + j;
  const int row0 = (swz / gridDim.x) * 128;
  const int col0 = (swz % gridDim.x) * 256;
  const int l15 = lane & 15, l4 = lane >> 4;
  const int srow = lane >> 2;
  const int schunk = (lane & 3) ^ ((lane >> 3) & 3);
  const int rslot8 = (l4 ^ ((l15 >> 1) & 3)) * 8;

  f32x4 acc[4][4] = {};

  auto stage = [&](int buf, int k0) {   // 3 gld16 per wave
#pragma unroll
    for (int q = 0; q < 3; ++q) {
      int s = wid * 3 + q;
      if (s < 8) {
        int grow = row0 + s * 16 + srow;
        if (grow >= M) grow = M - 1;
        gld16(A + (size_t)grow * lda + k0 + schunk * 8, &As[buf][s * 512]);
      } else {
        int gcol = col0 + (s - 8) * 16 + srow;
        gld16(Bt + (size_t)gcol * K + k0 + schunk * 8, &Bs[buf][(s - 8) * 512]);
      }
    }
  };

  const int nt = K >> 5;
  stage(0, 0);
  if (nt > 1) { stage(1, 32); wait_barrier<3>(); }
  else        { wait_barrier<0>(); }

  for (int t = 0; t < nt; ++t) {
    if (t + 2 < nt) stage((t + 2) % 3, (t + 2) * 32);
    const int cur = t % 3;
    bf16x8 af[4], bfr[4];
#pragma unroll
    for (int m = 0; m < 4; ++m)
      af[m] = *reinterpret_cast<bf16x8*>(&As[cur][(wr * 64 + m * 16 + l15) * 32 + rslot8]);
#pragma unroll
    for (int n = 0; n < 4; ++n)
      bfr[n] = *reinterpret_cast<bf16x8*>(&Bs[cur][(wc * 64 + n * 16 + l15) * 32 + rslot8]);
#pragma unroll
    for (int m = 0; m < 4; ++m)
#pragma unroll
      for (int n = 0; n < 4; ++n)
        acc[m][n] = __builtin_amdgcn_mfma_f32_16x16x32_bf16(af[m], bfr[n], acc[m][n], 0, 0, 0);
    if (t + 1 < nt) {
      if (t + 2 < nt) wait_barrier<3>(); else wait_barrier<0>();
    }
  }

#pragma unroll
  for (int n = 0; n < 4; ++n) {
    int col = col0 + wc * 64 + n * 16 + l15;
    float bv = bias ? bias[col] : 0.f;
#pragma unroll
    for (int m = 0; m < 4; ++m) {
      int rb = row0 + wr * 64 + m * 16 + l4 * 4;
#pragma unroll
      for (int e = 0; e < 4; ++e) {
        int r = rb + e;
        if (r < M) {
          float v = acc[m][n][e] + bv;
          if (RELU) v = fmaxf(v, 0.f);
          size_t idx = (size_t)r * ldc + col;
          if constexpr (OBF) ((short*)Cv)[idx] = f2bf(v);
          else               ((float*)Cv)[idx] = v;
        }
      }
    }
  }
}

// ---------------- combined goid GEMM (128x256, 8 waves, 2-buf, swizzled) ----
__global__ __launch_bounds__(512)
void k_combo_wide(const short* __restrict__ A, int lda,
                  const short* __restrict__ Bt,
                  const float* __restrict__ bp1,
                  short* __restrict__ X1, short* __restrict__ H1,
                  int M, int K)
{
  __shared__ __align__(16) short As[2][128 * 32];
  __shared__ __align__(16) short Bs[2][256 * 32];
  const int tid  = threadIdx.x;
  const int lane = tid & 63;
  const int wid  = tid >> 6;
  const int wr = wid >> 2, wc = wid & 3;
  const int row0 = blockIdx.y * 128;
  const int col0 = blockIdx.x * 256;
  const int l15 = lane & 15, l4 = lane >> 4;
  const int srow = lane >> 2;
  const int schunk = (lane & 3) ^ ((lane >> 3) & 3);
  const int rslot8 = (l4 ^ ((l15 >> 1) & 3)) * 8;

  f32x4 acc[4][4] = {};

  auto stage = [&](int buf, int k0) {
#pragma unroll
    for (int q = 0; q < 3; ++q) {
      int s = wid * 3 + q;
      if (s < 8) {
        int grow = row0 + s * 16 + srow;
        if (grow >= M) grow = M - 1;
        gld16(A + (size_t)grow * lda + k0 + schunk * 8, &As[buf][s * 512]);
      } else {
        int gcol = col0 + (s - 8) * 16 + srow;
        gld16(Bt + (size_t)gcol * K + k0 + schunk * 8, &Bs[buf][(s - 8) * 512]);
      }
    }
  };

  stage(0, 0);
  __syncthreads();
  int cur = 0;
  for (int k0 = 0; k0 < K; k0 += 32) {
    if (k0 + 32 < K) stage(cur ^ 1, k0 + 32);
    bf16x8 af[4], bfr[4];
#pragma unroll
    for (int m = 0; m < 4; ++m)
      af[m] = *reinterpret_cast<bf16x8*>(&As[cur][(wr * 64 + m * 16 + l15) * 32 + rslot8]);
#pragma unroll
    for (int n = 0; n < 4; ++n)
      bfr[n] = *reinterpret_cast<bf16x8*>(&Bs[cur][(wc * 64 + n * 16 + l15) * 32 + rslot8]);
#pragma unroll
    for (int m = 0; m < 4; ++m)
#pragma unroll
      for (int n = 0; n < 4; ++n)
        acc[m][n] = __builtin_amdgcn_mfma_f32_16x16x32_bf16(af[m], bfr[n], acc[m][n], 0, 0, 0);
    __syncthreads();
    cur ^= 1;
  }

  const int is_p1 = (col0 >= 256);
  short* dstp = is_p1 ? H1 : X1;
#pragma unroll
  for (int n = 0; n < 4; ++n) {
    int cl = wc * 64 + n * 16 + l15;
    float bv = is_p1 ? bp1[cl] : 0.f;
#pragma unroll
    for (int m = 0; m < 4; ++m) {
      int rb = row0 + wr * 64 + m * 16 + l4 * 4;
#pragma unroll
      for (int e = 0; e < 4; ++e) {
        int r = rb + e;
        if (r < M) dstp[(size_t)r * 256 + cl] = f2bf(acc[m][n][e] + bv);
      }
    }
  }
}

// ---------------- gene xw1: fp32-A, 128x256, 8 waves, 2-buf, swz B ----------
__global__ __launch_bounds__(512)
void k_gemm_gene(const float* __restrict__ A, int lda,
                 const short* __restrict__ Bt,
                 short* __restrict__ C,   // [M][256] bf16
                 int M, int K)
{
  __shared__ short As[2][128 * 40];              // pad-40 VALU-staged (2-way ok)
  __shared__ __align__(16) short Bs[2][256 * 32];
  const int tid  = threadIdx.x;
  const int lane = tid & 63;
  const int wid  = tid >> 6;
  const int wr = wid >> 2, wc = wid & 3;
  const int row0 = blockIdx.x * 128;
  const int l15 = lane & 15, l4 = lane >> 4;
  const int sr = tid >> 2, sc = tid & 3;
  const int srow = lane >> 2;
  const int schunk = (lane & 3) ^ ((lane >> 3) & 3);
  const int rslot8 = (l4 ^ ((l15 >> 1) & 3)) * 8;

  f32x4 acc[4][4] = {};

  auto stageB = [&](int buf, int k0) {
#pragma unroll
    for (int q = 0; q < 2; ++q) {
      int seg = wid * 2 + q;
      int gcol = seg * 16 + srow;
      gld16(Bt + (size_t)gcol * K + k0 + schunk * 8, &Bs[buf][seg * 512]);
    }
  };
  auto stageA = [&](int buf, int k0) {
    int grow = row0 + sr;
    float4 v0 = make_float4(0.f,0.f,0.f,0.f), v1 = v0;
    if (grow < M) {
      const float* ap = A + (size_t)grow * lda + k0 + sc * 8;
      v0 = *reinterpret_cast<const float4*>(ap);
      v1 = *reinterpret_cast<const float4*>(ap + 4);
    }
    bf16x8 t;
    t[0]=f2bf(v0.x); t[1]=f2bf(v0.y); t[2]=f2bf(v0.z); t[3]=f2bf(v0.w);
    t[4]=f2bf(v1.x); t[5]=f2bf(v1.y); t[6]=f2bf(v1.z); t[7]=f2bf(v1.w);
    *reinterpret_cast<bf16x8*>(&As[buf][sr * 40 + sc * 8]) = t;
  };

  stageB(0, 0); stageA(0, 0);
  __syncthreads();
  int cur = 0;
  for (int k0 = 0; k0 < K; k0 += 32) {
    if (k0 + 32 < K) { stageB(cur ^ 1, k0 + 32); stageA(cur ^ 1, k0 + 32); }
    bf16x8 af[4], bfr[4];
#pragma unroll
    for (int m = 0; m < 4; ++m)
      af[m] = *reinterpret_cast<bf16x8*>(&As[cur][(wr * 64 + m * 16 + l15) * 40 + l4 * 8]);
#pragma unroll
    for (int n = 0; n < 4; ++n)
      bfr[n] = *reinterpret_cast<bf16x8*>(&Bs[cur][(wc * 64 + n * 16 + l15) * 32 + rslot8]);
#pragma unroll
    for (int m = 0; m < 4; ++m)
#pragma unroll
      for (int n = 0; n < 4; ++n)
        acc[m][n] = __builtin_amdgcn_mfma_f32_16x16x32_bf16(af[m], bfr[n], acc[m][n], 0, 0, 0);
    __syncthreads();
    cur ^= 1;
  }

#pragma unroll
  for (int n = 0; n < 4; ++n) {
    int col = wc * 64 + n * 16 + l15;
#pragma unroll
    for (int m = 0; m < 4; ++m) {
      int rb = row0 + wr * 64 + m * 16 + l4 * 4;
#pragma unroll
      for (int e = 0; e < 4; ++e) {
        int r = rb + e;
        if (r < M) C[(size_t)r * 256 + col] = f2bf(acc[m][n][e]);
      }
    }
  }
}

// ---------------- out layer: h2bf[M][128] @ Wft[64][128] + bf -> out fp32 ----
__global__ __launch_bounds__(256)
void k_gemm_out(const short* __restrict__ A,      // h2bf, lda=128
                const short* __restrict__ Bt,     // Wft [64][128]
                const float* __restrict__ bias,
                float* __restrict__ C,            // [M][64]
                int M)
{
  __shared__ __align__(16) short As[2][256 * 32];
  __shared__ __align__(16) short Bs[2][64 * 32];
  const int tid  = threadIdx.x;
  const int lane = tid & 63;
  const int wid  = tid >> 6;
  const int row0 = blockIdx.x * 256;
  const int l15 = lane & 15, l4 = lane >> 4;
  const int srow = lane >> 2;
  const int schunk = (lane & 3) ^ ((lane >> 3) & 3);
  const int rslot8 = (l4 ^ ((l15 >> 1) & 3)) * 8;

  f32x4 acc[4][4] = {};

  auto stage = [&](int buf, int k0) {   // 5 gld16 per wave
#pragma unroll
    for (int q = 0; q < 4; ++q) {
      int seg = wid * 4 + q;            // 0..15
      int grow = row0 + seg * 16 + srow;
      if (grow >= M) grow = M - 1;
      gld16(A + (size_t)grow * 128 + k0 + schunk * 8, &As[buf][seg * 512]);
    }
    int gcol = wid * 16 + srow;         // 0..63
    gld16(Bt + (size_t)gcol * 128 + k0 + schunk * 8, &Bs[buf][wid * 512]);
  };

  stage(0, 0);
  __syncthreads();
  int cur = 0;
  for (int k0 = 0; k0 < 128; k0 += 32) {
    if (k0 + 32 < 128) stage(cur ^ 1, k0 + 32);
    bf16x8 af[4], bfr[4];
#pragma unroll
    for (int m = 0; m < 4; ++m)
      af[m] = *reinterpret_cast<bf16x8*>(&As[cur][(wid * 64 + m * 16 + l15) * 32 + rslot8]);
#pragma unroll
    for (int n = 0; n < 4; ++n)
      bfr[n] = *reinterpret_cast<bf16x8*>(&Bs[cur][(n * 16 + l15) * 32 + rslot8]);
#pragma unroll
    for (int m = 0; m < 4; ++m)
#pragma unroll
      for (int n = 0; n < 4; ++n)
        acc[m][n] = __builtin_amdgcn_mfma_f32_16x16x32_bf16(af[m], bfr[n], acc[m][n], 0, 0, 0);
    __syncthreads();
    cur ^= 1;
  }

#pragma unroll
  for (int n = 0; n < 4; ++n) {
    int col = n * 16 + l15;
    float bv = bias[col];
#pragma unroll
    for (int m = 0; m < 4; ++m) {
      int rb = row0 + wid * 64 + m * 16 + l4 * 4;
#pragma unroll
      for (int e = 0; e < 4; ++e) {
        int r = rb + e;
        if (r < M) C[(size_t)r * 64 + col] = acc[m][n][e] + bv;
      }
    }
  }
}

extern "C" void kernel_launch(void* const* d_in, const int* in_sizes, int n_in,
                              void* d_out, int out_size, void* d_ws, size_t ws_size,
                              hipStream_t stream) {
  const float* x   = (const float*)d_in[0];
  const int*   ei  = (const int*)d_in[1];
  const float* Wd1 = (const float*)d_in[3];
  const float* bd1 = (const float*)d_in[4];
  const float* Wd2 = (const float*)d_in[5];
  const float* bd2 = (const float*)d_in[6];
  const float* W1  = (const float*)d_in[7];
  const float* b1  = (const float*)d_in[8];
  const float* W2  = (const float*)d_in[9];
  const float* b2  = (const float*)d_in[10];
  const float* Wp1 = (const float*)d_in[11];
  const float* bp1 = (const float*)d_in[12];
  const float* Wp2 = (const float*)d_in[13];
  const float* bp2 = (const float*)d_in[14];
  const float* Wf  = (const float*)d_in[15];
  const float* bf_ = (const float*)d_in[16];
  float* out = (float*)d_out;
  float* ws  = (float*)d_ws;

  // workspace (float offsets), non-overlapping, 16B-aligned
  short* goidx_bf = (short*)(ws + 0);          // 10000 x 4096 bf16
  short* goidt_bf = (short*)(ws + 20480000);   // 10000 x 1280 bf16
  short* h1tmp_bf = (short*)(ws + 26880000);   // 10000 x 1024 bf16
  short* Wd1t = (short*)(ws + 32000000);       // 1024 x 4096
  short* Wd2t = (short*)(ws + 34097152);       // 1280 x 1024
  short* W1t  = (short*)(ws + 34752512);       //  256 x 1280 \ contiguous ->
  short* Wp1t = (short*)(ws + 34916352);       //  256 x 1280 / Wcomb[512][1280]
  short* W2t  = (short*)(ws + 35080192);       //  128 x 256
  short* xw1_bf = (short*)(ws + 35100000);     // 50000 x 256 bf16
  short* h1bf   = (short*)(ws + 41500000);     // 50000 x 256 bf16
  short* xw2_bf = (short*)(ws + 50460000);     // 50000 x 128 bf16
  short* h2bf   = (short*)(ws + 53660000);     // 50000 x 128 bf16
  float* deg    = ws + 60060000;               // 50,000
  int*   rowstart = (int*)(ws + 60150016);     // 40,000
  int*   cursor   = (int*)(ws + 60190016);     // 40,000
  int2*  edges    = (int2*)(ws + 60230016);    // 800,000 x 8B
  int*   gcount   = (int*)(ws + 61830016);     // 1
  short* Wp2t = (short*)(ws + 61830032);       // 128 x 256
  short* Wft  = (short*)(ws + 61846416);       //  64 x 128

  const float* gene_x = x;                          // rows 0..39999, lda=4096
  const float* goid_x = x + (size_t)kNGene * kGDim; // rows 40000..49999

  auto gb = [](int M, int Ncol) { return dim3((unsigned)(Ncol / 128), (unsigned)((M + 127) / 128)); };
  auto gw = [](int M, int Ncol) { return dim3((unsigned)(Ncol / 256), (unsigned)((M + 127) / 128)); };

  // 0) fused prep: goidx cvt + 7 weight transposes + deg init
  k_prep<<<kCvtBlocks + kTransBlocks + kInitBlocks, 256, 0, stream>>>(
      goid_x, goidx_bf, Wd1, Wd1t, Wd2, Wd2t, W1, W1t, Wp1, Wp1t,
      W2, W2t, Wp2, Wp2t, Wf, Wft, deg, gcount);

  // 1) degrees + CSR
  k_deg_hist<<<(kE + 255) / 256, 256, 0, stream>>>(ei, deg);
  k_rowassign<<<(kNGene + 255) / 256, 256, 0, stream>>>(deg, rowstart, cursor, gcount);
  k_fill<<<(kE + 255) / 256, 256, 0, stream>>>(ei, deg, cursor, edges);

  // 2) GOID MLP (wide tiles, 3-buffer counted-vmcnt pipeline, swizzled LDS)
  k_gemm_wide<1,1><<<gw(kNGoid, kD1), 512, 0, stream>>>(goidx_bf, kGDim, Wd1t, bd1,
                                                        h1tmp_bf, kD1, kNGoid, kGDim);
  k_gemm_wide<1,1><<<gw(kNGoid, kInDim), 512, 0, stream>>>(h1tmp_bf, kD1, Wd2t, bd2,
                                                           goidt_bf, kInDim, kNGoid, kD1);

  // 3) gene xw1 (single pass over gene_x)
  k_gemm_gene<<<dim3((kNGene + 127) / 128), 512, 0, stream>>>(gene_x, kGDim, W1t,
                                                              xw1_bf, kNGene, kInDim);

  // 4) combined goid GEMM: xw1 goid rows + bf16(p1) -> h1 goid rows
  k_combo_wide<<<dim3(2, (kNGoid + 127) / 128), 512, 0, stream>>>(
      goidt_bf, kInDim, W1t /*=Wcomb[512][1280]*/, bp1,
      xw1_bf + (size_t)kNGene * kH1, h1bf + (size_t)kNGene * kH1,
      kNGoid, kInDim);

  // 5) conv1: gather -> h1 bf16 gene rows
  k_gather_bf<kH1,1><<<(kNGene * 64 + 255) / 256, 256, 0, stream>>>(
      xw1_bf, deg, rowstart, edges, b1, h1bf);

  // 6) xw2 = h1 @ W2 -> bf16 message table
  k_gemm_bf16a<0,1><<<gb(kN, kH2), 256, 0, stream>>>(h1bf, kH1, W2t, nullptr,
                                                     xw2_bf, kH2, kN, kH1);

  // 7) conv2: gather -> h2 bf16 gene rows; goid rows = h1goid@Wp2+bp2 (bf16)
  k_gather_bf<kH2,1><<<(kNGene * 64 + 255) / 256, 256, 0, stream>>>(
      xw2_bf, deg, rowstart, edges, b2, h2bf);
  k_gemm_bf16a<0,1><<<gb(kNGoid, kH2), 256, 0, stream>>>(
      h1bf + (size_t)kNGene * kH1, kH1, Wp2t, bp2,
      h2bf + (size_t)kNGene * kH2, kH2, kNGoid, kH1);

  // 8) out = h2 @ Wf + bf (bf16 MFMA, 256x64 tile)
  k_gemm_out<<<(kN + 255) / 256, 256, 0, stream>>>(h2bf, Wft, bf_, out, kN);
}

// Round 14
// 572.978 us; speedup vs baseline: 1.8234x; 1.0529x over previous
//
#include <hip/hip_runtime.h>

// Problem constants (from reference)
constexpr int kNGene = 40000;
constexpr int kNGoid = 10000;
constexpr int kN     = 50000;
constexpr int kE     = 800000;
constexpr int kInDim = 1280;
constexpr int kH1    = 256;
constexpr int kH2    = 128;
constexpr int kOut   = 64;
constexpr int kGDim  = 4096;
constexpr int kD1    = 1024;

typedef short bf16x8 __attribute__((ext_vector_type(8)));
typedef float f32x4  __attribute__((ext_vector_type(4)));

static __device__ __forceinline__ short f2bf(float f) {
  union { float f; unsigned u; } v; v.f = f;
  unsigned r = v.u + 0x7FFF + ((v.u >> 16) & 1);   // RNE; inputs are finite
  return (short)(r >> 16);
}
static __device__ __forceinline__ float bf2f(short s) {
  union { unsigned u; float f; } v;
  v.u = ((unsigned)(unsigned short)s) << 16;
  return v.f;
}
// async global->LDS, 16B/lane; LDS dest = base + lane*16 (wave-linear).
static __device__ __forceinline__ void gld16(const void* g, void* l) {
  __builtin_amdgcn_global_load_lds(
      (const __attribute__((address_space(1))) void*)g,
      (__attribute__((address_space(3))) void*)l, 16, 0, 0);
}
// counted-vmcnt pipeline barrier
template <int N>
static __device__ __forceinline__ void wait_barrier() {
  if constexpr (N == 0)      asm volatile("s_waitcnt vmcnt(0)" ::: "memory");
  else if constexpr (N == 3) asm volatile("s_waitcnt vmcnt(3)" ::: "memory");
  else                       asm volatile("s_waitcnt vmcnt(4)" ::: "memory");
  __builtin_amdgcn_s_barrier();
  asm volatile("" ::: "memory");
}

// ---------------- fused prep: goidx cvt + 7 weight transposes + deg init ----
constexpr int kCvtBlocks   = 20000;  // 10000*4096/8/256
constexpr int kTransBlocks = 6088;   // 4096+1280+320+320+32+32+8
constexpr int kInitBlocks  = 196;    // ceil(50000/256)

__global__ __launch_bounds__(256)
void k_prep(const float* __restrict__ goid_x, short* __restrict__ goidx_bf,
            const float* __restrict__ Wd1, short* __restrict__ Wd1t,
            const float* __restrict__ Wd2, short* __restrict__ Wd2t,
            const float* __restrict__ W1,  short* __restrict__ W1t,
            const float* __restrict__ Wp1, short* __restrict__ Wp1t,
            const float* __restrict__ W2,  short* __restrict__ W2t,
            const float* __restrict__ Wp2, short* __restrict__ Wp2t,
            const float* __restrict__ Wf,  short* __restrict__ Wft,
            float* __restrict__ deg, int* __restrict__ gcount)
{
  __shared__ float t[32][33];
  int b = blockIdx.x;
  if (b < kCvtBlocks) {                       // goid_x -> bf16
    int idx = b * 256 + threadIdx.x;          // chunk of 8
    int r = idx >> 9;
    int c = (idx & 511) << 3;
    const float* sp = goid_x + (size_t)r * kGDim + c;
    float4 v0 = *reinterpret_cast<const float4*>(sp);
    float4 v1 = *reinterpret_cast<const float4*>(sp + 4);
    bf16x8 o;
    o[0]=f2bf(v0.x); o[1]=f2bf(v0.y); o[2]=f2bf(v0.z); o[3]=f2bf(v0.w);
    o[4]=f2bf(v1.x); o[5]=f2bf(v1.y); o[6]=f2bf(v1.z); o[7]=f2bf(v1.w);
    *reinterpret_cast<bf16x8*>(goidx_bf + (size_t)r * kGDim + c) = o;
    return;
  }
  if (b >= kCvtBlocks + kTransBlocks) {       // deg init
    int i = (b - kCvtBlocks - kTransBlocks) * 256 + threadIdx.x;
    if (i < kN) deg[i] = 1.0f;
    if (i == 0) *gcount = 0;
    return;
  }
  int b2 = b - kCvtBlocks;
  const float* W; short* Wt; int K, N, bi;
  if (b2 < 4096)      { W = Wd1; Wt = Wd1t; K = 4096; N = 1024; bi = b2; }
  else if (b2 < 5376) { W = Wd2; Wt = Wd2t; K = 1024; N = 1280; bi = b2 - 4096; }
  else if (b2 < 5696) { W = W1;  Wt = W1t;  K = 1280; N = 256;  bi = b2 - 5376; }
  else if (b2 < 6016) { W = Wp1; Wt = Wp1t; K = 1280; N = 256;  bi = b2 - 5696; }
  else if (b2 < 6048) { W = W2;  Wt = W2t;  K = 256;  N = 128;  bi = b2 - 6016; }
  else if (b2 < 6080) { W = Wp2; Wt = Wp2t; K = 256;  N = 128;  bi = b2 - 6048; }
  else                { W = Wf;  Wt = Wft;  K = 128;  N = 64;   bi = b2 - 6080; }
  int nbx = N >> 5;
  int n0 = (bi % nbx) * 32, k0 = (bi / nbx) * 32;
  int tx = threadIdx.x & 31, ty = threadIdx.x >> 5;
#pragma unroll
  for (int p = 0; p < 4; ++p)
    t[ty + 8 * p][tx] = W[(size_t)(k0 + ty + 8 * p) * N + n0 + tx];
  __syncthreads();
#pragma unroll
  for (int p = 0; p < 4; ++p)
    Wt[(size_t)(n0 + ty + 8 * p) * K + k0 + tx] = f2bf(t[tx][ty + 8 * p]);
}

// ---------------- CSR device pieces (512-thread blocks) ----------------
static __device__ void dev_hist(const int* __restrict__ ei, float* __restrict__ deg,
                                int bid) {
  int e = bid * 512 + threadIdx.x;
  if (e < kE) atomicAdd(&deg[ei[kE + e]], 1.0f);
}
static __device__ void dev_rowassign(const float* __restrict__ deg,
                                     int* __restrict__ rowstart,
                                     int* __restrict__ cursor,
                                     int* __restrict__ gcount, int bid) {
  int i = bid * 512 + threadIdx.x;
  int lane = threadIdx.x & 63;
  int c = (i < kNGene) ? ((int)deg[i] - 1) : 0;
  int incl = c;
#pragma unroll
  for (int off = 1; off < 64; off <<= 1) {
    int t = __shfl_up(incl, off, 64);
    if (lane >= off) incl += t;
  }
  int total = __shfl(incl, 63, 64);
  int base = 0;
  if (lane == 63) base = atomicAdd(gcount, total);
  base = __shfl(base, 63, 64);
  if (i < kNGene) {
    int s = base + incl - c;
    rowstart[i] = s;
    cursor[i] = s;
  }
}
static __device__ void dev_fill(const int* __restrict__ ei, const float* __restrict__ deg,
                                int* __restrict__ cursor, int2* __restrict__ edges,
                                int bid) {
  int e = bid * 512 + threadIdx.x;
  if (e >= kE) return;
  int dst = ei[kE + e];
  if (dst >= kNGene) return;
  int src = ei[e];
  int pos = atomicAdd(&cursor[dst], 1);
  float nrm = rsqrtf(deg[src] * deg[dst]);
  edges[pos] = make_int2(src, __float_as_int(nrm));
}

// ---------------- fused gather aggregation (bf16 messages, packed edges) ----
template <int F, int OBF>
__global__ __launch_bounds__(256)
void k_gather_bf(const short* __restrict__ xw, const float* __restrict__ deg,
                 const int* __restrict__ rowstart, const int2* __restrict__ edges,
                 const float* __restrict__ bias, void* __restrict__ hv) {
  constexpr int VEC = F / 64;
  int row = (blockIdx.x * blockDim.x + threadIdx.x) >> 6;
  int lane = threadIdx.x & 63;
  if (row >= kNGene) return;
  float dg = deg[row];
  float inv = 1.0f / dg;
  float acc[VEC];
  {
    const short* xr = xw + (size_t)row * F + lane * VEC;
    if constexpr (VEC == 4) {
      short4 s = *reinterpret_cast<const short4*>(xr);
      acc[0] = bf2f(s.x) * inv; acc[1] = bf2f(s.y) * inv;
      acc[2] = bf2f(s.z) * inv; acc[3] = bf2f(s.w) * inv;
    } else {
      short2 s = *reinterpret_cast<const short2*>(xr);
      acc[0] = bf2f(s.x) * inv; acc[1] = bf2f(s.y) * inv;
    }
  }
  const int2* ep = edges + rowstart[row];
  int n = (int)dg - 1;
  int e = 0;
  for (; e + 1 < n; e += 2) {
    int2 p0 = ep[e], p1 = ep[e + 1];
    float n0 = __int_as_float(p0.y), n1 = __int_as_float(p1.y);
    const short* x0 = xw + (size_t)p0.x * F + lane * VEC;
    const short* x1 = xw + (size_t)p1.x * F + lane * VEC;
    if constexpr (VEC == 4) {
      short4 s0 = *reinterpret_cast<const short4*>(x0);
      short4 s1 = *reinterpret_cast<const short4*>(x1);
      acc[0] += bf2f(s0.x) * n0; acc[1] += bf2f(s0.y) * n0;
      acc[2] += bf2f(s0.z) * n0; acc[3] += bf2f(s0.w) * n0;
      acc[0] += bf2f(s1.x) * n1; acc[1] += bf2f(s1.y) * n1;
      acc[2] += bf2f(s1.z) * n1; acc[3] += bf2f(s1.w) * n1;
    } else {
      short2 s0 = *reinterpret_cast<const short2*>(x0);
      short2 s1 = *reinterpret_cast<const short2*>(x1);
      acc[0] += bf2f(s0.x) * n0; acc[1] += bf2f(s0.y) * n0;
      acc[0] += bf2f(s1.x) * n1; acc[1] += bf2f(s1.y) * n1;
    }
  }
  if (e < n) {
    int2 p0 = ep[e];
    float n0 = __int_as_float(p0.y);
    const short* x0 = xw + (size_t)p0.x * F + lane * VEC;
    if constexpr (VEC == 4) {
      short4 s0 = *reinterpret_cast<const short4*>(x0);
      acc[0] += bf2f(s0.x) * n0; acc[1] += bf2f(s0.y) * n0;
      acc[2] += bf2f(s0.z) * n0; acc[3] += bf2f(s0.w) * n0;
    } else {
      short2 s0 = *reinterpret_cast<const short2*>(x0);
      acc[0] += bf2f(s0.x) * n0; acc[1] += bf2f(s0.y) * n0;
    }
  }
#pragma unroll
  for (int v = 0; v < VEC; ++v) acc[v] = fmaxf(acc[v] + bias[lane * VEC + v], 0.f);
  if constexpr (OBF) {
    short* hp = (short*)hv + (size_t)row * F + lane * VEC;
    if constexpr (VEC == 4) {
      short4 o; o.x = f2bf(acc[0]); o.y = f2bf(acc[1]); o.z = f2bf(acc[2]); o.w = f2bf(acc[3]);
      *reinterpret_cast<short4*>(hp) = o;
    } else {
      short2 o; o.x = f2bf(acc[0]); o.y = f2bf(acc[1]);
      *reinterpret_cast<short2*>(hp) = o;
    }
  } else {
    float* hp = (float*)hv + (size_t)row * F + lane * VEC;
    if constexpr (VEC == 4) {
      float4 o; o.x = acc[0]; o.y = acc[1]; o.z = acc[2]; o.w = acc[3];
      *reinterpret_cast<float4*>(hp) = o;
    } else {
      float2 o; o.x = acc[0]; o.y = acc[1];
      *reinterpret_cast<float2*>(hp) = o;
    }
  }
}

// ---------------- dev: bf16 GEMM 128x256, 8 waves, 2-buf, swizzled LDS ------
// As: 2 x 4096 shorts, Bs: 2 x 8192 shorts (caller partitions dynamic LDS).
template <int RELU, int OBF>
static __device__ void dev_wide(const short* __restrict__ A, int lda,
                                const short* __restrict__ Bt,
                                const float* __restrict__ bias,
                                void* __restrict__ Cv, int ldc,
                                int M, int K, int b0, int nbx, int nwg,
                                short* As, short* Bs)
{
  const int tid  = threadIdx.x;
  const int lane = tid & 63;
  const int wid  = tid >> 6;        // 0..7
  const int wr = wid >> 2, wc = wid & 3;
  // bijective XCD swizzle (m204)
  int qq = nwg >> 3, rr = nwg & 7, xcd = b0 & 7, j = b0 >> 3;
  int swz = ((xcd < rr) ? xcd * (qq + 1) : rr * (qq + 1) + (xcd - rr) * qq) + j;
  const int row0 = (swz / nbx) * 128;
  const int col0 = (swz % nbx) * 256;
  const int l15 = lane & 15, l4 = lane >> 4;
  const int srow = lane >> 2;
  const int schunk = (lane & 3) ^ ((lane >> 3) & 3);
  const int rslot8 = (l4 ^ ((l15 >> 1) & 3)) * 8;

  f32x4 acc[4][4] = {};

  auto stage = [&](int buf, int k0) {
#pragma unroll
    for (int q = 0; q < 3; ++q) {
      int s = wid * 3 + q;
      if (s < 8) {
        int grow = row0 + s * 16 + srow;
        if (grow >= M) grow = M - 1;
        gld16(A + (size_t)grow * lda + k0 + schunk * 8, As + buf * 4096 + s * 512);
      } else {
        int gcol = col0 + (s - 8) * 16 + srow;
        gld16(Bt + (size_t)gcol * K + k0 + schunk * 8, Bs + buf * 8192 + (s - 8) * 512);
      }
    }
  };

  stage(0, 0);
  __syncthreads();
  int cur = 0;
  for (int k0 = 0; k0 < K; k0 += 32) {
    if (k0 + 32 < K) stage(cur ^ 1, k0 + 32);
    bf16x8 af[4], bfr[4];
#pragma unroll
    for (int m = 0; m < 4; ++m)
      af[m] = *reinterpret_cast<bf16x8*>(As + cur * 4096 + (wr * 64 + m * 16 + l15) * 32 + rslot8);
#pragma unroll
    for (int n = 0; n < 4; ++n)
      bfr[n] = *reinterpret_cast<bf16x8*>(Bs + cur * 8192 + (wc * 64 + n * 16 + l15) * 32 + rslot8);
#pragma unroll
    for (int m = 0; m < 4; ++m)
#pragma unroll
      for (int n = 0; n < 4; ++n)
        acc[m][n] = __builtin_amdgcn_mfma_f32_16x16x32_bf16(af[m], bfr[n], acc[m][n], 0, 0, 0);
    __syncthreads();
    cur ^= 1;
  }

#pragma unroll
  for (int n = 0; n < 4; ++n) {
    int col = col0 + wc * 64 + n * 16 + l15;
    float bv = bias ? bias[col] : 0.f;
#pragma unroll
    for (int m = 0; m < 4; ++m) {
      int rb = row0 + wr * 64 + m * 16 + l4 * 4;
#pragma unroll
      for (int e = 0; e < 4; ++e) {
        int r = rb + e;
        if (r < M) {
          float v = acc[m][n][e] + bv;
          if (RELU) v = fmaxf(v, 0.f);
          size_t idx = (size_t)r * ldc + col;
          if constexpr (OBF) ((short*)Cv)[idx] = f2bf(v);
          else               ((float*)Cv)[idx] = v;
        }
      }
    }
  }
}

// ---------------- dev: gene xw1, fp32-A, 128x256, 8 waves, 2-buf ------------
// As: 2 x 5120 shorts (pad-40), Bs: 2 x 8192 shorts.
static __device__ void dev_gene(const float* __restrict__ A, int lda,
                                const short* __restrict__ Bt,
                                short* __restrict__ C, int M, int K,
                                int bx, short* As, short* Bs)
{
  const int tid  = threadIdx.x;
  const int lane = tid & 63;
  const int wid  = tid >> 6;
  const int wr = wid >> 2, wc = wid & 3;
  const int row0 = bx * 128;
  const int l15 = lane & 15, l4 = lane >> 4;
  const int sr = tid >> 2, sc = tid & 3;
  const int srow = lane >> 2;
  const int schunk = (lane & 3) ^ ((lane >> 3) & 3);
  const int rslot8 = (l4 ^ ((l15 >> 1) & 3)) * 8;

  f32x4 acc[4][4] = {};

  auto stageB = [&](int buf, int k0) {
#pragma unroll
    for (int q = 0; q < 2; ++q) {
      int seg = wid * 2 + q;
      int gcol = seg * 16 + srow;
      gld16(Bt + (size_t)gcol * K + k0 + schunk * 8, Bs + buf * 8192 + seg * 512);
    }
  };
  auto stageA = [&](int buf, int k0) {
    int grow = row0 + sr;
    float4 v0 = make_float4(0.f,0.f,0.f,0.f), v1 = v0;
    if (grow < M) {
      const float* ap = A + (size_t)grow * lda + k0 + sc * 8;
      v0 = *reinterpret_cast<const float4*>(ap);
      v1 = *reinterpret_cast<const float4*>(ap + 4);
    }
    bf16x8 t;
    t[0]=f2bf(v0.x); t[1]=f2bf(v0.y); t[2]=f2bf(v0.z); t[3]=f2bf(v0.w);
    t[4]=f2bf(v1.x); t[5]=f2bf(v1.y); t[6]=f2bf(v1.z); t[7]=f2bf(v1.w);
    *reinterpret_cast<bf16x8*>(As + buf * 5120 + sr * 40 + sc * 8) = t;
  };

  stageB(0, 0); stageA(0, 0);
  __syncthreads();
  int cur = 0;
  for (int k0 = 0; k0 < K; k0 += 32) {
    if (k0 + 32 < K) { stageB(cur ^ 1, k0 + 32); stageA(cur ^ 1, k0 + 32); }
    bf16x8 af[4], bfr[4];
#pragma unroll
    for (int m = 0; m < 4; ++m)
      af[m] = *reinterpret_cast<bf16x8*>(As + cur * 5120 + (wr * 64 + m * 16 + l15) * 40 + l4 * 8);
#pragma unroll
    for (int n = 0; n < 4; ++n)
      bfr[n] = *reinterpret_cast<bf16x8*>(Bs + cur * 8192 + (wc * 64 + n * 16 + l15) * 32 + rslot8);
#pragma unroll
    for (int m = 0; m < 4; ++m)
#pragma unroll
      for (int n = 0; n < 4; ++n)
        acc[m][n] = __builtin_amdgcn_mfma_f32_16x16x32_bf16(af[m], bfr[n], acc[m][n], 0, 0, 0);
    __syncthreads();
    cur ^= 1;
  }

#pragma unroll
  for (int n = 0; n < 4; ++n) {
    int col = wc * 64 + n * 16 + l15;
#pragma unroll
    for (int m = 0; m < 4; ++m) {
      int rb = row0 + wr * 64 + m * 16 + l4 * 4;
#pragma unroll
      for (int e = 0; e < 4; ++e) {
        int r = rb + e;
        if (r < M) C[(size_t)r * 256 + col] = f2bf(acc[m][n][e]);
      }
    }
  }
}

// ---------------- dev: combined goid GEMM (128x256, 8 waves, 2-buf) ---------
static __device__ void dev_combo(const short* __restrict__ A, int lda,
                                 const short* __restrict__ Bt,
                                 const float* __restrict__ bp1,
                                 short* __restrict__ X1, short* __restrict__ H1,
                                 int M, int K, int bx, int by,
                                 short* As, short* Bs)
{
  const int tid  = threadIdx.x;
  const int lane = tid & 63;
  const int wid  = tid >> 6;
  const int wr = wid >> 2, wc = wid & 3;
  const int row0 = by * 128;
  const int col0 = bx * 256;
  const int l15 = lane & 15, l4 = lane >> 4;
  const int srow = lane >> 2;
  const int schunk = (lane & 3) ^ ((lane >> 3) & 3);
  const int rslot8 = (l4 ^ ((l15 >> 1) & 3)) * 8;

  f32x4 acc[4][4] = {};

  auto stage = [&](int buf, int k0) {
#pragma unroll
    for (int q = 0; q < 3; ++q) {
      int s = wid * 3 + q;
      if (s < 8) {
        int grow = row0 + s * 16 + srow;
        if (grow >= M) grow = M - 1;
        gld16(A + (size_t)grow * lda + k0 + schunk * 8, As + buf * 4096 + s * 512);
      } else {
        int gcol = col0 + (s - 8) * 16 + srow;
        gld16(Bt + (size_t)gcol * K + k0 + schunk * 8, Bs + buf * 8192 + (s - 8) * 512);
      }
    }
  };

  stage(0, 0);
  __syncthreads();
  int cur = 0;
  for (int k0 = 0; k0 < K; k0 += 32) {
    if (k0 + 32 < K) stage(cur ^ 1, k0 + 32);
    bf16x8 af[4], bfr[4];
#pragma unroll
    for (int m = 0; m < 4; ++m)
      af[m] = *reinterpret_cast<bf16x8*>(As + cur * 4096 + (wr * 64 + m * 16 + l15) * 32 + rslot8);
#pragma unroll
    for (int n = 0; n < 4; ++n)
      bfr[n] = *reinterpret_cast<bf16x8*>(Bs + cur * 8192 + (wc * 64 + n * 16 + l15) * 32 + rslot8);
#pragma unroll
    for (int m = 0; m < 4; ++m)
#pragma unroll
      for (int n = 0; n < 4; ++n)
        acc[m][n] = __builtin_amdgcn_mfma_f32_16x16x32_bf16(af[m], bfr[n], acc[m][n], 0, 0, 0);
    __syncthreads();
    cur ^= 1;
  }

  const int is_p1 = (col0 >= 256);
  short* dstp = is_p1 ? H1 : X1;
#pragma unroll
  for (int n = 0; n < 4; ++n) {
    int cl = wc * 64 + n * 16 + l15;
    float bv = is_p1 ? bp1[cl] : 0.f;
#pragma unroll
    for (int m = 0; m < 4; ++m) {
      int rb = row0 + wr * 64 + m * 16 + l4 * 4;
#pragma unroll
      for (int e = 0; e < 4; ++e) {
        int r = rb + e;
        if (r < M) dstp[(size_t)r * 256 + cl] = f2bf(acc[m][n][e] + bv);
      }
    }
  }
}

// ---------------- dev: bf16 GEMM 128x128, 3-buf counted pipeline ------------
// As: 3 x 4096 shorts, Bs: 3 x 4096 shorts. 256 threads.
template <int RELU, int OBF>
static __device__ void dev_bf16a(const short* __restrict__ A, int lda,
                                 const short* __restrict__ Bt,
                                 const float* __restrict__ bias,
                                 void* __restrict__ Cv, int ldc,
                                 int M, int K, int bx, int by,
                                 short* As, short* Bs)
{
  const int tid  = threadIdx.x;
  const int lane = tid & 63;
  const int wid  = tid >> 6;
  const int wr = wid >> 1, wc = wid & 1;
  const int row0 = by * 128;
  const int col0 = bx * 128;
  const int l15 = lane & 15, l4 = lane >> 4;
  const int srow = lane >> 2;
  const int schunk = (lane & 3) ^ ((lane >> 3) & 3);
  const int rslot8 = (l4 ^ ((l15 >> 1) & 3)) * 8;

  f32x4 acc[4][4] = {};

  auto stage = [&](int buf, int k0) {   // 4 gld16 per wave
#pragma unroll
    for (int q = 0; q < 2; ++q) {
      int seg = wid * 2 + q;
      int r = seg * 16 + srow;
      int grow = row0 + r;
      if (grow >= M) grow = M - 1;
      gld16(A + (size_t)grow * lda + k0 + schunk * 8, As + buf * 4096 + seg * 512);
      int gcol = col0 + r;
      gld16(Bt + (size_t)gcol * K + k0 + schunk * 8, Bs + buf * 4096 + seg * 512);
    }
  };

  const int nt = K >> 5;
  stage(0, 0);
  if (nt > 1) { stage(1, 32); wait_barrier<4>(); }
  else        { wait_barrier<0>(); }

  for (int t = 0; t < nt; ++t) {
    if (t + 2 < nt) stage((t + 2) % 3, (t + 2) * 32);
    const int cur = t % 3;
    bf16x8 af[4], bfr[4];
#pragma unroll
    for (int m = 0; m < 4; ++m)
      af[m] = *reinterpret_cast<bf16x8*>(As + cur * 4096 + (wr * 64 + m * 16 + l15) * 32 + rslot8);
#pragma unroll
    for (int n = 0; n < 4; ++n)
      bfr[n] = *reinterpret_cast<bf16x8*>(Bs + cur * 4096 + (wc * 64 + n * 16 + l15) * 32 + rslot8);
#pragma unroll
    for (int m = 0; m < 4; ++m)
#pragma unroll
      for (int n = 0; n < 4; ++n)
        acc[m][n] = __builtin_amdgcn_mfma_f32_16x16x32_bf16(af[m], bfr[n], acc[m][n], 0, 0, 0);
    if (t + 1 < nt) {
      if (t + 2 < nt) wait_barrier<4>(); else wait_barrier<0>();
    }
  }

#pragma unroll
  for (int n = 0; n < 4; ++n) {
    int col = col0 + wc * 64 + n * 16 + l15;
    float bv = bias ? bias[col] : 0.f;
#pragma unroll
    for (int m = 0; m < 4; ++m) {
      int rb = row0 + wr * 64 + m * 16 + l4 * 4;
#pragma unroll
      for (int e = 0; e < 4; ++e) {
        int r = rb + e;
        if (r < M) {
          float v = acc[m][n][e] + bv;
          if (RELU) v = fmaxf(v, 0.f);
          size_t idx = (size_t)r * ldc + col;
          if constexpr (OBF) ((short*)Cv)[idx] = f2bf(v);
          else               ((float*)Cv)[idx] = v;
        }
      }
    }
  }
}

// ---------------- merged super-kernels ----------------
constexpr int kWd1Blocks  = 316;   // (10000/128=79 rows)x(1024/256=4 cols)
constexpr int kGeneBlocks = 313;   // 40000/128
constexpr int kHistBlocks = 1563;  // ceil(800000/512)
constexpr int kWd2Blocks  = 395;   // 79 x (1280/256=5)
constexpr int kRowBlocks  = 79;    // ceil(40000/512)
constexpr int kComboBlocks = 158;  // 79 x 2
constexpr int kXw2Blocks  = 391;   // ceil(50000/128)
constexpr int kWp2Blocks  = 79;    // ceil(10000/128)

__global__ __launch_bounds__(512)
void k_big1(const short* goidx_bf, const short* Wd1t, const float* bd1, short* h1tmp_bf,
            const float* gene_x, const short* W1t, short* xw1_bf,
            const int* ei, float* deg)
{
  extern __shared__ short smem[];
  int b = blockIdx.x;
  if (b < kWd1Blocks) {
    dev_wide<1,1>(goidx_bf, kGDim, Wd1t, bd1, h1tmp_bf, kD1, kNGoid, kGDim,
                  b, 4, kWd1Blocks, smem, smem + 2 * 4096);
  } else if (b < kWd1Blocks + kGeneBlocks) {
    dev_gene(gene_x, kGDim, W1t, xw1_bf, kNGene, kInDim,
             b - kWd1Blocks, smem, smem + 2 * 5120);
  } else {
    dev_hist(ei, deg, b - kWd1Blocks - kGeneBlocks);
  }
}

__global__ __launch_bounds__(512)
void k_big2(const short* h1tmp_bf, const short* Wd2t, const float* bd2, short* goidt_bf,
            const float* deg, int* rowstart, int* cursor, int* gcount)
{
  extern __shared__ short smem[];
  int b = blockIdx.x;
  if (b < kWd2Blocks) {
    dev_wide<1,1>(h1tmp_bf, kD1, Wd2t, bd2, goidt_bf, kInDim, kNGoid, kD1,
                  b, 5, kWd2Blocks, smem, smem + 2 * 4096);
  } else {
    dev_rowassign(deg, rowstart, cursor, gcount, b - kWd2Blocks);
  }
}

__global__ __launch_bounds__(512)
void k_big3(const short* goidt_bf, const short* Wcomb, const float* bp1,
            short* X1, short* H1,
            const int* ei, const float* deg, int* cursor, int2* edges)
{
  extern __shared__ short smem[];
  int b = blockIdx.x;
  if (b < kComboBlocks) {
    dev_combo(goidt_bf, kInDim, Wcomb, bp1, X1, H1, kNGoid, kInDim,
              b & 1, b >> 1, smem, smem + 2 * 4096);
  } else {
    dev_fill(ei, deg, cursor, edges, b - kComboBlocks);
  }
}

__global__ __launch_bounds__(256)
void k_xwp(const short* h1bf, const short* W2t, short* xw2_bf,
           const short* h1goid, const short* Wp2t, const float* bp2, short* h2goid)
{
  extern __shared__ short smem[];
  int b = blockIdx.x;
  if (b < kXw2Blocks) {
    dev_bf16a<0,1>(h1bf, kH1, W2t, nullptr, xw2_bf, kH2, kN, kH1,
                   0, b, smem, smem + 3 * 4096);
  } else {
    dev_bf16a<0,1>(h1goid, kH1, Wp2t, bp2, h2goid, kH2, kNGoid, kH1,
                   0, b - kXw2Blocks, smem, smem + 3 * 4096);
  }
}

// ---------------- out layer: h2bf[M][128] @ Wft[64][128] + bf -> out fp32 ----
__global__ __launch_bounds__(256)
void k_gemm_out(const short* __restrict__ A,      // h2bf, lda=128
                const short* __restrict__ Bt,     // Wft [64][128]
                const float* __restrict__ bias,
                float* __restrict__ C,            // [M][64]
                int M)
{
  __shared__ __align__(16) short As[2][256 * 32];
  __shared__ __align__(16) short Bs[2][64 * 32];
  const int tid  = threadIdx.x;
  const int lane = tid & 63;
  const int wid  = tid >> 6;
  const int row0 = blockIdx.x * 256;
  const int l15 = lane & 15, l4 = lane >> 4;
  const int srow = lane >> 2;
  const int schunk = (lane & 3) ^ ((lane >> 3) & 3);
  const int rslot8 = (l4 ^ ((l15 >> 1) & 3)) * 8;

  f32x4 acc[4][4] = {};

  auto stage = [&](int buf, int k0) {
#pragma unroll
    for (int q = 0; q < 4; ++q) {
      int seg = wid * 4 + q;
      int grow = row0 + seg * 16 + srow;
      if (grow >= M) grow = M - 1;
      gld16(A + (size_t)grow * 128 + k0 + schunk * 8, &As[buf][seg * 512]);
    }
    int gcol = wid * 16 + srow;
    gld16(Bt + (size_t)gcol * 128 + k0 + schunk * 8, &Bs[buf][wid * 512]);
  };

  stage(0, 0);
  __syncthreads();
  int cur = 0;
  for (int k0 = 0; k0 < 128; k0 += 32) {
    if (k0 + 32 < 128) stage(cur ^ 1, k0 + 32);
    bf16x8 af[4], bfr[4];
#pragma unroll
    for (int m = 0; m < 4; ++m)
      af[m] = *reinterpret_cast<bf16x8*>(&As[cur][(wid * 64 + m * 16 + l15) * 32 + rslot8]);
#pragma unroll
    for (int n = 0; n < 4; ++n)
      bfr[n] = *reinterpret_cast<bf16x8*>(&Bs[cur][(n * 16 + l15) * 32 + rslot8]);
#pragma unroll
    for (int m = 0; m < 4; ++m)
#pragma unroll
      for (int n = 0; n < 4; ++n)
        acc[m][n] = __builtin_amdgcn_mfma_f32_16x16x32_bf16(af[m], bfr[n], acc[m][n], 0, 0, 0);
    __syncthreads();
    cur ^= 1;
  }

#pragma unroll
  for (int n = 0; n < 4; ++n) {
    int col = n * 16 + l15;
    float bv = bias[col];
#pragma unroll
    for (int m = 0; m < 4; ++m) {
      int rb = row0 + wid * 64 + m * 16 + l4 * 4;
#pragma unroll
      for (int e = 0; e < 4; ++e) {
        int r = rb + e;
        if (r < M) C[(size_t)r * 64 + col] = acc[m][n][e] + bv;
      }
    }
  }
}

extern "C" void kernel_launch(void* const* d_in, const int* in_sizes, int n_in,
                              void* d_out, int out_size, void* d_ws, size_t ws_size,
                              hipStream_t stream) {
  const float* x   = (const float*)d_in[0];
  const int*   ei  = (const int*)d_in[1];
  const float* Wd1 = (const float*)d_in[3];
  const float* bd1 = (const float*)d_in[4];
  const float* Wd2 = (const float*)d_in[5];
  const float* bd2 = (const float*)d_in[6];
  const float* W1  = (const float*)d_in[7];
  const float* b1  = (const float*)d_in[8];
  const float* W2  = (const float*)d_in[9];
  const float* b2  = (const float*)d_in[10];
  const float* Wp1 = (const float*)d_in[11];
  const float* bp1 = (const float*)d_in[12];
  const float* Wp2 = (const float*)d_in[13];
  const float* bp2 = (const float*)d_in[14];
  const float* Wf  = (const float*)d_in[15];
  const float* bf_ = (const float*)d_in[16];
  float* out = (float*)d_out;
  float* ws  = (float*)d_ws;

  // workspace (float offsets), non-overlapping, 16B-aligned
  short* goidx_bf = (short*)(ws + 0);          // 10000 x 4096 bf16
  short* goidt_bf = (short*)(ws + 20480000);   // 10000 x 1280 bf16
  short* h1tmp_bf = (short*)(ws + 26880000);   // 10000 x 1024 bf16
  short* Wd1t = (short*)(ws + 32000000);       // 1024 x 4096
  short* Wd2t = (short*)(ws + 34097152);       // 1280 x 1024
  short* W1t  = (short*)(ws + 34752512);       //  256 x 1280 \ contiguous ->
  short* Wp1t = (short*)(ws + 34916352);       //  256 x 1280 / Wcomb[512][1280]
  short* W2t  = (short*)(ws + 35080192);       //  128 x 256
  short* xw1_bf = (short*)(ws + 35100000);     // 50000 x 256 bf16
  short* h1bf   = (short*)(ws + 41500000);     // 50000 x 256 bf16
  short* xw2_bf = (short*)(ws + 50460000);     // 50000 x 128 bf16
  short* h2bf   = (short*)(ws + 53660000);     // 50000 x 128 bf16
  float* deg    = ws + 60060000;               // 50,000
  int*   rowstart = (int*)(ws + 60150016);     // 40,000
  int*   cursor   = (int*)(ws + 60190016);     // 40,000
  int2*  edges    = (int2*)(ws + 60230016);    // 800,000 x 8B
  int*   gcount   = (int*)(ws + 61830016);     // 1
  short* Wp2t = (short*)(ws + 61830032);       // 128 x 256
  short* Wft  = (short*)(ws + 61846416);       //  64 x 128

  const float* gene_x = x;                          // rows 0..39999, lda=4096
  const float* goid_x = x + (size_t)kNGene * kGDim; // rows 40000..49999

  // 0) fused prep: goidx cvt + 7 weight transposes + deg init
  k_prep<<<kCvtBlocks + kTransBlocks + kInitBlocks, 256, 0, stream>>>(
      goid_x, goidx_bf, Wd1, Wd1t, Wd2, Wd2t, W1, W1t, Wp1, Wp1t,
      W2, W2t, Wp2, Wp2t, Wf, Wft, deg, gcount);

  // 1) big1: Wd1 GEMM || gene xw1 GEMM || degree histogram
  k_big1<<<kWd1Blocks + kGeneBlocks + kHistBlocks, 512, 53248, stream>>>(
      goidx_bf, Wd1t, bd1, h1tmp_bf, gene_x, W1t, xw1_bf, ei, deg);

  // 2) big2: Wd2 GEMM || rowassign
  k_big2<<<kWd2Blocks + kRowBlocks, 512, 49152, stream>>>(
      h1tmp_bf, Wd2t, bd2, goidt_bf, deg, rowstart, cursor, gcount);

  // 3) big3: combo GEMM (xw1 goid rows + h1 goid rows) || edge fill
  k_big3<<<kComboBlocks + kHistBlocks, 512, 49152, stream>>>(
      goidt_bf, W1t /*=Wcomb[512][1280]*/, bp1,
      xw1_bf + (size_t)kNGene * kH1, h1bf + (size_t)kNGene * kH1,
      ei, deg, cursor, edges);

  // 4) conv1: gather -> h1 bf16 gene rows
  k_gather_bf<kH1,1><<<(kNGene * 64 + 255) / 256, 256, 0, stream>>>(
      xw1_bf, deg, rowstart, edges, b1, h1bf);

  // 5) xw2 GEMM || Wp2 GEMM
  k_xwp<<<kXw2Blocks + kWp2Blocks, 256, 49152, stream>>>(
      h1bf, W2t, xw2_bf,
      h1bf + (size_t)kNGene * kH1, Wp2t, bp2, h2bf + (size_t)kNGene * kH2);

  // 6) conv2: gather -> h2 bf16 gene rows
  k_gather_bf<kH2,1><<<(kNGene * 64 + 255) / 256, 256, 0, stream>>>(
      xw2_bf, deg, rowstart, edges, b2, h2bf);

  // 7) out = h2 @ Wf + bf (bf16 MFMA, 256x64 tile)
  k_gemm_out<<<(kN + 255) / 256, 256, 0, stream>>>(h2bf, Wft, bf_, out, kN);
}

// Round 15
// 561.527 us; speedup vs baseline: 1.8606x; 1.0204x over previous
//
#include <hip/hip_runtime.h>

// Problem constants (from reference)
constexpr int kNGene = 40000;
constexpr int kNGoid = 10000;
constexpr int kN     = 50000;
constexpr int kE     = 800000;
constexpr int kInDim = 1280;
constexpr int kH1    = 256;
constexpr int kH2    = 128;
constexpr int kOut   = 64;
constexpr int kGDim  = 4096;
constexpr int kD1    = 1024;

typedef short bf16x8 __attribute__((ext_vector_type(8)));
typedef float f32x4  __attribute__((ext_vector_type(4)));

static __device__ __forceinline__ short f2bf(float f) {
  union { float f; unsigned u; } v; v.f = f;
  unsigned r = v.u + 0x7FFF + ((v.u >> 16) & 1);   // RNE; inputs are finite
  return (short)(r >> 16);
}
static __device__ __forceinline__ float bf2f(short s) {
  union { unsigned u; float f; } v;
  v.u = ((unsigned)(unsigned short)s) << 16;
  return v.f;
}
// async global->LDS, 16B/lane; LDS dest = base + lane*16 (wave-linear).
static __device__ __forceinline__ void gld16(const void* g, void* l) {
  __builtin_amdgcn_global_load_lds(
      (const __attribute__((address_space(1))) void*)g,
      (__attribute__((address_space(3))) void*)l, 16, 0, 0);
}
// counted-vmcnt pipeline barrier
template <int N>
static __device__ __forceinline__ void wait_barrier() {
  if constexpr (N == 0)      asm volatile("s_waitcnt vmcnt(0)" ::: "memory");
  else if constexpr (N == 3) asm volatile("s_waitcnt vmcnt(3)" ::: "memory");
  else                       asm volatile("s_waitcnt vmcnt(4)" ::: "memory");
  __builtin_amdgcn_s_barrier();
  asm volatile("" ::: "memory");
}

// ---------------- fused prep: goidx cvt + 7 weight transposes + deg init ----
constexpr int kCvtBlocks   = 20000;  // 10000*4096/8/256
constexpr int kTransBlocks = 6088;   // 4096+1280+320+320+32+32+8
constexpr int kInitBlocks  = 196;    // ceil(50000/256)

__global__ __launch_bounds__(256)
void k_prep(const float* __restrict__ goid_x, short* __restrict__ goidx_bf,
            const float* __restrict__ Wd1, short* __restrict__ Wd1t,
            const float* __restrict__ Wd2, short* __restrict__ Wd2t,
            const float* __restrict__ W1,  short* __restrict__ W1t,
            const float* __restrict__ Wp1, short* __restrict__ Wp1t,
            const float* __restrict__ W2,  short* __restrict__ W2t,
            const float* __restrict__ Wp2, short* __restrict__ Wp2t,
            const float* __restrict__ Wf,  short* __restrict__ Wft,
            float* __restrict__ deg, int* __restrict__ gcount)
{
  __shared__ float t[32][33];
  int b = blockIdx.x;
  if (b < kCvtBlocks) {                       // goid_x -> bf16
    int idx = b * 256 + threadIdx.x;          // chunk of 8
    int r = idx >> 9;
    int c = (idx & 511) << 3;
    const float* sp = goid_x + (size_t)r * kGDim + c;
    float4 v0 = *reinterpret_cast<const float4*>(sp);
    float4 v1 = *reinterpret_cast<const float4*>(sp + 4);
    bf16x8 o;
    o[0]=f2bf(v0.x); o[1]=f2bf(v0.y); o[2]=f2bf(v0.z); o[3]=f2bf(v0.w);
    o[4]=f2bf(v1.x); o[5]=f2bf(v1.y); o[6]=f2bf(v1.z); o[7]=f2bf(v1.w);
    *reinterpret_cast<bf16x8*>(goidx_bf + (size_t)r * kGDim + c) = o;
    return;
  }
  if (b >= kCvtBlocks + kTransBlocks) {       // deg init
    int i = (b - kCvtBlocks - kTransBlocks) * 256 + threadIdx.x;
    if (i < kN) deg[i] = 1.0f;
    if (i == 0) *gcount = 0;
    return;
  }
  int b2 = b - kCvtBlocks;
  const float* W; short* Wt; int K, N, bi;
  if (b2 < 4096)      { W = Wd1; Wt = Wd1t; K = 4096; N = 1024; bi = b2; }
  else if (b2 < 5376) { W = Wd2; Wt = Wd2t; K = 1024; N = 1280; bi = b2 - 4096; }
  else if (b2 < 5696) { W = W1;  Wt = W1t;  K = 1280; N = 256;  bi = b2 - 5376; }
  else if (b2 < 6016) { W = Wp1; Wt = Wp1t; K = 1280; N = 256;  bi = b2 - 5696; }
  else if (b2 < 6048) { W = W2;  Wt = W2t;  K = 256;  N = 128;  bi = b2 - 6016; }
  else if (b2 < 6080) { W = Wp2; Wt = Wp2t; K = 256;  N = 128;  bi = b2 - 6048; }
  else                { W = Wf;  Wt = Wft;  K = 128;  N = 64;   bi = b2 - 6080; }
  int nbx = N >> 5;
  int n0 = (bi % nbx) * 32, k0 = (bi / nbx) * 32;
  int tx = threadIdx.x & 31, ty = threadIdx.x >> 5;
#pragma unroll
  for (int p = 0; p < 4; ++p)
    t[ty + 8 * p][tx] = W[(size_t)(k0 + ty + 8 * p) * N + n0 + tx];
  __syncthreads();
#pragma unroll
  for (int p = 0; p < 4; ++p)
    Wt[(size_t)(n0 + ty + 8 * p) * K + k0 + tx] = f2bf(t[tx][ty + 8 * p]);
}

// ---------------- CSR device pieces (512-thread blocks) ----------------
static __device__ void dev_hist(const int* __restrict__ ei, float* __restrict__ deg,
                                int bid) {
  int e = bid * 512 + threadIdx.x;
  if (e < kE) atomicAdd(&deg[ei[kE + e]], 1.0f);
}
static __device__ void dev_rowassign(const float* __restrict__ deg,
                                     int* __restrict__ rowstart,
                                     int* __restrict__ cursor,
                                     int* __restrict__ gcount, int bid) {
  int i = bid * 512 + threadIdx.x;
  int lane = threadIdx.x & 63;
  int c = (i < kNGene) ? ((int)deg[i] - 1) : 0;
  int incl = c;
#pragma unroll
  for (int off = 1; off < 64; off <<= 1) {
    int t = __shfl_up(incl, off, 64);
    if (lane >= off) incl += t;
  }
  int total = __shfl(incl, 63, 64);
  int base = 0;
  if (lane == 63) base = atomicAdd(gcount, total);
  base = __shfl(base, 63, 64);
  if (i < kNGene) {
    int s = base + incl - c;
    rowstart[i] = s;
    cursor[i] = s;
  }
}
static __device__ void dev_fill(const int* __restrict__ ei, const float* __restrict__ deg,
                                int* __restrict__ cursor, int2* __restrict__ edges,
                                int bid) {
  int e = bid * 512 + threadIdx.x;
  if (e >= kE) return;
  int dst = ei[kE + e];
  if (dst >= kNGene) return;
  int src = ei[e];
  int pos = atomicAdd(&cursor[dst], 1);
  float nrm = rsqrtf(deg[src] * deg[dst]);
  edges[pos] = make_int2(src, __float_as_int(nrm));
}

// ---------------- gather: half-wave 2-edge scheme, bf16 in/out --------------
// One wave per dst row. Wave halves each own ALL F features (lane covers
// F/32) and process alternating edges; halves merge via shfl_xor(32).
// conv1 (F=256): 16B loads; conv2 (F=128): 8B loads.
template <int F>
__global__ __launch_bounds__(256)
void k_gather2(const short* __restrict__ xw, const float* __restrict__ deg,
               const int* __restrict__ rowstart, const int2* __restrict__ edges,
               const float* __restrict__ bias, short* __restrict__ h) {
  constexpr int VEC = F / 32;            // 8 (F=256) or 4 (F=128)
  int row = (blockIdx.x * blockDim.x + threadIdx.x) >> 6;
  int lane = threadIdx.x & 63;
  int half = lane >> 5, lp = lane & 31;
  if (row >= kNGene) return;
  float dg = deg[row];
  float inv = 1.0f / dg;
  float acc[VEC] = {};
  if (half == 0) {                       // self-loop in half 0 only
    const short* xr = xw + (size_t)row * F + lp * VEC;
    if constexpr (VEC == 8) {
      bf16x8 s = *reinterpret_cast<const bf16x8*>(xr);
#pragma unroll
      for (int v = 0; v < 8; ++v) acc[v] = bf2f(s[v]) * inv;
    } else {
      short4 s = *reinterpret_cast<const short4*>(xr);
      acc[0] = bf2f(s.x) * inv; acc[1] = bf2f(s.y) * inv;
      acc[2] = bf2f(s.z) * inv; acc[3] = bf2f(s.w) * inv;
    }
  }
  int e0 = rowstart[row];
  int n = (int)dg - 1;
  for (int e = half; e < n; e += 2) {
    int2 p = edges[e0 + e];
    float nrm = __int_as_float(p.y);
    const short* xs = xw + (size_t)p.x * F + lp * VEC;
    if constexpr (VEC == 8) {
      bf16x8 s = *reinterpret_cast<const bf16x8*>(xs);
#pragma unroll
      for (int v = 0; v < 8; ++v) acc[v] += bf2f(s[v]) * nrm;
    } else {
      short4 s = *reinterpret_cast<const short4*>(xs);
      acc[0] += bf2f(s.x) * nrm; acc[1] += bf2f(s.y) * nrm;
      acc[2] += bf2f(s.z) * nrm; acc[3] += bf2f(s.w) * nrm;
    }
  }
  // merge halves
#pragma unroll
  for (int v = 0; v < VEC; ++v) acc[v] += __shfl_xor(acc[v], 32, 64);
  if (half == 0) {
    short o[VEC];
#pragma unroll
    for (int v = 0; v < VEC; ++v)
      o[v] = f2bf(fmaxf(acc[v] + bias[lp * VEC + v], 0.f));
    short* hp = h + (size_t)row * F + lp * VEC;
    if constexpr (VEC == 8)
      *reinterpret_cast<bf16x8*>(hp) = *reinterpret_cast<bf16x8*>(o);
    else
      *reinterpret_cast<short4*>(hp) = *reinterpret_cast<short4*>(o);
  }
}

// ---------------- dev: bf16 GEMM 128x256, 8 waves, 2-buf, swizzled LDS ------
template <int RELU, int OBF>
static __device__ void dev_wide(const short* __restrict__ A, int lda,
                                const short* __restrict__ Bt,
                                const float* __restrict__ bias,
                                void* __restrict__ Cv, int ldc,
                                int M, int K, int b0, int nbx, int nwg,
                                short* As, short* Bs)
{
  const int tid  = threadIdx.x;
  const int lane = tid & 63;
  const int wid  = tid >> 6;        // 0..7
  const int wr = wid >> 2, wc = wid & 3;
  // bijective XCD swizzle (m204)
  int qq = nwg >> 3, rr = nwg & 7, xcd = b0 & 7, j = b0 >> 3;
  int swz = ((xcd < rr) ? xcd * (qq + 1) : rr * (qq + 1) + (xcd - rr) * qq) + j;
  const int row0 = (swz / nbx) * 128;
  const int col0 = (swz % nbx) * 256;
  const int l15 = lane & 15, l4 = lane >> 4;
  const int srow = lane >> 2;
  const int schunk = (lane & 3) ^ ((lane >> 3) & 3);
  const int rslot8 = (l4 ^ ((l15 >> 1) & 3)) * 8;

  f32x4 acc[4][4] = {};

  auto stage = [&](int buf, int k0) {
#pragma unroll
    for (int q = 0; q < 3; ++q) {
      int s = wid * 3 + q;
      if (s < 8) {
        int grow = row0 + s * 16 + srow;
        if (grow >= M) grow = M - 1;
        gld16(A + (size_t)grow * lda + k0 + schunk * 8, As + buf * 4096 + s * 512);
      } else {
        int gcol = col0 + (s - 8) * 16 + srow;
        gld16(Bt + (size_t)gcol * K + k0 + schunk * 8, Bs + buf * 8192 + (s - 8) * 512);
      }
    }
  };

  stage(0, 0);
  __syncthreads();
  int cur = 0;
  for (int k0 = 0; k0 < K; k0 += 32) {
    if (k0 + 32 < K) stage(cur ^ 1, k0 + 32);
    bf16x8 af[4], bfr[4];
#pragma unroll
    for (int m = 0; m < 4; ++m)
      af[m] = *reinterpret_cast<bf16x8*>(As + cur * 4096 + (wr * 64 + m * 16 + l15) * 32 + rslot8);
#pragma unroll
    for (int n = 0; n < 4; ++n)
      bfr[n] = *reinterpret_cast<bf16x8*>(Bs + cur * 8192 + (wc * 64 + n * 16 + l15) * 32 + rslot8);
#pragma unroll
    for (int m = 0; m < 4; ++m)
#pragma unroll
      for (int n = 0; n < 4; ++n)
        acc[m][n] = __builtin_amdgcn_mfma_f32_16x16x32_bf16(af[m], bfr[n], acc[m][n], 0, 0, 0);
    __syncthreads();
    cur ^= 1;
  }

#pragma unroll
  for (int n = 0; n < 4; ++n) {
    int col = col0 + wc * 64 + n * 16 + l15;
    float bv = bias ? bias[col] : 0.f;
#pragma unroll
    for (int m = 0; m < 4; ++m) {
      int rb = row0 + wr * 64 + m * 16 + l4 * 4;
#pragma unroll
      for (int e = 0; e < 4; ++e) {
        int r = rb + e;
        if (r < M) {
          float v = acc[m][n][e] + bv;
          if (RELU) v = fmaxf(v, 0.f);
          size_t idx = (size_t)r * ldc + col;
          if constexpr (OBF) ((short*)Cv)[idx] = f2bf(v);
          else               ((float*)Cv)[idx] = v;
        }
      }
    }
  }
}

// ---------------- dev: gene xw1, fp32-A, 128x256, 8 waves, 2-buf ------------
static __device__ void dev_gene(const float* __restrict__ A, int lda,
                                const short* __restrict__ Bt,
                                short* __restrict__ C, int M, int K,
                                int bx, short* As, short* Bs)
{
  const int tid  = threadIdx.x;
  const int lane = tid & 63;
  const int wid  = tid >> 6;
  const int wr = wid >> 2, wc = wid & 3;
  const int row0 = bx * 128;
  const int l15 = lane & 15, l4 = lane >> 4;
  const int sr = tid >> 2, sc = tid & 3;
  const int srow = lane >> 2;
  const int schunk = (lane & 3) ^ ((lane >> 3) & 3);
  const int rslot8 = (l4 ^ ((l15 >> 1) & 3)) * 8;

  f32x4 acc[4][4] = {};

  auto stageB = [&](int buf, int k0) {
#pragma unroll
    for (int q = 0; q < 2; ++q) {
      int seg = wid * 2 + q;
      int gcol = seg * 16 + srow;
      gld16(Bt + (size_t)gcol * K + k0 + schunk * 8, Bs + buf * 8192 + seg * 512);
    }
  };
  auto stageA = [&](int buf, int k0) {
    int grow = row0 + sr;
    float4 v0 = make_float4(0.f,0.f,0.f,0.f), v1 = v0;
    if (grow < M) {
      const float* ap = A + (size_t)grow * lda + k0 + sc * 8;
      v0 = *reinterpret_cast<const float4*>(ap);
      v1 = *reinterpret_cast<const float4*>(ap + 4);
    }
    bf16x8 t;
    t[0]=f2bf(v0.x); t[1]=f2bf(v0.y); t[2]=f2bf(v0.z); t[3]=f2bf(v0.w);
    t[4]=f2bf(v1.x); t[5]=f2bf(v1.y); t[6]=f2bf(v1.z); t[7]=f2bf(v1.w);
    *reinterpret_cast<bf16x8*>(As + buf * 5120 + sr * 40 + sc * 8) = t;
  };

  stageB(0, 0); stageA(0, 0);
  __syncthreads();
  int cur = 0;
  for (int k0 = 0; k0 < K; k0 += 32) {
    if (k0 + 32 < K) { stageB(cur ^ 1, k0 + 32); stageA(cur ^ 1, k0 + 32); }
    bf16x8 af[4], bfr[4];
#pragma unroll
    for (int m = 0; m < 4; ++m)
      af[m] = *reinterpret_cast<bf16x8*>(As + cur * 5120 + (wr * 64 + m * 16 + l15) * 40 + l4 * 8);
#pragma unroll
    for (int n = 0; n < 4; ++n)
      bfr[n] = *reinterpret_cast<bf16x8*>(Bs + cur * 8192 + (wc * 64 + n * 16 + l15) * 32 + rslot8);
#pragma unroll
    for (int m = 0; m < 4; ++m)
#pragma unroll
      for (int n = 0; n < 4; ++n)
        acc[m][n] = __builtin_amdgcn_mfma_f32_16x16x32_bf16(af[m], bfr[n], acc[m][n], 0, 0, 0);
    __syncthreads();
    cur ^= 1;
  }

#pragma unroll
  for (int n = 0; n < 4; ++n) {
    int col = wc * 64 + n * 16 + l15;
#pragma unroll
    for (int m = 0; m < 4; ++m) {
      int rb = row0 + wr * 64 + m * 16 + l4 * 4;
#pragma unroll
      for (int e = 0; e < 4; ++e) {
        int r = rb + e;
        if (r < M) C[(size_t)r * 256 + col] = f2bf(acc[m][n][e]);
      }
    }
  }
}

// ---------------- dev: combined goid GEMM (128x256, 8 waves, 2-buf) ---------
static __device__ void dev_combo(const short* __restrict__ A, int lda,
                                 const short* __restrict__ Bt,
                                 const float* __restrict__ bp1,
                                 short* __restrict__ X1, short* __restrict__ H1,
                                 int M, int K, int bx, int by,
                                 short* As, short* Bs)
{
  const int tid  = threadIdx.x;
  const int lane = tid & 63;
  const int wid  = tid >> 6;
  const int wr = wid >> 2, wc = wid & 3;
  const int row0 = by * 128;
  const int col0 = bx * 256;
  const int l15 = lane & 15, l4 = lane >> 4;
  const int srow = lane >> 2;
  const int schunk = (lane & 3) ^ ((lane >> 3) & 3);
  const int rslot8 = (l4 ^ ((l15 >> 1) & 3)) * 8;

  f32x4 acc[4][4] = {};

  auto stage = [&](int buf, int k0) {
#pragma unroll
    for (int q = 0; q < 3; ++q) {
      int s = wid * 3 + q;
      if (s < 8) {
        int grow = row0 + s * 16 + srow;
        if (grow >= M) grow = M - 1;
        gld16(A + (size_t)grow * lda + k0 + schunk * 8, As + buf * 4096 + s * 512);
      } else {
        int gcol = col0 + (s - 8) * 16 + srow;
        gld16(Bt + (size_t)gcol * K + k0 + schunk * 8, Bs + buf * 8192 + (s - 8) * 512);
      }
    }
  };

  stage(0, 0);
  __syncthreads();
  int cur = 0;
  for (int k0 = 0; k0 < K; k0 += 32) {
    if (k0 + 32 < K) stage(cur ^ 1, k0 + 32);
    bf16x8 af[4], bfr[4];
#pragma unroll
    for (int m = 0; m < 4; ++m)
      af[m] = *reinterpret_cast<bf16x8*>(As + cur * 4096 + (wr * 64 + m * 16 + l15) * 32 + rslot8);
#pragma unroll
    for (int n = 0; n < 4; ++n)
      bfr[n] = *reinterpret_cast<bf16x8*>(Bs + cur * 8192 + (wc * 64 + n * 16 + l15) * 32 + rslot8);
#pragma unroll
    for (int m = 0; m < 4; ++m)
#pragma unroll
      for (int n = 0; n < 4; ++n)
        acc[m][n] = __builtin_amdgcn_mfma_f32_16x16x32_bf16(af[m], bfr[n], acc[m][n], 0, 0, 0);
    __syncthreads();
    cur ^= 1;
  }

  const int is_p1 = (col0 >= 256);
  short* dstp = is_p1 ? H1 : X1;
#pragma unroll
  for (int n = 0; n < 4; ++n) {
    int cl = wc * 64 + n * 16 + l15;
    float bv = is_p1 ? bp1[cl] : 0.f;
#pragma unroll
    for (int m = 0; m < 4; ++m) {
      int rb = row0 + wr * 64 + m * 16 + l4 * 4;
#pragma unroll
      for (int e = 0; e < 4; ++e) {
        int r = rb + e;
        if (r < M) dstp[(size_t)r * 256 + cl] = f2bf(acc[m][n][e] + bv);
      }
    }
  }
}

// ---------------- dev: bf16 GEMM 128x128, 3-buf counted pipeline ------------
template <int RELU, int OBF>
static __device__ void dev_bf16a(const short* __restrict__ A, int lda,
                                 const short* __restrict__ Bt,
                                 const float* __restrict__ bias,
                                 void* __restrict__ Cv, int ldc,
                                 int M, int K, int bx, int by,
                                 short* As, short* Bs)
{
  const int tid  = threadIdx.x;
  const int lane = tid & 63;
  const int wid  = tid >> 6;
  const int wr = wid >> 1, wc = wid & 1;
  const int row0 = by * 128;
  const int col0 = bx * 128;
  const int l15 = lane & 15, l4 = lane >> 4;
  const int srow = lane >> 2;
  const int schunk = (lane & 3) ^ ((lane >> 3) & 3);
  const int rslot8 = (l4 ^ ((l15 >> 1) & 3)) * 8;

  f32x4 acc[4][4] = {};

  auto stage = [&](int buf, int k0) {   // 4 gld16 per wave
#pragma unroll
    for (int q = 0; q < 2; ++q) {
      int seg = wid * 2 + q;
      int r = seg * 16 + srow;
      int grow = row0 + r;
      if (grow >= M) grow = M - 1;
      gld16(A + (size_t)grow * lda + k0 + schunk * 8, As + buf * 4096 + seg * 512);
      int gcol = col0 + r;
      gld16(Bt + (size_t)gcol * K + k0 + schunk * 8, Bs + buf * 4096 + seg * 512);
    }
  };

  const int nt = K >> 5;
  stage(0, 0);
  if (nt > 1) { stage(1, 32); wait_barrier<4>(); }
  else        { wait_barrier<0>(); }

  for (int t = 0; t < nt; ++t) {
    if (t + 2 < nt) stage((t + 2) % 3, (t + 2) * 32);
    const int cur = t % 3;
    bf16x8 af[4], bfr[4];
#pragma unroll
    for (int m = 0; m < 4; ++m)
      af[m] = *reinterpret_cast<bf16x8*>(As + cur * 4096 + (wr * 64 + m * 16 + l15) * 32 + rslot8);
#pragma unroll
    for (int n = 0; n < 4; ++n)
      bfr[n] = *reinterpret_cast<bf16x8*>(Bs + cur * 4096 + (wc * 64 + n * 16 + l15) * 32 + rslot8);
#pragma unroll
    for (int m = 0; m < 4; ++m)
#pragma unroll
      for (int n = 0; n < 4; ++n)
        acc[m][n] = __builtin_amdgcn_mfma_f32_16x16x32_bf16(af[m], bfr[n], acc[m][n], 0, 0, 0);
    if (t + 1 < nt) {
      if (t + 2 < nt) wait_barrier<4>(); else wait_barrier<0>();
    }
  }

#pragma unroll
  for (int n = 0; n < 4; ++n) {
    int col = col0 + wc * 64 + n * 16 + l15;
    float bv = bias ? bias[col] : 0.f;
#pragma unroll
    for (int m = 0; m < 4; ++m) {
      int rb = row0 + wr * 64 + m * 16 + l4 * 4;
#pragma unroll
      for (int e = 0; e < 4; ++e) {
        int r = rb + e;
        if (r < M) {
          float v = acc[m][n][e] + bv;
          if (RELU) v = fmaxf(v, 0.f);
          size_t idx = (size_t)r * ldc + col;
          if constexpr (OBF) ((short*)Cv)[idx] = f2bf(v);
          else               ((float*)Cv)[idx] = v;
        }
      }
    }
  }
}

// ---------------- merged super-kernels ----------------
constexpr int kWd1Blocks  = 316;   // (10000/128=79 rows)x(1024/256=4 cols)
constexpr int kGeneBlocks = 313;   // 40000/128
constexpr int kHistBlocks = 1563;  // ceil(800000/512)
constexpr int kWd2Blocks  = 395;   // 79 x (1280/256=5)
constexpr int kRowBlocks  = 79;    // ceil(40000/512)
constexpr int kComboBlocks = 158;  // 79 x 2
constexpr int kXw2Blocks  = 391;   // ceil(50000/128)
constexpr int kWp2Blocks  = 79;    // ceil(10000/128)

__global__ __launch_bounds__(512)
void k_big1(const short* goidx_bf, const short* Wd1t, const float* bd1, short* h1tmp_bf,
            const float* gene_x, const short* W1t, short* xw1_bf,
            const int* ei, float* deg)
{
  extern __shared__ short smem[];
  int b = blockIdx.x;
  if (b < kWd1Blocks) {
    dev_wide<1,1>(goidx_bf, kGDim, Wd1t, bd1, h1tmp_bf, kD1, kNGoid, kGDim,
                  b, 4, kWd1Blocks, smem, smem + 2 * 4096);
  } else if (b < kWd1Blocks + kGeneBlocks) {
    dev_gene(gene_x, kGDim, W1t, xw1_bf, kNGene, kInDim,
             b - kWd1Blocks, smem, smem + 2 * 5120);
  } else {
    dev_hist(ei, deg, b - kWd1Blocks - kGeneBlocks);
  }
}

__global__ __launch_bounds__(512)
void k_big2(const short* h1tmp_bf, const short* Wd2t, const float* bd2, short* goidt_bf,
            const float* deg, int* rowstart, int* cursor, int* gcount)
{
  extern __shared__ short smem[];
  int b = blockIdx.x;
  if (b < kWd2Blocks) {
    dev_wide<1,1>(h1tmp_bf, kD1, Wd2t, bd2, goidt_bf, kInDim, kNGoid, kD1,
                  b, 5, kWd2Blocks, smem, smem + 2 * 4096);
  } else {
    dev_rowassign(deg, rowstart, cursor, gcount, b - kWd2Blocks);
  }
}

__global__ __launch_bounds__(512)
void k_big3(const short* goidt_bf, const short* Wcomb, const float* bp1,
            short* X1, short* H1,
            const int* ei, const float* deg, int* cursor, int2* edges)
{
  extern __shared__ short smem[];
  int b = blockIdx.x;
  if (b < kComboBlocks) {
    dev_combo(goidt_bf, kInDim, Wcomb, bp1, X1, H1, kNGoid, kInDim,
              b & 1, b >> 1, smem, smem + 2 * 4096);
  } else {
    dev_fill(ei, deg, cursor, edges, b - kComboBlocks);
  }
}

__global__ __launch_bounds__(256)
void k_xwp(const short* h1bf, const short* W2t, short* xw2_bf,
           const short* h1goid, const short* Wp2t, const float* bp2, short* h2goid)
{
  extern __shared__ short smem[];
  int b = blockIdx.x;
  if (b < kXw2Blocks) {
    dev_bf16a<0,1>(h1bf, kH1, W2t, nullptr, xw2_bf, kH2, kN, kH1,
                   0, b, smem, smem + 3 * 4096);
  } else {
    dev_bf16a<0,1>(h1goid, kH1, Wp2t, bp2, h2goid, kH2, kNGoid, kH1,
                   0, b - kXw2Blocks, smem, smem + 3 * 4096);
  }
}

// ---------------- out layer: h2bf[M][128] @ Wft[64][128] + bf -> out fp32 ----
__global__ __launch_bounds__(256)
void k_gemm_out(const short* __restrict__ A,      // h2bf, lda=128
                const short* __restrict__ Bt,     // Wft [64][128]
                const float* __restrict__ bias,
                float* __restrict__ C,            // [M][64]
                int M)
{
  __shared__ __align__(16) short As[2][256 * 32];
  __shared__ __align__(16) short Bs[2][64 * 32];
  const int tid  = threadIdx.x;
  const int lane = tid & 63;
  const int wid  = tid >> 6;
  const int row0 = blockIdx.x * 256;
  const int l15 = lane & 15, l4 = lane >> 4;
  const int srow = lane >> 2;
  const int schunk = (lane & 3) ^ ((lane >> 3) & 3);
  const int rslot8 = (l4 ^ ((l15 >> 1) & 3)) * 8;

  f32x4 acc[4][4] = {};

  auto stage = [&](int buf, int k0) {
#pragma unroll
    for (int q = 0; q < 4; ++q) {
      int seg = wid * 4 + q;
      int grow = row0 + seg * 16 + srow;
      if (grow >= M) grow = M - 1;
      gld16(A + (size_t)grow * 128 + k0 + schunk * 8, &As[buf][seg * 512]);
    }
    int gcol = wid * 16 + srow;
    gld16(Bt + (size_t)gcol * 128 + k0 + schunk * 8, &Bs[buf][wid * 512]);
  };

  stage(0, 0);
  __syncthreads();
  int cur = 0;
  for (int k0 = 0; k0 < 128; k0 += 32) {
    if (k0 + 32 < 128) stage(cur ^ 1, k0 + 32);
    bf16x8 af[4], bfr[4];
#pragma unroll
    for (int m = 0; m < 4; ++m)
      af[m] = *reinterpret_cast<bf16x8*>(&As[cur][(wid * 64 + m * 16 + l15) * 32 + rslot8]);
#pragma unroll
    for (int n = 0; n < 4; ++n)
      bfr[n] = *reinterpret_cast<bf16x8*>(&Bs[cur][(n * 16 + l15) * 32 + rslot8]);
#pragma unroll
    for (int m = 0; m < 4; ++m)
#pragma unroll
      for (int n = 0; n < 4; ++n)
        acc[m][n] = __builtin_amdgcn_mfma_f32_16x16x32_bf16(af[m], bfr[n], acc[m][n], 0, 0, 0);
    __syncthreads();
    cur ^= 1;
  }

#pragma unroll
  for (int n = 0; n < 4; ++n) {
    int col = n * 16 + l15;
    float bv = bias[col];
#pragma unroll
    for (int m = 0; m < 4; ++m) {
      int rb = row0 + wid * 64 + m * 16 + l4 * 4;
#pragma unroll
      for (int e = 0; e < 4; ++e) {
        int r = rb + e;
        if (r < M) C[(size_t)r * 64 + col] = acc[m][n][e] + bv;
      }
    }
  }
}

extern "C" void kernel_launch(void* const* d_in, const int* in_sizes, int n_in,
                              void* d_out, int out_size, void* d_ws, size_t ws_size,
                              hipStream_t stream) {
  const float* x   = (const float*)d_in[0];
  const int*   ei  = (const int*)d_in[1];
  const float* Wd1 = (const float*)d_in[3];
  const float* bd1 = (const float*)d_in[4];
  const float* Wd2 = (const float*)d_in[5];
  const float* bd2 = (const float*)d_in[6];
  const float* W1  = (const float*)d_in[7];
  const float* b1  = (const float*)d_in[8];
  const float* W2  = (const float*)d_in[9];
  const float* b2  = (const float*)d_in[10];
  const float* Wp1 = (const float*)d_in[11];
  const float* bp1 = (const float*)d_in[12];
  const float* Wp2 = (const float*)d_in[13];
  const float* bp2 = (const float*)d_in[14];
  const float* Wf  = (const float*)d_in[15];
  const float* bf_ = (const float*)d_in[16];
  float* out = (float*)d_out;
  float* ws  = (float*)d_ws;

  // workspace (float offsets), non-overlapping, 16B-aligned
  short* goidx_bf = (short*)(ws + 0);          // 10000 x 4096 bf16
  short* goidt_bf = (short*)(ws + 20480000);   // 10000 x 1280 bf16
  short* h1tmp_bf = (short*)(ws + 26880000);   // 10000 x 1024 bf16
  short* Wd1t = (short*)(ws + 32000000);       // 1024 x 4096
  short* Wd2t = (short*)(ws + 34097152);       // 1280 x 1024
  short* W1t  = (short*)(ws + 34752512);       //  256 x 1280 \ contiguous ->
  short* Wp1t = (short*)(ws + 34916352);       //  256 x 1280 / Wcomb[512][1280]
  short* W2t  = (short*)(ws + 35080192);       //  128 x 256
  short* xw1_bf = (short*)(ws + 35100000);     // 50000 x 256 bf16
  short* h1bf   = (short*)(ws + 41500000);     // 50000 x 256 bf16
  short* xw2_bf = (short*)(ws + 50460000);     // 50000 x 128 bf16
  short* h2bf   = (short*)(ws + 53660000);     // 50000 x 128 bf16
  float* deg    = ws + 60060000;               // 50,000
  int*   rowstart = (int*)(ws + 60150016);     // 40,000
  int*   cursor   = (int*)(ws + 60190016);     // 40,000
  int2*  edges    = (int2*)(ws + 60230016);    // 800,000 x 8B
  int*   gcount   = (int*)(ws + 61830016);     // 1
  short* Wp2t = (short*)(ws + 61830032);       // 128 x 256
  short* Wft  = (short*)(ws + 61846416);       //  64 x 128

  const float* gene_x = x;                          // rows 0..39999, lda=4096
  const float* goid_x = x + (size_t)kNGene * kGDim; // rows 40000..49999

  // 0) fused prep: goidx cvt + 7 weight transposes + deg init
  k_prep<<<kCvtBlocks + kTransBlocks + kInitBlocks, 256, 0, stream>>>(
      goid_x, goidx_bf, Wd1, Wd1t, Wd2, Wd2t, W1, W1t, Wp1, Wp1t,
      W2, W2t, Wp2, Wp2t, Wf, Wft, deg, gcount);

  // 1) big1: Wd1 GEMM || gene xw1 GEMM || degree histogram
  k_big1<<<kWd1Blocks + kGeneBlocks + kHistBlocks, 512, 53248, stream>>>(
      goidx_bf, Wd1t, bd1, h1tmp_bf, gene_x, W1t, xw1_bf, ei, deg);

  // 2) big2: Wd2 GEMM || rowassign
  k_big2<<<kWd2Blocks + kRowBlocks, 512, 49152, stream>>>(
      h1tmp_bf, Wd2t, bd2, goidt_bf, deg, rowstart, cursor, gcount);

  // 3) big3: combo GEMM (xw1 goid rows + h1 goid rows) || edge fill
  k_big3<<<kComboBlocks + kHistBlocks, 512, 49152, stream>>>(
      goidt_bf, W1t /*=Wcomb[512][1280]*/, bp1,
      xw1_bf + (size_t)kNGene * kH1, h1bf + (size_t)kNGene * kH1,
      ei, deg, cursor, edges);

  // 4) conv1: gather (half-wave 2-edge) -> h1 bf16 gene rows
  k_gather2<kH1><<<(kNGene * 64 + 255) / 256, 256, 0, stream>>>(
      xw1_bf, deg, rowstart, edges, b1, h1bf);

  // 5) xw2 GEMM || Wp2 GEMM
  k_xwp<<<kXw2Blocks + kWp2Blocks, 256, 49152, stream>>>(
      h1bf, W2t, xw2_bf,
      h1bf + (size_t)kNGene * kH1, Wp2t, bp2, h2bf + (size_t)kNGene * kH2);

  // 6) conv2: gather (half-wave 2-edge) -> h2 bf16 gene rows
  k_gather2<kH2><<<(kNGene * 64 + 255) / 256, 256, 0, stream>>>(
      xw2_bf, deg, rowstart, edges, b2, h2bf);

  // 7) out = h2 @ Wf + bf (bf16 MFMA, 256x64 tile)
  k_gemm_out<<<(kN + 255) / 256, 256, 0, stream>>>(h2bf, Wft, bf_, out, kN);
}